// Round 6
// baseline (171.107 us; speedup 1.0000x reference)
//
#include <hip/hip_runtime.h>

// ---------------------------------------------------------------------------
// HSIC feature-extraction pipeline, M=4096, DIM_X=1024, DIM_Y=PROJ=128
// Round 12: gram_hist_pd producer efficiency.
//   - 8-panel slot schedule: the 3 Gram terms share panels; stage each of
//     {Ah0,Ah1,Al0,Al1,Bh0,Bh1,Bl0,Bl1} exactly once into 4 rotating 16KB
//     slots with cross-phase prefetch (was 12 stages, -33% staged reads).
//   - hist epilogue: merge equal bins within each uint4 (concentrated
//     distribution -> up to 4x fewer LDS atomics at ~3 VALU ops/value).
// ---------------------------------------------------------------------------

constexpr int   MM  = 4096;
constexpr int   DX  = 1024;
constexpr int   DY  = 128;
constexpr int   PJ  = 128;
constexpr unsigned RANK0 = 8388607u;           // median ranks (even count)
constexpr unsigned RANK1 = 8388608u;
constexpr int   NTRI128 = 528;                 // 32*33/2 tiles (128^2)
constexpr int   NTRI64  = 2080;                // 64*65/2 tiles (64^2)

typedef __attribute__((ext_vector_type(8))) short bf16x8;
typedef __attribute__((ext_vector_type(4))) float f32x4;

struct Ctrl {
  unsigned pref[2];
  unsigned rrank[2];
  float sigma;
  float coef;      // -log2(e)/sigma
};

__device__ __forceinline__ unsigned mapf(float f) {
  unsigned b = __float_as_uint(f);
  return (b & 0x80000000u) ? ~b : (b | 0x80000000u);
}
__device__ __forceinline__ float unmapf(unsigned u) {
  unsigned b = (u & 0x80000000u) ? (u & 0x7fffffffu) : ~u;
  return __uint_as_float(b);
}
__device__ __forceinline__ unsigned short f2bf(float f) {
  unsigned u = __float_as_uint(f);
  return (unsigned short)((u + 0x7fffu + ((u >> 16) & 1u)) >> 16);
}
__device__ __forceinline__ float bf2f(unsigned short h) {
  return __uint_as_float(((unsigned)h) << 16);
}
__device__ __forceinline__ void gload_lds16(const void* g, void* l) {
  __builtin_amdgcn_global_load_lds(
      (const __attribute__((address_space(1))) unsigned int*)g,
      (__attribute__((address_space(3))) unsigned int*)l, 16, 0, 0);
}
__device__ __forceinline__ void tri_map(int lin, int& bi, int& bj) {
  int b = (int)((sqrtf(8.0f * (float)lin + 1.0f) - 1.0f) * 0.5f);
  while ((b + 1) * (b + 2) / 2 <= lin) ++b;
  while (b * (b + 1) / 2 > lin) --b;
  bi = b;
  bj = lin - b * (b + 1) / 2;
}

// ---- column stats (merged x and y) -----------------------------------------
__global__ void colstats(const float* __restrict__ x, const float* __restrict__ y,
                         double* __restrict__ sumx, double* __restrict__ sqx,
                         double* __restrict__ sumy, double* __restrict__ sqy) {
  const int r0 = blockIdx.y * 256;
  const float* src;
  double *sum, *sq;
  int col, ncols;
  if (blockIdx.x < 4) {
    col = blockIdx.x * 256 + threadIdx.x; ncols = DX; src = x; sum = sumx; sq = sqx;
  } else {
    col = threadIdx.x; ncols = DY; src = y; sum = sumy; sq = sqy;
    if (col >= DY) return;
  }
  const float* px = src + (size_t)r0 * ncols + col;
  double s = 0.0, s2 = 0.0;
  for (int r = 0; r < 256; ++r) {
    float v = *px;
    s  += (double)v;
    s2 += (double)v * (double)v;
    px += ncols;
  }
  atomicAdd(&sum[col], s);
  atomicAdd(&sq[col],  s2);
}

__global__ void finalize_stats(const double* __restrict__ sumx, const double* __restrict__ sqx,
                               const double* __restrict__ sumy, const double* __restrict__ sqy,
                               const float* __restrict__ gx, const float* __restrict__ bx,
                               const float* __restrict__ gy, const float* __restrict__ by,
                               float* __restrict__ axv, float* __restrict__ cxv,
                               float* __restrict__ ayv, float* __restrict__ cyv) {
  const double* sum; const double* sq; const float* gamma; const float* beta;
  float *a, *c; int j;
  if (blockIdx.x < 4) {
    j = blockIdx.x * 256 + threadIdx.x;
    sum = sumx; sq = sqx; gamma = gx; beta = bx; a = axv; c = cxv;
  } else {
    j = threadIdx.x;
    if (j >= DY) return;
    sum = sumy; sq = sqy; gamma = gy; beta = by; a = ayv; c = cyv;
  }
  double mu  = sum[j] * (1.0 / 4096.0);
  double var = sq[j] * (1.0 / 4096.0) - mu * mu;
  float rstd = (float)(1.0 / sqrt(var + 1e-5));
  float aj   = rstd * gamma[j];
  a[j] = aj;
  c[j] = beta[j] - (float)mu * aj;
}

// ---- merged prep: xsplit | ysplit | wsplit | bprime ------------------------
__global__ __launch_bounds__(256) void prep(
    const float* __restrict__ x, const float* __restrict__ y,
    const float* __restrict__ W, const float* __restrict__ b,
    const float* __restrict__ ax, const float* __restrict__ cx,
    const float* __restrict__ ay, const float* __restrict__ cy,
    unsigned short* __restrict__ Ah, unsigned short* __restrict__ Al,
    unsigned short* __restrict__ Wh, unsigned short* __restrict__ Wl,
    unsigned short* __restrict__ Zhy, unsigned short* __restrict__ Zly,
    float* __restrict__ n2y, float* __restrict__ bp) {
  __shared__ float red[256];
  const int bx = blockIdx.x, tid = threadIdx.x;
  if (bx < 4096) {                          // xsplit: xn = x*ax -> bf16 hi/lo
    int i4 = bx * 256 + tid;
    float4 v = ((const float4*)x)[i4];
    int c0 = (i4 * 4) & 1023;
    v.x *= ax[c0]; v.y *= ax[c0 + 1]; v.z *= ax[c0 + 2]; v.w *= ax[c0 + 3];
    ushort4 h, lo;
    h.x = f2bf(v.x); h.y = f2bf(v.y); h.z = f2bf(v.z); h.w = f2bf(v.w);
    lo.x = f2bf(v.x - bf2f(h.x)); lo.y = f2bf(v.y - bf2f(h.y));
    lo.z = f2bf(v.z - bf2f(h.z)); lo.w = f2bf(v.w - bf2f(h.w));
    ((ushort4*)Ah)[i4] = h;
    ((ushort4*)Al)[i4] = lo;
  } else if (bx < 5120) {                   // ysplit + row-norm
    int wv = tid >> 6, lane = tid & 63;
    int row = (bx - 4096) * 4 + wv;
    size_t base = (size_t)row * 128;
    float v0 = y[base + lane]      * ay[lane]      + cy[lane];
    float v1 = y[base + 64 + lane] * ay[64 + lane] + cy[64 + lane];
    unsigned short h0 = f2bf(v0), h1 = f2bf(v1);
    Zhy[base + lane] = h0;            Zhy[base + 64 + lane] = h1;
    Zly[base + lane] = f2bf(v0 - bf2f(h0));
    Zly[base + 64 + lane] = f2bf(v1 - bf2f(h1));
    float s = v0 * v0 + v1 * v1;
    for (int off = 32; off > 0; off >>= 1) s += __shfl_down(s, off, 64);
    if (lane == 0) n2y[row] = s;
  } else if (bx < 5248) {                   // wsplit
    int i4 = (bx - 5120) * 256 + tid;
    float4 v = ((const float4*)W)[i4];
    ushort4 h, lo;
    h.x = f2bf(v.x); h.y = f2bf(v.y); h.z = f2bf(v.z); h.w = f2bf(v.w);
    lo.x = f2bf(v.x - bf2f(h.x)); lo.y = f2bf(v.y - bf2f(h.y));
    lo.z = f2bf(v.z - bf2f(h.z)); lo.w = f2bf(v.w - bf2f(h.w));
    ((ushort4*)Wh)[i4] = h;
    ((ushort4*)Wl)[i4] = lo;
  } else {                                  // bprime: bp = b + cx @ W^T
    int p = bx - 5248;
    float s = 0.f;
    for (int j = tid; j < DX; j += 256) s += cx[j] * W[(size_t)p * DX + j];
    red[tid] = s; __syncthreads();
    for (int off = 128; off > 0; off >>= 1) {
      if (tid < off) red[tid] += red[tid + off];
      __syncthreads();
    }
    if (tid == 0) bp[p] = b[p] + red[0];
  }
}

// ---- shared MFMA helpers (128-row tiles) -----------------------------------
template <int STRIDE>
__device__ __forceinline__ void stage_panel(const unsigned short* __restrict__ src,
                                            int r0, int k0, short* dst, int tid) {
  #pragma unroll
  for (int c = 0; c < 4; ++c) {
    int e     = c * 256 + tid;            // 16B chunk index, 0..1023
    int row   = e >> 3;                   // 0..127
    int inrow = (e & 7) << 4;             // byte offset within 128B row
    int srcb  = inrow ^ ((row & 7) << 4); // pre-swizzled global source
    gload_lds16(src + (size_t)(r0 + row) * STRIDE + k0 + (srcb >> 1), &dst[e * 8]);
  }
}

__device__ __forceinline__ void mfma_tiles(const short* As, const short* Bs,
                                           int wr, int wc, int l, f32x4 (&acc)[4][4]) {
  #pragma unroll
  for (int ks = 0; ks < 2; ++ks) {
    bf16x8 af[4], bfr[4];
    #pragma unroll
    for (int mi = 0; mi < 4; ++mi) {
      int row   = wr * 64 + mi * 16 + (l & 15);
      int inrow = (ks * 64 + ((l >> 4) << 4)) ^ ((row & 7) << 4);
      af[mi] = *(const bf16x8*)&As[row * 64 + (inrow >> 1)];
    }
    #pragma unroll
    for (int ni = 0; ni < 4; ++ni) {
      int row   = wc * 64 + ni * 16 + (l & 15);
      int inrow = (ks * 64 + ((l >> 4) << 4)) ^ ((row & 7) << 4);
      bfr[ni] = *(const bf16x8*)&Bs[row * 64 + (inrow >> 1)];
    }
    #pragma unroll
    for (int mi = 0; mi < 4; ++mi)
      #pragma unroll
      for (int ni = 0; ni < 4; ++ni)
        acc[mi][ni] = __builtin_amdgcn_mfma_f32_16x16x32_bf16(af[mi], bfr[ni], acc[mi][ni], 0, 0, 0);
  }
}

// ---- 64-row tile helpers (fallback KL pass) --------------------------------
__device__ __forceinline__ void stage64(const unsigned short* __restrict__ src,
                                        int r0, int k0, short* dst, int tid) {
  #pragma unroll
  for (int c = 0; c < 2; ++c) {
    int e     = c * 256 + tid;            // 16B chunk index, 0..511
    int row   = e >> 3;                   // 0..63  (8 chunks per 128B row)
    int inrow = (e & 7) << 4;             // byte offset within 128B row
    int srcb  = inrow ^ ((row & 7) << 4);
    gload_lds16(src + (size_t)(r0 + row) * 128 + k0 + (srcb >> 1), &dst[e * 8]);
  }
}

__device__ __forceinline__ void mfma64(const short* As, const short* Bs,
                                       int wr, int wc, int l, f32x4 (&acc)[2][2]) {
  #pragma unroll
  for (int ks = 0; ks < 2; ++ks) {
    bf16x8 af[2], bfr[2];
    #pragma unroll
    for (int mi = 0; mi < 2; ++mi) {
      int row   = wr * 32 + mi * 16 + (l & 15);
      int inrow = (ks * 64 + ((l >> 4) << 4)) ^ ((row & 7) << 4);
      af[mi] = *(const bf16x8*)&As[row * 64 + (inrow >> 1)];
    }
    #pragma unroll
    for (int ni = 0; ni < 2; ++ni) {
      int row   = wc * 32 + ni * 16 + (l & 15);
      int inrow = (ks * 64 + ((l >> 4) << 4)) ^ ((row & 7) << 4);
      bfr[ni] = *(const bf16x8*)&Bs[row * 64 + (inrow >> 1)];
    }
    #pragma unroll
    for (int mi = 0; mi < 2; ++mi)
      #pragma unroll
      for (int ni = 0; ni < 2; ++ni)
        acc[mi][ni] = __builtin_amdgcn_mfma_f32_16x16x32_bf16(af[mi], bfr[ni], acc[mi][ni], 0, 0, 0);
  }
}

// ---- proj partial GEMM: grid (32 row-tiles, 8 K-chunks), double-buffered ---
__global__ __launch_bounds__(256) void proj_part(
    const unsigned short* __restrict__ Ah, const unsigned short* __restrict__ Al,
    const unsigned short* __restrict__ Wh, const unsigned short* __restrict__ Wl,
    float* __restrict__ Pp) {
  __shared__ __align__(16) short smem[32768];   // 64 KB: 2 x (A 16KB | B 16KB)
  const int tid = threadIdx.x;
  const int l   = tid & 63, w = tid >> 6;
  const int wr  = w >> 1, wc = w & 1;
  const int r0  = blockIdx.x * 128;
  const int s   = blockIdx.y;

  auto stage_ph = [&](int t, short* h) {
    int ktg  = s * 6 + t;                  // 0..47: 3 terms x 16 K-chunks
    int term = ktg >> 4, k0 = (ktg & 15) << 6;
    const unsigned short* sA = (term < 2) ? Ah : Al;   // [hi|hi|lo]
    const unsigned short* sB = (term == 1) ? Wl : Wh;  // [hi|lo|hi]
    stage_panel<1024>(sA, r0, k0, h, tid);
    stage_panel<1024>(sB, 0, k0, h + 8192, tid);
  };

  f32x4 acc[4][4] = {};
  stage_ph(0, smem);
  asm volatile("s_waitcnt vmcnt(0)" ::: "memory");
  __syncthreads();
  for (int t = 0; t < 6; ++t) {
    short* h = smem + (t & 1) * 16384;
    if (t < 5) stage_ph(t + 1, smem + ((t + 1) & 1) * 16384);
    mfma_tiles(h, h + 8192, wr, wc, l, acc);
    asm volatile("s_waitcnt vmcnt(0)" ::: "memory");
    __syncthreads();
  }
  float* out = Pp + (size_t)s * (MM * PJ);
  #pragma unroll
  for (int mi = 0; mi < 4; ++mi)
    #pragma unroll
    for (int ni = 0; ni < 4; ++ni)
      #pragma unroll
      for (int r = 0; r < 4; ++r) {
        int i = r0 + wr * 64 + mi * 16 + ((l >> 4) << 2) + r;
        int j = wc * 64 + ni * 16 + (l & 15);
        out[(size_t)i * PJ + j] = acc[mi][ni][r];
      }
}

// ---- proj finish: sum partials + bias + split + row-norm -------------------
__global__ void proj_finish(const float* __restrict__ Pp, const float* __restrict__ bp,
                            unsigned short* __restrict__ Zh, unsigned short* __restrict__ Zl,
                            float* __restrict__ n2x) {
  int wv = threadIdx.x >> 6, lane = threadIdx.x & 63;
  int row = blockIdx.x * 4 + wv;
  size_t base = (size_t)row * 128;
  float v0 = bp[lane], v1 = bp[64 + lane];
  #pragma unroll
  for (int s = 0; s < 8; ++s) {
    v0 += Pp[(size_t)s * (MM * PJ) + base + lane];
    v1 += Pp[(size_t)s * (MM * PJ) + base + 64 + lane];
  }
  unsigned short h0 = f2bf(v0), h1 = f2bf(v1);
  Zh[base + lane] = h0;            Zh[base + 64 + lane] = h1;
  Zl[base + lane] = f2bf(v0 - bf2f(h0));
  Zl[base + 64 + lane] = f2bf(v1 - bf2f(h1));
  float s2 = v0 * v0 + v1 * v1;
  for (int off = 32; off > 0; off >>= 1) s2 += __shfl_down(s2, off, 64);
  if (lane == 0) n2x[row] = s2;
}

// ---- fused gram + hist1 + pd store (fast path) -----------------------------
// 8-panel slot schedule: unique panels {A,B} x {hi,lo} x {k0,k64}, staged once
// into 4 rotating 16KB slots. Terms T1=hi.hi, T2=hi.lo, T3=lo.hi all
// accumulate into acc. Slot hazards: every overwrite is after the barrier
// ending the last phase that read the slot.
__global__ __launch_bounds__(256) void gram_hist_pd(
    const unsigned short* __restrict__ Zhx, const unsigned short* __restrict__ Zlx,
    const unsigned short* __restrict__ Zhy, const unsigned short* __restrict__ Zly,
    const float* __restrict__ n2x, const float* __restrict__ n2y,
    unsigned* __restrict__ ghx, unsigned* __restrict__ ghy,
    unsigned* __restrict__ pd) {
  __shared__ __align__(16) short smem[32768];   // 64 KB: 4 x 16KB slots
  int bi, bj;
  tri_map(blockIdx.x, bi, bj);
  const int z = blockIdx.y;
  const unsigned short* Zh = z ? Zhy : Zhx;
  const unsigned short* Zl = z ? Zly : Zlx;
  const float* n2 = z ? n2y : n2x;
  unsigned* gh = z ? ghy : ghx;
  const int r0 = bi * 128, c0 = bj * 128;

  const int tid = threadIdx.x;
  const int l   = tid & 63, w = tid >> 6;
  const int wr  = w >> 1, wc = w & 1;

  short* S0 = smem;
  short* S1 = smem + 8192;
  short* S2 = smem + 16384;
  short* S3 = smem + 24576;

  f32x4 acc[4][4] = {};
  // prologue: Ah0->S0, Bh0->S1, Bl0->S2
  stage_panel<128>(Zh, r0, 0, S0, tid);
  stage_panel<128>(Zh, c0, 0, S1, tid);
  stage_panel<128>(Zl, c0, 0, S2, tid);
  asm volatile("s_waitcnt vmcnt(0)" ::: "memory");
  __syncthreads();
  // P1: T1k0 (Ah0,Bh0); prefetch Al0->S3
  stage_panel<128>(Zl, r0, 0, S3, tid);
  mfma_tiles(S0, S1, wr, wc, l, acc);
  asm volatile("s_waitcnt vmcnt(0)" ::: "memory");
  __syncthreads();
  // P2: T2k0 (Ah0,Bl0)
  mfma_tiles(S0, S2, wr, wc, l, acc);
  __syncthreads();
  // P3: T3k0 (Al0,Bh0); prefetch Ah1->S0, Bh1->S2
  stage_panel<128>(Zh, r0, 64, S0, tid);
  stage_panel<128>(Zh, c0, 64, S2, tid);
  mfma_tiles(S3, S1, wr, wc, l, acc);
  asm volatile("s_waitcnt vmcnt(0)" ::: "memory");
  __syncthreads();
  // P4: T1k64 (Ah1,Bh1); prefetch Bl1->S1, Al1->S3
  stage_panel<128>(Zl, c0, 64, S1, tid);
  stage_panel<128>(Zl, r0, 64, S3, tid);
  mfma_tiles(S0, S2, wr, wc, l, acc);
  asm volatile("s_waitcnt vmcnt(0)" ::: "memory");
  __syncthreads();
  // P5: T2k64 (Ah1,Bl1)
  mfma_tiles(S0, S1, wr, wc, l, acc);
  __syncthreads();
  // P6: T3k64 (Al1,Bh1)
  mfma_tiles(S3, S2, wr, wc, l, acc);
  __syncthreads();

  unsigned* lh = (unsigned*)smem;
  for (int t = tid; t < 8192; t += 256) lh[t] = 0u;
  __syncthreads();

  const unsigned inc = (bi == bj) ? 1u : 2u;
  unsigned* pdt = pd + ((size_t)z * NTRI128 + blockIdx.x) * 16384;

  float n2i[4][4], n2j[4];
  #pragma unroll
  for (int mi = 0; mi < 4; ++mi)
    #pragma unroll
    for (int r = 0; r < 4; ++r)
      n2i[mi][r] = n2[r0 + wr * 64 + mi * 16 + ((l >> 4) << 2) + r];
  #pragma unroll
  for (int ni = 0; ni < 4; ++ni) n2j[ni] = n2[c0 + wc * 64 + ni * 16 + (l & 15)];

  #pragma unroll
  for (int mi = 0; mi < 4; ++mi) {
    #pragma unroll
    for (int ni = 0; ni < 4; ++ni) {
      uint4 uv;
      unsigned bb[4];
      unsigned cnt[4] = {inc, inc, inc, inc};
      #pragma unroll
      for (int r = 0; r < 4; ++r) {
        float pdv = n2i[mi][r] + n2j[ni] - 2.0f * acc[mi][ni][r];
        unsigned u = mapf(pdv);
        ((unsigned*)&uv)[r] = u;
        bb[r] = u >> 20;
      }
      *(uint4*)&pdt[(mi * 4 + ni) * 1024 + tid * 4] = uv;
      // merge equal bins (concentrated distribution -> usually 1 atomic)
      #pragma unroll
      for (int r = 3; r >= 1; --r) {
        #pragma unroll
        for (int s = 0; s < r; ++s) {
          if (bb[r] == bb[s]) { cnt[s] += cnt[r]; cnt[r] = 0; break; }
        }
      }
      #pragma unroll
      for (int r = 0; r < 4; ++r)
        if (cnt[r])
          atomicAdd(&lh[((bb[r] & 2047u) << 2) | (unsigned)(l & 3)],
                    cnt[r] << ((bb[r] >> 11) << 4));
    }
  }
  __syncthreads();
  for (int t = tid; t < 4096; t += 256) {
    unsigned idx = (unsigned)(t & 2047) << 2;
    int sh = (t >> 11) << 4;
    unsigned v = ((lh[idx]     >> sh) & 0xffffu)
               + ((lh[idx | 1] >> sh) & 0xffffu)
               + ((lh[idx | 2] >> sh) & 0xffffu)
               + ((lh[idx | 3] >> sh) & 0xffffu);
    if (v) atomicAdd(&gh[t], v);
  }
}

// ---- streaming hist2 from stored pd (fast path, uint4 loads) ---------------
__global__ __launch_bounds__(256) void pd_hist2(
    const unsigned* __restrict__ pd,
    const Ctrl* __restrict__ ctrlx, const Ctrl* __restrict__ ctrly,
    unsigned* __restrict__ part) {
  __shared__ unsigned lh[8192];
  const int tid = threadIdx.x, z = blockIdx.y;
  int bi, bj;
  tri_map(blockIdx.x, bi, bj);
  const Ctrl* ctrl = z ? ctrly : ctrlx;
  const unsigned p0 = ctrl->pref[0], p1 = ctrl->pref[1];
  const unsigned inc = (bi == bj) ? 1u : 2u;
  const uint4* pt = (const uint4*)(pd + ((size_t)z * NTRI128 + blockIdx.x) * 16384);
  for (int t = tid; t < 8192; t += 256) lh[t] = 0u;
  __syncthreads();
  #pragma unroll 4
  for (int it = 0; it < 16; ++it) {
    uint4 uv = pt[it * 256 + tid];
    #pragma unroll
    for (int e = 0; e < 4; ++e) {
      unsigned u = ((const unsigned*)&uv)[e];
      unsigned top = u >> 20, mid = (u >> 8) & 4095u;
      if (top == p0) atomicAdd(&lh[mid], inc);
      if (top == p1) atomicAdd(&lh[4096 + mid], inc);
    }
  }
  __syncthreads();
  unsigned* dst = part + ((size_t)z * NTRI128 + blockIdx.x) * 4096;
  for (int t = tid; t < 4096; t += 256)
    dst[t] = (lh[2 * t] & 0xffffu) | (lh[2 * t + 1] << 16);
}

// ---- streaming KL from stored pd (fast path, uint4 loads) ------------------
// grid (528, 2): blockIdx.y = vh splits the mi-halves (slabs 8*vh..8*vh+7).
__global__ __launch_bounds__(256) void pd_kl(
    const unsigned* __restrict__ pdx, const unsigned* __restrict__ pdy,
    const Ctrl* __restrict__ ctrlx, const Ctrl* __restrict__ ctrly,
    double* __restrict__ colK, double* __restrict__ colL, double* __restrict__ S1) {
  __shared__ float rowKs[128], rowLs[128], colKs[128], colLs[128];
  __shared__ float red[256];
  int bi, bj;
  tri_map(blockIdx.x, bi, bj);
  const int r0 = bi * 128, c0 = bj * 128;
  const bool diag = (bi == bj);
  const int tid = threadIdx.x;
  const int l = tid & 63, w = tid >> 6;
  const int wr = w >> 1, wc = w & 1;
  const int vh = blockIdx.y;
  const float fx = ctrlx->coef, fy = ctrly->coef;
  const uint4* ptx = (const uint4*)(pdx + (size_t)blockIdx.x * 16384);
  const uint4* pty = (const uint4*)(pdy + (size_t)blockIdx.x * 16384);
  if (tid < 128) { rowKs[tid] = 0.f; rowLs[tid] = 0.f; colKs[tid] = 0.f; colLs[tid] = 0.f; }
  __syncthreads();
  float s1 = 0.f;
  float cK[4] = {}, cL[4] = {};
  #pragma unroll
  for (int m = 0; m < 2; ++m) {
    int mi = vh * 2 + m;
    float rkK[4] = {}, rkL[4] = {};
    #pragma unroll
    for (int ni = 0; ni < 4; ++ni) {
      uint4 ux = ptx[(mi * 4 + ni) * 256 + tid];
      uint4 uy = pty[(mi * 4 + ni) * 256 + tid];
      #pragma unroll
      for (int r = 0; r < 4; ++r) {
        float Kv = exp2f(unmapf(((const unsigned*)&ux)[r]) * fx);
        float Lv = exp2f(unmapf(((const unsigned*)&uy)[r]) * fy);
        s1 += Kv * Lv;
        rkK[r] += Kv; rkL[r] += Lv;
        cK[ni] += Kv; cL[ni] += Lv;
      }
    }
    #pragma unroll
    for (int r = 0; r < 4; ++r) {
      int il = wr * 64 + mi * 16 + ((l >> 4) << 2) + r;
      float rk = rkK[r], rl = rkL[r];
      rk += __shfl_xor(rk, 1); rk += __shfl_xor(rk, 2);
      rk += __shfl_xor(rk, 4); rk += __shfl_xor(rk, 8);
      rl += __shfl_xor(rl, 1); rl += __shfl_xor(rl, 2);
      rl += __shfl_xor(rl, 4); rl += __shfl_xor(rl, 8);
      if ((l & 15) == 0) {
        atomicAdd(&rowKs[il], rk);
        atomicAdd(&rowLs[il], rl);
      }
    }
  }
  #pragma unroll
  for (int ni = 0; ni < 4; ++ni) {
    float ck = cK[ni], cl = cL[ni];
    ck += __shfl_xor(ck, 16); ck += __shfl_xor(ck, 32);
    cl += __shfl_xor(cl, 16); cl += __shfl_xor(cl, 32);
    if (l < 16) {
      int jl = wc * 64 + ni * 16 + l;
      atomicAdd(&colKs[jl], ck);
      atomicAdd(&colLs[jl], cl);
    }
  }
  red[tid] = s1;
  __syncthreads();
  for (int off = 128; off > 0; off >>= 1) {
    if (tid < off) red[tid] += red[tid + off];
    __syncthreads();
  }
  if (tid == 0) atomicAdd(S1, (double)red[0] * (diag ? 1.0 : 2.0));
  if (tid < 128) {
    atomicAdd(&colK[c0 + tid], (double)colKs[tid]);
    atomicAdd(&colL[c0 + tid], (double)colLs[tid]);
    if (!diag) {
      atomicAdd(&colK[r0 + tid], (double)rowKs[tid]);
      atomicAdd(&colL[r0 + tid], (double)rowLs[tid]);
    }
  }
}

// ---- gram hist passes (fallback path) --------------------------------------
template <int MODE>
__global__ __launch_bounds__(256) void gram_hist(
    const unsigned short* __restrict__ Zhx, const unsigned short* __restrict__ Zlx,
    const unsigned short* __restrict__ Zhy, const unsigned short* __restrict__ Zly,
    const float* __restrict__ n2x, const float* __restrict__ n2y,
    const Ctrl* __restrict__ ctrlx, const Ctrl* __restrict__ ctrly,
    unsigned* __restrict__ ghx, unsigned* __restrict__ ghy,
    unsigned* __restrict__ part) {
  __shared__ __align__(16) short smem[32768];
  int bi, bj;
  tri_map(blockIdx.x, bi, bj);
  const int z = blockIdx.y;
  const unsigned short* Zh = z ? Zhy : Zhx;
  const unsigned short* Zl = z ? Zly : Zlx;
  const float* n2 = z ? n2y : n2x;
  const Ctrl* ctrl = z ? ctrly : ctrlx;
  unsigned* gh = z ? ghy : ghx;
  const int r0 = bi * 128, c0 = bj * 128;

  const int tid = threadIdx.x;
  const int l   = tid & 63, w = tid >> 6;
  const int wr  = w >> 1, wc = w & 1;

  auto stage_ph = [&](int kt, short* h) {
    const unsigned short* srcA = (kt < 4) ? Zh : Zl;
    const unsigned short* srcB = (kt < 2 || kt >= 4) ? Zh : Zl;
    const int k0 = (kt & 1) * 64;
    stage_panel<128>(srcA, r0, k0, h, tid);
    stage_panel<128>(srcB, c0, k0, h + 8192, tid);
  };

  f32x4 acc[4][4] = {};
  stage_ph(0, smem);
  asm volatile("s_waitcnt vmcnt(0)" ::: "memory");
  __syncthreads();
  for (int kt = 0; kt < 6; ++kt) {
    short* h = smem + (kt & 1) * 16384;
    if (kt < 5) stage_ph(kt + 1, smem + ((kt + 1) & 1) * 16384);
    mfma_tiles(h, h + 8192, wr, wc, l, acc);
    asm volatile("s_waitcnt vmcnt(0)" ::: "memory");
    __syncthreads();
  }

  unsigned* lh = (unsigned*)smem;
  for (int t = tid; t < 8192; t += 256) lh[t] = 0u;
  __syncthreads();

  unsigned p0 = 0, p1 = 0;
  if constexpr (MODE == 2) { p0 = ctrl->pref[0]; p1 = ctrl->pref[1]; }
  const unsigned inc = (bi == bj) ? 1u : 2u;

  float n2i[4][4], n2j[4];
  #pragma unroll
  for (int mi = 0; mi < 4; ++mi)
    #pragma unroll
    for (int r = 0; r < 4; ++r)
      n2i[mi][r] = n2[r0 + wr * 64 + mi * 16 + ((l >> 4) << 2) + r];
  #pragma unroll
  for (int ni = 0; ni < 4; ++ni) n2j[ni] = n2[c0 + wc * 64 + ni * 16 + (l & 15)];

  #pragma unroll
  for (int mi = 0; mi < 4; ++mi) {
    #pragma unroll
    for (int ni = 0; ni < 4; ++ni) {
      #pragma unroll
      for (int r = 0; r < 4; ++r) {
        float pdv = n2i[mi][r] + n2j[ni] - 2.0f * acc[mi][ni][r];
        unsigned u = mapf(pdv);
        if constexpr (MODE == 1) {
          unsigned bin = u >> 20;
          atomicAdd(&lh[((bin & 2047u) << 2) | (unsigned)(l & 3)],
                    inc << ((bin >> 11) << 4));
        } else {
          unsigned top = u >> 20, mid = (u >> 8) & 4095u;
          if (top == p0) atomicAdd(&lh[mid], inc);
          if (top == p1) atomicAdd(&lh[4096 + mid], inc);
        }
      }
    }
  }
  __syncthreads();
  if constexpr (MODE == 1) {
    for (int t = tid; t < 4096; t += 256) {
      unsigned idx = (unsigned)(t & 2047) << 2;
      int sh = (t >> 11) << 4;
      unsigned v = ((lh[idx]     >> sh) & 0xffffu)
                 + ((lh[idx | 1] >> sh) & 0xffffu)
                 + ((lh[idx | 2] >> sh) & 0xffffu)
                 + ((lh[idx | 3] >> sh) & 0xffffu);
      if (v) atomicAdd(&gh[t], v);
    }
  } else {
    unsigned* dst = part + ((size_t)z * NTRI128 + blockIdx.x) * 4096;
    for (int t = tid; t < 4096; t += 256)
      dst[t] = (lh[2 * t] & 0xffffu) | (lh[2 * t + 1] << 16);
  }
}

// ---- sum the per-block MODE-2 histograms -----------------------------------
__global__ void hist2_reduce(const unsigned* __restrict__ part,
                             unsigned* __restrict__ ghx, unsigned* __restrict__ ghy) {
  const int t = blockIdx.x * 256 + threadIdx.x;   // 0..4095: u32 pair index
  const int z = blockIdx.y;
  const int b0 = blockIdx.z * 66;
  const int nb = (b0 + 66 <= NTRI128) ? 66 : (NTRI128 - b0);
  const unsigned* p = part + ((size_t)z * NTRI128 + b0) * 4096;
  unsigned s0 = 0, s1 = 0;
  for (int b = 0; b < nb; ++b) {
    unsigned v = p[(size_t)b * 4096 + t];
    s0 += v & 0xffffu;
    s1 += v >> 16;
  }
  unsigned* gh = z ? ghy : ghx;
  if (s0) atomicAdd(&gh[2 * t], s0);
  if (s1) atomicAdd(&gh[2 * t + 1], s1);
}

// ---- KL pass (fallback path, round-8 single-buffer 64^2 version) -----------
__global__ __launch_bounds__(256) void gram_kl(
    const unsigned short* __restrict__ Zhx, const unsigned short* __restrict__ Zlx,
    const unsigned short* __restrict__ Zhy, const unsigned short* __restrict__ Zly,
    const float* __restrict__ n2x, const float* __restrict__ n2y,
    const Ctrl* __restrict__ ctrlx, const Ctrl* __restrict__ ctrly,
    double* __restrict__ colK, double* __restrict__ colL, double* __restrict__ S1) {
  __shared__ __align__(16) short smem[8192];   // 16 KB: As(64x64) | Bs(64x64)
  int bi, bj;
  tri_map(blockIdx.x, bi, bj);
  const int r0 = bi * 64, c0 = bj * 64;
  const bool diag = (bi == bj);
  const int tid = threadIdx.x;
  const int l   = tid & 63, w = tid >> 6;
  const int wr  = w >> 1, wc = w & 1;
  short* As = smem;
  short* Bs = smem + 4096;

  f32x4 accx[2][2] = {};
  f32x4 accy[2][2] = {};
  #pragma unroll
  for (int m = 0; m < 2; ++m) {
    const unsigned short* Zh = m ? Zhy : Zhx;
    const unsigned short* Zl = m ? Zly : Zlx;
    for (int kt = 0; kt < 6; ++kt) {
      const unsigned short* sA = (kt < 4) ? Zh : Zl;
      const unsigned short* sB = (kt < 2 || kt >= 4) ? Zh : Zl;
      const int k0 = (kt & 1) * 64;
      stage64(sA, r0, k0, As, tid);
      stage64(sB, c0, k0, Bs, tid);
      asm volatile("s_waitcnt vmcnt(0)" ::: "memory");
      __syncthreads();
      if (m == 0) mfma64(As, Bs, wr, wc, l, accx);
      else        mfma64(As, Bs, wr, wc, l, accy);
      __syncthreads();
    }
  }

  float* rowKs = (float*)smem;
  float* rowLs = rowKs + 64;
  float* colKs = rowLs + 64;
  float* colLs = colKs + 64;
  float* red   = colLs + 64;
  ((float*)smem)[tid] = 0.f;
  __syncthreads();

  const float fx = ctrlx->coef, fy = ctrly->coef;
  float s1 = 0.f;
  float cK[2] = {0.f, 0.f}, cL[2] = {0.f, 0.f};
  #pragma unroll
  for (int mi = 0; mi < 2; ++mi) {
    #pragma unroll
    for (int r = 0; r < 4; ++r) {
      int il = wr * 32 + mi * 16 + ((l >> 4) << 2) + r;
      int i  = r0 + il;
      float rk = 0.f, rl = 0.f;
      #pragma unroll
      for (int ni = 0; ni < 2; ++ni) {
        int j = c0 + wc * 32 + ni * 16 + (l & 15);
        float Kv = exp2f((n2x[i] + n2x[j] - 2.0f * accx[mi][ni][r]) * fx);
        float Lv = exp2f((n2y[i] + n2y[j] - 2.0f * accy[mi][ni][r]) * fy);
        s1 += Kv * Lv;
        rk += Kv; rl += Lv;
        cK[ni] += Kv; cL[ni] += Lv;
      }
      rk += __shfl_xor(rk, 1); rk += __shfl_xor(rk, 2);
      rk += __shfl_xor(rk, 4); rk += __shfl_xor(rk, 8);
      rl += __shfl_xor(rl, 1); rl += __shfl_xor(rl, 2);
      rl += __shfl_xor(rl, 4); rl += __shfl_xor(rl, 8);
      if ((l & 15) == 0) {
        atomicAdd(&rowKs[il], rk);
        atomicAdd(&rowLs[il], rl);
      }
    }
  }
  #pragma unroll
  for (int ni = 0; ni < 2; ++ni) {
    float ck = cK[ni], cl = cL[ni];
    ck += __shfl_xor(ck, 16); ck += __shfl_xor(ck, 32);
    cl += __shfl_xor(cl, 16); cl += __shfl_xor(cl, 32);
    if (l < 16) {
      int jl = wc * 32 + ni * 16 + l;
      atomicAdd(&colKs[jl], ck);
      atomicAdd(&colLs[jl], cl);
    }
  }
  red[tid] = s1;
  __syncthreads();
  for (int off = 128; off > 0; off >>= 1) {
    if (tid < off) red[tid] += red[tid + off];
    __syncthreads();
  }
  if (tid == 0) atomicAdd(S1, (double)red[0] * (diag ? 1.0 : 2.0));
  if (tid < 64) {
    atomicAdd(&colK[c0 + tid], (double)colKs[tid]);
    atomicAdd(&colL[c0 + tid], (double)colLs[tid]);
    if (!diag) {
      atomicAdd(&colK[r0 + tid], (double)rowKs[tid]);
      atomicAdd(&colL[r0 + tid], (double)rowLs[tid]);
    }
  }
}

// ---- radix-select scan (one block; both matrices, both queries) ------------
template <int SEG>
__global__ void scan_select(const unsigned* __restrict__ hxa, const unsigned* __restrict__ hya,
                            int qstride, Ctrl* ctrlx, Ctrl* ctrly, int level) {
  __shared__ unsigned part[256];
  __shared__ unsigned s_bin[2];
  const int tid = threadIdx.x;
  for (int m = 0; m < 2; ++m) {
    const unsigned* hbase = m ? hya : hxa;
    Ctrl* ctrl = m ? ctrly : ctrlx;
    for (int q = 0; q < 2; ++q) {
      const unsigned* h = hbase + q * qstride;
      unsigned rank = (level == 1) ? ((q == 0) ? RANK0 : RANK1) : ctrl->rrank[q];
      unsigned loc[SEG];
      unsigned s = 0;
      #pragma unroll
      for (int b = 0; b < SEG; ++b) { loc[b] = h[tid * SEG + b]; s += loc[b]; }
      part[tid] = s; __syncthreads();
      for (int off = 1; off < 256; off <<= 1) {
        unsigned t = (tid >= off) ? part[tid - off] : 0u;
        __syncthreads();
        part[tid] += t;
        __syncthreads();
      }
      unsigned pre = part[tid] - s;
      if (rank >= pre && rank < pre + s) {
        unsigned cum = pre;
        #pragma unroll
        for (int b = 0; b < SEG; ++b) {
          if (rank < cum + loc[b]) {
            s_bin[q] = tid * SEG + b;
            if (level == 1) ctrl->rrank[q] = rank - cum;
            break;
          }
          cum += loc[b];
        }
      }
      __syncthreads();
    }
    if (level == 1) {
      if (tid < 2) ctrl->pref[tid] = s_bin[tid];
    } else {
      if (tid == 0) {
        unsigned u0 = (((ctrl->pref[0] << 12) | s_bin[0]) << 8) + 128u;
        unsigned u1 = (((ctrl->pref[1] << 12) | s_bin[1]) << 8) + 128u;
        float med = 0.5f * (unmapf(u0) + unmapf(u1));
        float sig = fmaxf(1e-6f, med);
        ctrl->sigma = sig;
        ctrl->coef  = -1.4426950408889634f / sig;
      }
    }
    __syncthreads();
  }
}

// ---- final combine ---------------------------------------------------------
__global__ void finalize_hsic(const double* __restrict__ colK, const double* __restrict__ colL,
                              const double* __restrict__ S1, float* __restrict__ out) {
  __shared__ double rk[256], rl[256], rkl[256];
  double tk = 0.0, tl = 0.0, tkl = 0.0;
  for (int i = threadIdx.x; i < MM; i += 256) {
    double k = colK[i], l = colL[i];
    tk += k; tl += l; tkl += k * l;
  }
  rk[threadIdx.x] = tk; rl[threadIdx.x] = tl; rkl[threadIdx.x] = tkl;
  __syncthreads();
  for (int off = 128; off > 0; off >>= 1) {
    if (threadIdx.x < off) {
      rk[threadIdx.x]  += rk[threadIdx.x + off];
      rl[threadIdx.x]  += rl[threadIdx.x + off];
      rkl[threadIdx.x] += rkl[threadIdx.x + off];
    }
    __syncthreads();
  }
  if (threadIdx.x == 0) {
    double m = 4096.0;
    double s = S1[0] - (2.0 / m) * rkl[0] + rk[0] * rl[0] / (m * m);
    out[0] = (float)(s / (4095.0 * 4095.0));
  }
}

// ---------------------------------------------------------------------------
extern "C" void kernel_launch(void* const* d_in, const int* in_sizes, int n_in,
                              void* d_out, int out_size, void* d_ws, size_t ws_size,
                              hipStream_t stream) {
  const float* x   = (const float*)d_in[0];
  const float* y   = (const float*)d_in[1];
  const float* bxg = (const float*)d_in[2];
  const float* bxb = (const float*)d_in[3];
  const float* byg = (const float*)d_in[4];
  const float* byb = (const float*)d_in[5];
  const float* W   = (const float*)d_in[6];
  const float* b   = (const float*)d_in[7];
  float* out = (float*)d_out;

  char* w = (char*)d_ws;
  unsigned short* Ah  = (unsigned short*)(w);                   // 8 MB
  unsigned short* Al  = (unsigned short*)(w + 8388608ull);      // 8 MB
  unsigned short* Wh  = (unsigned short*)(w + 16777216ull);     // 256 KB
  unsigned short* Wl  = (unsigned short*)(w + 17039360ull);     // 256 KB
  unsigned short* Zhx = (unsigned short*)(w + 17301504ull);     // 1 MB each
  unsigned short* Zlx = (unsigned short*)(w + 18350080ull);
  unsigned short* Zhy = (unsigned short*)(w + 19398656ull);
  unsigned short* Zly = (unsigned short*)(w + 20447232ull);
  float*          Pp  = (float*)(w + 21495808ull);              // 8 x 2 MB
  // MODE-2 per-block hist slices overlay dead Ah/Al/Wh/Wl: 17,301,504 B.
  unsigned*       part = (unsigned*)(w);
  size_t ZR = 21495808ull + 16777216ull;
  double*   sumx = (double*)(w + ZR);
  double*   sqx  = sumx + 1024;
  double*   sumy = sqx + 1024;
  double*   sqy  = sumy + 128;
  unsigned* h1x  = (unsigned*)(sqy + 128);
  unsigned* h1y  = h1x + 4096;
  unsigned* h2x  = h1y + 4096;
  unsigned* h2y  = h2x + 8192;
  double*   colK = (double*)(h2y + 8192);
  double*   colL = colK + 4096;
  double*   S1   = colL + 4096;
  size_t zero_bytes = (size_t)((char*)(S1 + 1) - (w + ZR));
  size_t PR = ZR + ((zero_bytes + 255ull) & ~255ull);
  float* ax  = (float*)(w + PR);
  float* cx  = ax + 1024;
  float* ay  = cx + 1024;
  float* cy  = ay + 128;
  float* bp  = cy + 128;
  float* n2x = bp + 128;
  float* n2y = n2x + 4096;
  Ctrl* ctrlx = (Ctrl*)(n2y + 4096);
  Ctrl* ctrly = ctrlx + 1;

  // pd store (fast path): u32[2][528][16384] at 40 MiB
  constexpr size_t PD0     = 41943040ull;
  constexpr size_t PD_ELEM = (size_t)NTRI128 * 16384;            // per z
  constexpr size_t WS_FAST = PD0 + 2ull * PD_ELEM * 4ull;        // 111,149,056
  unsigned* pdx = (unsigned*)(w + PD0);
  unsigned* pdy = pdx + PD_ELEM;
  const bool fast = (ws_size >= WS_FAST);

  hipMemsetAsync(w + ZR, 0, zero_bytes, stream);

  colstats<<<dim3(5, 16), 256, 0, stream>>>(x, y, sumx, sqx, sumy, sqy);
  finalize_stats<<<5, 256, 0, stream>>>(sumx, sqx, sumy, sqy, bxg, bxb, byg, byb,
                                        ax, cx, ay, cy);
  prep<<<5376, 256, 0, stream>>>(x, y, W, b, ax, cx, ay, cy,
                                 Ah, Al, Wh, Wl, Zhy, Zly, n2y, bp);
  proj_part<<<dim3(32, 8), 256, 0, stream>>>(Ah, Al, Wh, Wl, Pp);
  proj_finish<<<1024, 256, 0, stream>>>(Pp, bp, Zhx, Zlx, n2x);

  if (fast) {
    gram_hist_pd<<<dim3(NTRI128, 2), 256, 0, stream>>>(Zhx, Zlx, Zhy, Zly, n2x, n2y,
                                                       h1x, h1y, pdx);
    scan_select<16><<<1, 256, 0, stream>>>(h1x, h1y, 0, ctrlx, ctrly, 1);
    pd_hist2<<<dim3(NTRI128, 2), 256, 0, stream>>>(pdx, ctrlx, ctrly, part);
    hist2_reduce<<<dim3(16, 2, 8), 256, 0, stream>>>(part, h2x, h2y);
    scan_select<16><<<1, 256, 0, stream>>>(h2x, h2y, 4096, ctrlx, ctrly, 2);
    pd_kl<<<dim3(NTRI128, 2), 256, 0, stream>>>(pdx, pdy, ctrlx, ctrly,
                                                colK, colL, S1);
  } else {
    gram_hist<1><<<dim3(NTRI128, 2), 256, 0, stream>>>(Zhx, Zlx, Zhy, Zly, n2x, n2y,
                                                       ctrlx, ctrly, h1x, h1y, part);
    scan_select<16><<<1, 256, 0, stream>>>(h1x, h1y, 0, ctrlx, ctrly, 1);
    gram_hist<2><<<dim3(NTRI128, 2), 256, 0, stream>>>(Zhx, Zlx, Zhy, Zly, n2x, n2y,
                                                       ctrlx, ctrly, h2x, h2y, part);
    hist2_reduce<<<dim3(16, 2, 8), 256, 0, stream>>>(part, h2x, h2y);
    scan_select<16><<<1, 256, 0, stream>>>(h2x, h2y, 4096, ctrlx, ctrly, 2);
    gram_kl<<<NTRI64, 256, 0, stream>>>(Zhx, Zlx, Zhy, Zly, n2x, n2y,
                                        ctrlx, ctrly, colK, colL, S1);
  }
  finalize_hsic<<<1, 256, 0, stream>>>(colK, colL, S1, out);
}

// Round 7
// 165.102 us; speedup vs baseline: 1.0364x; 1.0364x over previous
//
#include <hip/hip_runtime.h>

// ---------------------------------------------------------------------------
// HSIC feature-extraction pipeline, M=4096, DIM_X=1024, DIM_Y=PROJ=128
// Round 13: exact revert to round-11 (best measured: 164.1 us).
//   Round-12's slot schedule + bin-merge both regressed (+10 us):
//   staged reads were L2-resident (FETCH unchanged), merge VALU > atomic
//   savings. Keep the uniform 1-ahead double-buffer + plain 4-copy hist.
// ---------------------------------------------------------------------------

constexpr int   MM  = 4096;
constexpr int   DX  = 1024;
constexpr int   DY  = 128;
constexpr int   PJ  = 128;
constexpr unsigned RANK0 = 8388607u;           // median ranks (even count)
constexpr unsigned RANK1 = 8388608u;
constexpr int   NTRI128 = 528;                 // 32*33/2 tiles (128^2)
constexpr int   NTRI64  = 2080;                // 64*65/2 tiles (64^2)

typedef __attribute__((ext_vector_type(8))) short bf16x8;
typedef __attribute__((ext_vector_type(4))) float f32x4;

struct Ctrl {
  unsigned pref[2];
  unsigned rrank[2];
  float sigma;
  float coef;      // -log2(e)/sigma
};

__device__ __forceinline__ unsigned mapf(float f) {
  unsigned b = __float_as_uint(f);
  return (b & 0x80000000u) ? ~b : (b | 0x80000000u);
}
__device__ __forceinline__ float unmapf(unsigned u) {
  unsigned b = (u & 0x80000000u) ? (u & 0x7fffffffu) : ~u;
  return __uint_as_float(b);
}
__device__ __forceinline__ unsigned short f2bf(float f) {
  unsigned u = __float_as_uint(f);
  return (unsigned short)((u + 0x7fffu + ((u >> 16) & 1u)) >> 16);
}
__device__ __forceinline__ float bf2f(unsigned short h) {
  return __uint_as_float(((unsigned)h) << 16);
}
__device__ __forceinline__ void gload_lds16(const void* g, void* l) {
  __builtin_amdgcn_global_load_lds(
      (const __attribute__((address_space(1))) unsigned int*)g,
      (__attribute__((address_space(3))) unsigned int*)l, 16, 0, 0);
}
__device__ __forceinline__ void tri_map(int lin, int& bi, int& bj) {
  int b = (int)((sqrtf(8.0f * (float)lin + 1.0f) - 1.0f) * 0.5f);
  while ((b + 1) * (b + 2) / 2 <= lin) ++b;
  while (b * (b + 1) / 2 > lin) --b;
  bi = b;
  bj = lin - b * (b + 1) / 2;
}

// ---- column stats (merged x and y) -----------------------------------------
__global__ void colstats(const float* __restrict__ x, const float* __restrict__ y,
                         double* __restrict__ sumx, double* __restrict__ sqx,
                         double* __restrict__ sumy, double* __restrict__ sqy) {
  const int r0 = blockIdx.y * 256;
  const float* src;
  double *sum, *sq;
  int col, ncols;
  if (blockIdx.x < 4) {
    col = blockIdx.x * 256 + threadIdx.x; ncols = DX; src = x; sum = sumx; sq = sqx;
  } else {
    col = threadIdx.x; ncols = DY; src = y; sum = sumy; sq = sqy;
    if (col >= DY) return;
  }
  const float* px = src + (size_t)r0 * ncols + col;
  double s = 0.0, s2 = 0.0;
  for (int r = 0; r < 256; ++r) {
    float v = *px;
    s  += (double)v;
    s2 += (double)v * (double)v;
    px += ncols;
  }
  atomicAdd(&sum[col], s);
  atomicAdd(&sq[col],  s2);
}

__global__ void finalize_stats(const double* __restrict__ sumx, const double* __restrict__ sqx,
                               const double* __restrict__ sumy, const double* __restrict__ sqy,
                               const float* __restrict__ gx, const float* __restrict__ bx,
                               const float* __restrict__ gy, const float* __restrict__ by,
                               float* __restrict__ axv, float* __restrict__ cxv,
                               float* __restrict__ ayv, float* __restrict__ cyv) {
  const double* sum; const double* sq; const float* gamma; const float* beta;
  float *a, *c; int j;
  if (blockIdx.x < 4) {
    j = blockIdx.x * 256 + threadIdx.x;
    sum = sumx; sq = sqx; gamma = gx; beta = bx; a = axv; c = cxv;
  } else {
    j = threadIdx.x;
    if (j >= DY) return;
    sum = sumy; sq = sqy; gamma = gy; beta = by; a = ayv; c = cyv;
  }
  double mu  = sum[j] * (1.0 / 4096.0);
  double var = sq[j] * (1.0 / 4096.0) - mu * mu;
  float rstd = (float)(1.0 / sqrt(var + 1e-5));
  float aj   = rstd * gamma[j];
  a[j] = aj;
  c[j] = beta[j] - (float)mu * aj;
}

// ---- merged prep: xsplit | ysplit | wsplit | bprime ------------------------
__global__ __launch_bounds__(256) void prep(
    const float* __restrict__ x, const float* __restrict__ y,
    const float* __restrict__ W, const float* __restrict__ b,
    const float* __restrict__ ax, const float* __restrict__ cx,
    const float* __restrict__ ay, const float* __restrict__ cy,
    unsigned short* __restrict__ Ah, unsigned short* __restrict__ Al,
    unsigned short* __restrict__ Wh, unsigned short* __restrict__ Wl,
    unsigned short* __restrict__ Zhy, unsigned short* __restrict__ Zly,
    float* __restrict__ n2y, float* __restrict__ bp) {
  __shared__ float red[256];
  const int bx = blockIdx.x, tid = threadIdx.x;
  if (bx < 4096) {                          // xsplit: xn = x*ax -> bf16 hi/lo
    int i4 = bx * 256 + tid;
    float4 v = ((const float4*)x)[i4];
    int c0 = (i4 * 4) & 1023;
    v.x *= ax[c0]; v.y *= ax[c0 + 1]; v.z *= ax[c0 + 2]; v.w *= ax[c0 + 3];
    ushort4 h, lo;
    h.x = f2bf(v.x); h.y = f2bf(v.y); h.z = f2bf(v.z); h.w = f2bf(v.w);
    lo.x = f2bf(v.x - bf2f(h.x)); lo.y = f2bf(v.y - bf2f(h.y));
    lo.z = f2bf(v.z - bf2f(h.z)); lo.w = f2bf(v.w - bf2f(h.w));
    ((ushort4*)Ah)[i4] = h;
    ((ushort4*)Al)[i4] = lo;
  } else if (bx < 5120) {                   // ysplit + row-norm
    int wv = tid >> 6, lane = tid & 63;
    int row = (bx - 4096) * 4 + wv;
    size_t base = (size_t)row * 128;
    float v0 = y[base + lane]      * ay[lane]      + cy[lane];
    float v1 = y[base + 64 + lane] * ay[64 + lane] + cy[64 + lane];
    unsigned short h0 = f2bf(v0), h1 = f2bf(v1);
    Zhy[base + lane] = h0;            Zhy[base + 64 + lane] = h1;
    Zly[base + lane] = f2bf(v0 - bf2f(h0));
    Zly[base + 64 + lane] = f2bf(v1 - bf2f(h1));
    float s = v0 * v0 + v1 * v1;
    for (int off = 32; off > 0; off >>= 1) s += __shfl_down(s, off, 64);
    if (lane == 0) n2y[row] = s;
  } else if (bx < 5248) {                   // wsplit
    int i4 = (bx - 5120) * 256 + tid;
    float4 v = ((const float4*)W)[i4];
    ushort4 h, lo;
    h.x = f2bf(v.x); h.y = f2bf(v.y); h.z = f2bf(v.z); h.w = f2bf(v.w);
    lo.x = f2bf(v.x - bf2f(h.x)); lo.y = f2bf(v.y - bf2f(h.y));
    lo.z = f2bf(v.z - bf2f(h.z)); lo.w = f2bf(v.w - bf2f(h.w));
    ((ushort4*)Wh)[i4] = h;
    ((ushort4*)Wl)[i4] = lo;
  } else {                                  // bprime: bp = b + cx @ W^T
    int p = bx - 5248;
    float s = 0.f;
    for (int j = tid; j < DX; j += 256) s += cx[j] * W[(size_t)p * DX + j];
    red[tid] = s; __syncthreads();
    for (int off = 128; off > 0; off >>= 1) {
      if (tid < off) red[tid] += red[tid + off];
      __syncthreads();
    }
    if (tid == 0) bp[p] = b[p] + red[0];
  }
}

// ---- shared MFMA helpers (128-row tiles) -----------------------------------
template <int STRIDE>
__device__ __forceinline__ void stage_panel(const unsigned short* __restrict__ src,
                                            int r0, int k0, short* dst, int tid) {
  #pragma unroll
  for (int c = 0; c < 4; ++c) {
    int e     = c * 256 + tid;            // 16B chunk index, 0..1023
    int row   = e >> 3;                   // 0..127
    int inrow = (e & 7) << 4;             // byte offset within 128B row
    int srcb  = inrow ^ ((row & 7) << 4); // pre-swizzled global source
    gload_lds16(src + (size_t)(r0 + row) * STRIDE + k0 + (srcb >> 1), &dst[e * 8]);
  }
}

__device__ __forceinline__ void mfma_tiles(const short* As, const short* Bs,
                                           int wr, int wc, int l, f32x4 (&acc)[4][4]) {
  #pragma unroll
  for (int ks = 0; ks < 2; ++ks) {
    bf16x8 af[4], bfr[4];
    #pragma unroll
    for (int mi = 0; mi < 4; ++mi) {
      int row   = wr * 64 + mi * 16 + (l & 15);
      int inrow = (ks * 64 + ((l >> 4) << 4)) ^ ((row & 7) << 4);
      af[mi] = *(const bf16x8*)&As[row * 64 + (inrow >> 1)];
    }
    #pragma unroll
    for (int ni = 0; ni < 4; ++ni) {
      int row   = wc * 64 + ni * 16 + (l & 15);
      int inrow = (ks * 64 + ((l >> 4) << 4)) ^ ((row & 7) << 4);
      bfr[ni] = *(const bf16x8*)&Bs[row * 64 + (inrow >> 1)];
    }
    #pragma unroll
    for (int mi = 0; mi < 4; ++mi)
      #pragma unroll
      for (int ni = 0; ni < 4; ++ni)
        acc[mi][ni] = __builtin_amdgcn_mfma_f32_16x16x32_bf16(af[mi], bfr[ni], acc[mi][ni], 0, 0, 0);
  }
}

// ---- 64-row tile helpers (fallback KL pass) --------------------------------
__device__ __forceinline__ void stage64(const unsigned short* __restrict__ src,
                                        int r0, int k0, short* dst, int tid) {
  #pragma unroll
  for (int c = 0; c < 2; ++c) {
    int e     = c * 256 + tid;            // 16B chunk index, 0..511
    int row   = e >> 3;                   // 0..63  (8 chunks per 128B row)
    int inrow = (e & 7) << 4;             // byte offset within 128B row
    int srcb  = inrow ^ ((row & 7) << 4);
    gload_lds16(src + (size_t)(r0 + row) * 128 + k0 + (srcb >> 1), &dst[e * 8]);
  }
}

__device__ __forceinline__ void mfma64(const short* As, const short* Bs,
                                       int wr, int wc, int l, f32x4 (&acc)[2][2]) {
  #pragma unroll
  for (int ks = 0; ks < 2; ++ks) {
    bf16x8 af[2], bfr[2];
    #pragma unroll
    for (int mi = 0; mi < 2; ++mi) {
      int row   = wr * 32 + mi * 16 + (l & 15);
      int inrow = (ks * 64 + ((l >> 4) << 4)) ^ ((row & 7) << 4);
      af[mi] = *(const bf16x8*)&As[row * 64 + (inrow >> 1)];
    }
    #pragma unroll
    for (int ni = 0; ni < 2; ++ni) {
      int row   = wc * 32 + ni * 16 + (l & 15);
      int inrow = (ks * 64 + ((l >> 4) << 4)) ^ ((row & 7) << 4);
      bfr[ni] = *(const bf16x8*)&Bs[row * 64 + (inrow >> 1)];
    }
    #pragma unroll
    for (int mi = 0; mi < 2; ++mi)
      #pragma unroll
      for (int ni = 0; ni < 2; ++ni)
        acc[mi][ni] = __builtin_amdgcn_mfma_f32_16x16x32_bf16(af[mi], bfr[ni], acc[mi][ni], 0, 0, 0);
  }
}

// ---- proj partial GEMM: grid (32 row-tiles, 8 K-chunks), double-buffered ---
__global__ __launch_bounds__(256) void proj_part(
    const unsigned short* __restrict__ Ah, const unsigned short* __restrict__ Al,
    const unsigned short* __restrict__ Wh, const unsigned short* __restrict__ Wl,
    float* __restrict__ Pp) {
  __shared__ __align__(16) short smem[32768];   // 64 KB: 2 x (A 16KB | B 16KB)
  const int tid = threadIdx.x;
  const int l   = tid & 63, w = tid >> 6;
  const int wr  = w >> 1, wc = w & 1;
  const int r0  = blockIdx.x * 128;
  const int s   = blockIdx.y;

  auto stage_ph = [&](int t, short* h) {
    int ktg  = s * 6 + t;                  // 0..47: 3 terms x 16 K-chunks
    int term = ktg >> 4, k0 = (ktg & 15) << 6;
    const unsigned short* sA = (term < 2) ? Ah : Al;   // [hi|hi|lo]
    const unsigned short* sB = (term == 1) ? Wl : Wh;  // [hi|lo|hi]
    stage_panel<1024>(sA, r0, k0, h, tid);
    stage_panel<1024>(sB, 0, k0, h + 8192, tid);
  };

  f32x4 acc[4][4] = {};
  stage_ph(0, smem);
  asm volatile("s_waitcnt vmcnt(0)" ::: "memory");
  __syncthreads();
  for (int t = 0; t < 6; ++t) {
    short* h = smem + (t & 1) * 16384;
    if (t < 5) stage_ph(t + 1, smem + ((t + 1) & 1) * 16384);
    mfma_tiles(h, h + 8192, wr, wc, l, acc);
    asm volatile("s_waitcnt vmcnt(0)" ::: "memory");
    __syncthreads();
  }
  float* out = Pp + (size_t)s * (MM * PJ);
  #pragma unroll
  for (int mi = 0; mi < 4; ++mi)
    #pragma unroll
    for (int ni = 0; ni < 4; ++ni)
      #pragma unroll
      for (int r = 0; r < 4; ++r) {
        int i = r0 + wr * 64 + mi * 16 + ((l >> 4) << 2) + r;
        int j = wc * 64 + ni * 16 + (l & 15);
        out[(size_t)i * PJ + j] = acc[mi][ni][r];
      }
}

// ---- proj finish: sum partials + bias + split + row-norm -------------------
__global__ void proj_finish(const float* __restrict__ Pp, const float* __restrict__ bp,
                            unsigned short* __restrict__ Zh, unsigned short* __restrict__ Zl,
                            float* __restrict__ n2x) {
  int wv = threadIdx.x >> 6, lane = threadIdx.x & 63;
  int row = blockIdx.x * 4 + wv;
  size_t base = (size_t)row * 128;
  float v0 = bp[lane], v1 = bp[64 + lane];
  #pragma unroll
  for (int s = 0; s < 8; ++s) {
    v0 += Pp[(size_t)s * (MM * PJ) + base + lane];
    v1 += Pp[(size_t)s * (MM * PJ) + base + 64 + lane];
  }
  unsigned short h0 = f2bf(v0), h1 = f2bf(v1);
  Zh[base + lane] = h0;            Zh[base + 64 + lane] = h1;
  Zl[base + lane] = f2bf(v0 - bf2f(h0));
  Zl[base + 64 + lane] = f2bf(v1 - bf2f(h1));
  float s2 = v0 * v0 + v1 * v1;
  for (int off = 32; off > 0; off >>= 1) s2 += __shfl_down(s2, off, 64);
  if (lane == 0) n2x[row] = s2;
}

// ---- fused gram + hist1 + pd store (fast path) -----------------------------
// pd slab layout per (z,tile): u32[16][1024], elem (mi*4+ni)*1024 + tid*4 + r.
// Stored as one uint4 per (mi,ni): 16B/lane coalesced.
__global__ __launch_bounds__(256) void gram_hist_pd(
    const unsigned short* __restrict__ Zhx, const unsigned short* __restrict__ Zlx,
    const unsigned short* __restrict__ Zhy, const unsigned short* __restrict__ Zly,
    const float* __restrict__ n2x, const float* __restrict__ n2y,
    unsigned* __restrict__ ghx, unsigned* __restrict__ ghy,
    unsigned* __restrict__ pd) {
  __shared__ __align__(16) short smem[32768];   // 64 KB: 2 x (As 16KB | Bs 16KB)
  int bi, bj;
  tri_map(blockIdx.x, bi, bj);
  const int z = blockIdx.y;
  const unsigned short* Zh = z ? Zhy : Zhx;
  const unsigned short* Zl = z ? Zly : Zlx;
  const float* n2 = z ? n2y : n2x;
  unsigned* gh = z ? ghy : ghx;
  const int r0 = bi * 128, c0 = bj * 128;

  const int tid = threadIdx.x;
  const int l   = tid & 63, w = tid >> 6;
  const int wr  = w >> 1, wc = w & 1;

  auto stage_ph = [&](int kt, short* h) {
    const unsigned short* srcA = (kt < 4) ? Zh : Zl;
    const unsigned short* srcB = (kt < 2 || kt >= 4) ? Zh : Zl;
    const int k0 = (kt & 1) * 64;
    stage_panel<128>(srcA, r0, k0, h, tid);
    stage_panel<128>(srcB, c0, k0, h + 8192, tid);
  };

  f32x4 acc[4][4] = {};
  stage_ph(0, smem);
  asm volatile("s_waitcnt vmcnt(0)" ::: "memory");
  __syncthreads();
  for (int kt = 0; kt < 6; ++kt) {
    short* h = smem + (kt & 1) * 16384;
    if (kt < 5) stage_ph(kt + 1, smem + ((kt + 1) & 1) * 16384);
    mfma_tiles(h, h + 8192, wr, wc, l, acc);
    asm volatile("s_waitcnt vmcnt(0)" ::: "memory");
    __syncthreads();
  }

  unsigned* lh = (unsigned*)smem;
  for (int t = tid; t < 8192; t += 256) lh[t] = 0u;
  __syncthreads();

  const unsigned inc = (bi == bj) ? 1u : 2u;
  unsigned* pdt = pd + ((size_t)z * NTRI128 + blockIdx.x) * 16384;

  float n2i[4][4], n2j[4];
  #pragma unroll
  for (int mi = 0; mi < 4; ++mi)
    #pragma unroll
    for (int r = 0; r < 4; ++r)
      n2i[mi][r] = n2[r0 + wr * 64 + mi * 16 + ((l >> 4) << 2) + r];
  #pragma unroll
  for (int ni = 0; ni < 4; ++ni) n2j[ni] = n2[c0 + wc * 64 + ni * 16 + (l & 15)];

  #pragma unroll
  for (int mi = 0; mi < 4; ++mi) {
    #pragma unroll
    for (int ni = 0; ni < 4; ++ni) {
      uint4 uv;
      #pragma unroll
      for (int r = 0; r < 4; ++r) {
        float pdv = n2i[mi][r] + n2j[ni] - 2.0f * acc[mi][ni][r];
        unsigned u = mapf(pdv);
        ((unsigned*)&uv)[r] = u;
        unsigned bin = u >> 20;
        atomicAdd(&lh[((bin & 2047u) << 2) | (unsigned)(l & 3)],
                  inc << ((bin >> 11) << 4));
      }
      *(uint4*)&pdt[(mi * 4 + ni) * 1024 + tid * 4] = uv;
    }
  }
  __syncthreads();
  for (int t = tid; t < 4096; t += 256) {
    unsigned idx = (unsigned)(t & 2047) << 2;
    int sh = (t >> 11) << 4;
    unsigned v = ((lh[idx]     >> sh) & 0xffffu)
               + ((lh[idx | 1] >> sh) & 0xffffu)
               + ((lh[idx | 2] >> sh) & 0xffffu)
               + ((lh[idx | 3] >> sh) & 0xffffu);
    if (v) atomicAdd(&gh[t], v);
  }
}

// ---- streaming hist2 from stored pd (fast path, uint4 loads) ---------------
__global__ __launch_bounds__(256) void pd_hist2(
    const unsigned* __restrict__ pd,
    const Ctrl* __restrict__ ctrlx, const Ctrl* __restrict__ ctrly,
    unsigned* __restrict__ part) {
  __shared__ unsigned lh[8192];
  const int tid = threadIdx.x, z = blockIdx.y;
  int bi, bj;
  tri_map(blockIdx.x, bi, bj);
  const Ctrl* ctrl = z ? ctrly : ctrlx;
  const unsigned p0 = ctrl->pref[0], p1 = ctrl->pref[1];
  const unsigned inc = (bi == bj) ? 1u : 2u;
  const uint4* pt = (const uint4*)(pd + ((size_t)z * NTRI128 + blockIdx.x) * 16384);
  for (int t = tid; t < 8192; t += 256) lh[t] = 0u;
  __syncthreads();
  #pragma unroll 4
  for (int it = 0; it < 16; ++it) {
    uint4 uv = pt[it * 256 + tid];
    #pragma unroll
    for (int e = 0; e < 4; ++e) {
      unsigned u = ((const unsigned*)&uv)[e];
      unsigned top = u >> 20, mid = (u >> 8) & 4095u;
      if (top == p0) atomicAdd(&lh[mid], inc);
      if (top == p1) atomicAdd(&lh[4096 + mid], inc);
    }
  }
  __syncthreads();
  unsigned* dst = part + ((size_t)z * NTRI128 + blockIdx.x) * 4096;
  for (int t = tid; t < 4096; t += 256)
    dst[t] = (lh[2 * t] & 0xffffu) | (lh[2 * t + 1] << 16);
}

// ---- streaming KL from stored pd (fast path, uint4 loads) ------------------
// grid (528, 2): blockIdx.y = vh splits the mi-halves (slabs 8*vh..8*vh+7).
__global__ __launch_bounds__(256) void pd_kl(
    const unsigned* __restrict__ pdx, const unsigned* __restrict__ pdy,
    const Ctrl* __restrict__ ctrlx, const Ctrl* __restrict__ ctrly,
    double* __restrict__ colK, double* __restrict__ colL, double* __restrict__ S1) {
  __shared__ float rowKs[128], rowLs[128], colKs[128], colLs[128];
  __shared__ float red[256];
  int bi, bj;
  tri_map(blockIdx.x, bi, bj);
  const int r0 = bi * 128, c0 = bj * 128;
  const bool diag = (bi == bj);
  const int tid = threadIdx.x;
  const int l = tid & 63, w = tid >> 6;
  const int wr = w >> 1, wc = w & 1;
  const int vh = blockIdx.y;
  const float fx = ctrlx->coef, fy = ctrly->coef;
  const uint4* ptx = (const uint4*)(pdx + (size_t)blockIdx.x * 16384);
  const uint4* pty = (const uint4*)(pdy + (size_t)blockIdx.x * 16384);
  if (tid < 128) { rowKs[tid] = 0.f; rowLs[tid] = 0.f; colKs[tid] = 0.f; colLs[tid] = 0.f; }
  __syncthreads();
  float s1 = 0.f;
  float cK[4] = {}, cL[4] = {};
  #pragma unroll
  for (int m = 0; m < 2; ++m) {
    int mi = vh * 2 + m;
    float rkK[4] = {}, rkL[4] = {};
    #pragma unroll
    for (int ni = 0; ni < 4; ++ni) {
      uint4 ux = ptx[(mi * 4 + ni) * 256 + tid];
      uint4 uy = pty[(mi * 4 + ni) * 256 + tid];
      #pragma unroll
      for (int r = 0; r < 4; ++r) {
        float Kv = exp2f(unmapf(((const unsigned*)&ux)[r]) * fx);
        float Lv = exp2f(unmapf(((const unsigned*)&uy)[r]) * fy);
        s1 += Kv * Lv;
        rkK[r] += Kv; rkL[r] += Lv;
        cK[ni] += Kv; cL[ni] += Lv;
      }
    }
    #pragma unroll
    for (int r = 0; r < 4; ++r) {
      int il = wr * 64 + mi * 16 + ((l >> 4) << 2) + r;
      float rk = rkK[r], rl = rkL[r];
      rk += __shfl_xor(rk, 1); rk += __shfl_xor(rk, 2);
      rk += __shfl_xor(rk, 4); rk += __shfl_xor(rk, 8);
      rl += __shfl_xor(rl, 1); rl += __shfl_xor(rl, 2);
      rl += __shfl_xor(rl, 4); rl += __shfl_xor(rl, 8);
      if ((l & 15) == 0) {
        atomicAdd(&rowKs[il], rk);
        atomicAdd(&rowLs[il], rl);
      }
    }
  }
  #pragma unroll
  for (int ni = 0; ni < 4; ++ni) {
    float ck = cK[ni], cl = cL[ni];
    ck += __shfl_xor(ck, 16); ck += __shfl_xor(ck, 32);
    cl += __shfl_xor(cl, 16); cl += __shfl_xor(cl, 32);
    if (l < 16) {
      int jl = wc * 64 + ni * 16 + l;
      atomicAdd(&colKs[jl], ck);
      atomicAdd(&colLs[jl], cl);
    }
  }
  red[tid] = s1;
  __syncthreads();
  for (int off = 128; off > 0; off >>= 1) {
    if (tid < off) red[tid] += red[tid + off];
    __syncthreads();
  }
  if (tid == 0) atomicAdd(S1, (double)red[0] * (diag ? 1.0 : 2.0));
  if (tid < 128) {
    atomicAdd(&colK[c0 + tid], (double)colKs[tid]);
    atomicAdd(&colL[c0 + tid], (double)colLs[tid]);
    if (!diag) {
      atomicAdd(&colK[r0 + tid], (double)rowKs[tid]);
      atomicAdd(&colL[r0 + tid], (double)rowLs[tid]);
    }
  }
}

// ---- gram hist passes (fallback path) --------------------------------------
template <int MODE>
__global__ __launch_bounds__(256) void gram_hist(
    const unsigned short* __restrict__ Zhx, const unsigned short* __restrict__ Zlx,
    const unsigned short* __restrict__ Zhy, const unsigned short* __restrict__ Zly,
    const float* __restrict__ n2x, const float* __restrict__ n2y,
    const Ctrl* __restrict__ ctrlx, const Ctrl* __restrict__ ctrly,
    unsigned* __restrict__ ghx, unsigned* __restrict__ ghy,
    unsigned* __restrict__ part) {
  __shared__ __align__(16) short smem[32768];
  int bi, bj;
  tri_map(blockIdx.x, bi, bj);
  const int z = blockIdx.y;
  const unsigned short* Zh = z ? Zhy : Zhx;
  const unsigned short* Zl = z ? Zly : Zlx;
  const float* n2 = z ? n2y : n2x;
  const Ctrl* ctrl = z ? ctrly : ctrlx;
  unsigned* gh = z ? ghy : ghx;
  const int r0 = bi * 128, c0 = bj * 128;

  const int tid = threadIdx.x;
  const int l   = tid & 63, w = tid >> 6;
  const int wr  = w >> 1, wc = w & 1;

  auto stage_ph = [&](int kt, short* h) {
    const unsigned short* srcA = (kt < 4) ? Zh : Zl;
    const unsigned short* srcB = (kt < 2 || kt >= 4) ? Zh : Zl;
    const int k0 = (kt & 1) * 64;
    stage_panel<128>(srcA, r0, k0, h, tid);
    stage_panel<128>(srcB, c0, k0, h + 8192, tid);
  };

  f32x4 acc[4][4] = {};
  stage_ph(0, smem);
  asm volatile("s_waitcnt vmcnt(0)" ::: "memory");
  __syncthreads();
  for (int kt = 0; kt < 6; ++kt) {
    short* h = smem + (kt & 1) * 16384;
    if (kt < 5) stage_ph(kt + 1, smem + ((kt + 1) & 1) * 16384);
    mfma_tiles(h, h + 8192, wr, wc, l, acc);
    asm volatile("s_waitcnt vmcnt(0)" ::: "memory");
    __syncthreads();
  }

  unsigned* lh = (unsigned*)smem;
  for (int t = tid; t < 8192; t += 256) lh[t] = 0u;
  __syncthreads();

  unsigned p0 = 0, p1 = 0;
  if constexpr (MODE == 2) { p0 = ctrl->pref[0]; p1 = ctrl->pref[1]; }
  const unsigned inc = (bi == bj) ? 1u : 2u;

  float n2i[4][4], n2j[4];
  #pragma unroll
  for (int mi = 0; mi < 4; ++mi)
    #pragma unroll
    for (int r = 0; r < 4; ++r)
      n2i[mi][r] = n2[r0 + wr * 64 + mi * 16 + ((l >> 4) << 2) + r];
  #pragma unroll
  for (int ni = 0; ni < 4; ++ni) n2j[ni] = n2[c0 + wc * 64 + ni * 16 + (l & 15)];

  #pragma unroll
  for (int mi = 0; mi < 4; ++mi) {
    #pragma unroll
    for (int ni = 0; ni < 4; ++ni) {
      #pragma unroll
      for (int r = 0; r < 4; ++r) {
        float pdv = n2i[mi][r] + n2j[ni] - 2.0f * acc[mi][ni][r];
        unsigned u = mapf(pdv);
        if constexpr (MODE == 1) {
          unsigned bin = u >> 20;
          atomicAdd(&lh[((bin & 2047u) << 2) | (unsigned)(l & 3)],
                    inc << ((bin >> 11) << 4));
        } else {
          unsigned top = u >> 20, mid = (u >> 8) & 4095u;
          if (top == p0) atomicAdd(&lh[mid], inc);
          if (top == p1) atomicAdd(&lh[4096 + mid], inc);
        }
      }
    }
  }
  __syncthreads();
  if constexpr (MODE == 1) {
    for (int t = tid; t < 4096; t += 256) {
      unsigned idx = (unsigned)(t & 2047) << 2;
      int sh = (t >> 11) << 4;
      unsigned v = ((lh[idx]     >> sh) & 0xffffu)
                 + ((lh[idx | 1] >> sh) & 0xffffu)
                 + ((lh[idx | 2] >> sh) & 0xffffu)
                 + ((lh[idx | 3] >> sh) & 0xffffu);
      if (v) atomicAdd(&gh[t], v);
    }
  } else {
    unsigned* dst = part + ((size_t)z * NTRI128 + blockIdx.x) * 4096;
    for (int t = tid; t < 4096; t += 256)
      dst[t] = (lh[2 * t] & 0xffffu) | (lh[2 * t + 1] << 16);
  }
}

// ---- sum the per-block MODE-2 histograms -----------------------------------
__global__ void hist2_reduce(const unsigned* __restrict__ part,
                             unsigned* __restrict__ ghx, unsigned* __restrict__ ghy) {
  const int t = blockIdx.x * 256 + threadIdx.x;   // 0..4095: u32 pair index
  const int z = blockIdx.y;
  const int b0 = blockIdx.z * 66;
  const int nb = (b0 + 66 <= NTRI128) ? 66 : (NTRI128 - b0);
  const unsigned* p = part + ((size_t)z * NTRI128 + b0) * 4096;
  unsigned s0 = 0, s1 = 0;
  for (int b = 0; b < nb; ++b) {
    unsigned v = p[(size_t)b * 4096 + t];
    s0 += v & 0xffffu;
    s1 += v >> 16;
  }
  unsigned* gh = z ? ghy : ghx;
  if (s0) atomicAdd(&gh[2 * t], s0);
  if (s1) atomicAdd(&gh[2 * t + 1], s1);
}

// ---- KL pass (fallback path, round-8 single-buffer 64^2 version) -----------
__global__ __launch_bounds__(256) void gram_kl(
    const unsigned short* __restrict__ Zhx, const unsigned short* __restrict__ Zlx,
    const unsigned short* __restrict__ Zhy, const unsigned short* __restrict__ Zly,
    const float* __restrict__ n2x, const float* __restrict__ n2y,
    const Ctrl* __restrict__ ctrlx, const Ctrl* __restrict__ ctrly,
    double* __restrict__ colK, double* __restrict__ colL, double* __restrict__ S1) {
  __shared__ __align__(16) short smem[8192];   // 16 KB: As(64x64) | Bs(64x64)
  int bi, bj;
  tri_map(blockIdx.x, bi, bj);
  const int r0 = bi * 64, c0 = bj * 64;
  const bool diag = (bi == bj);
  const int tid = threadIdx.x;
  const int l   = tid & 63, w = tid >> 6;
  const int wr  = w >> 1, wc = w & 1;
  short* As = smem;
  short* Bs = smem + 4096;

  f32x4 accx[2][2] = {};
  f32x4 accy[2][2] = {};
  #pragma unroll
  for (int m = 0; m < 2; ++m) {
    const unsigned short* Zh = m ? Zhy : Zhx;
    const unsigned short* Zl = m ? Zly : Zlx;
    for (int kt = 0; kt < 6; ++kt) {
      const unsigned short* sA = (kt < 4) ? Zh : Zl;
      const unsigned short* sB = (kt < 2 || kt >= 4) ? Zh : Zl;
      const int k0 = (kt & 1) * 64;
      stage64(sA, r0, k0, As, tid);
      stage64(sB, c0, k0, Bs, tid);
      asm volatile("s_waitcnt vmcnt(0)" ::: "memory");
      __syncthreads();
      if (m == 0) mfma64(As, Bs, wr, wc, l, accx);
      else        mfma64(As, Bs, wr, wc, l, accy);
      __syncthreads();
    }
  }

  float* rowKs = (float*)smem;
  float* rowLs = rowKs + 64;
  float* colKs = rowLs + 64;
  float* colLs = colKs + 64;
  float* red   = colLs + 64;
  ((float*)smem)[tid] = 0.f;
  __syncthreads();

  const float fx = ctrlx->coef, fy = ctrly->coef;
  float s1 = 0.f;
  float cK[2] = {0.f, 0.f}, cL[2] = {0.f, 0.f};
  #pragma unroll
  for (int mi = 0; mi < 2; ++mi) {
    #pragma unroll
    for (int r = 0; r < 4; ++r) {
      int il = wr * 32 + mi * 16 + ((l >> 4) << 2) + r;
      int i  = r0 + il;
      float rk = 0.f, rl = 0.f;
      #pragma unroll
      for (int ni = 0; ni < 2; ++ni) {
        int j = c0 + wc * 32 + ni * 16 + (l & 15);
        float Kv = exp2f((n2x[i] + n2x[j] - 2.0f * accx[mi][ni][r]) * fx);
        float Lv = exp2f((n2y[i] + n2y[j] - 2.0f * accy[mi][ni][r]) * fy);
        s1 += Kv * Lv;
        rk += Kv; rl += Lv;
        cK[ni] += Kv; cL[ni] += Lv;
      }
      rk += __shfl_xor(rk, 1); rk += __shfl_xor(rk, 2);
      rk += __shfl_xor(rk, 4); rk += __shfl_xor(rk, 8);
      rl += __shfl_xor(rl, 1); rl += __shfl_xor(rl, 2);
      rl += __shfl_xor(rl, 4); rl += __shfl_xor(rl, 8);
      if ((l & 15) == 0) {
        atomicAdd(&rowKs[il], rk);
        atomicAdd(&rowLs[il], rl);
      }
    }
  }
  #pragma unroll
  for (int ni = 0; ni < 2; ++ni) {
    float ck = cK[ni], cl = cL[ni];
    ck += __shfl_xor(ck, 16); ck += __shfl_xor(ck, 32);
    cl += __shfl_xor(cl, 16); cl += __shfl_xor(cl, 32);
    if (l < 16) {
      int jl = wc * 32 + ni * 16 + l;
      atomicAdd(&colKs[jl], ck);
      atomicAdd(&colLs[jl], cl);
    }
  }
  red[tid] = s1;
  __syncthreads();
  for (int off = 128; off > 0; off >>= 1) {
    if (tid < off) red[tid] += red[tid + off];
    __syncthreads();
  }
  if (tid == 0) atomicAdd(S1, (double)red[0] * (diag ? 1.0 : 2.0));
  if (tid < 64) {
    atomicAdd(&colK[c0 + tid], (double)colKs[tid]);
    atomicAdd(&colL[c0 + tid], (double)colLs[tid]);
    if (!diag) {
      atomicAdd(&colK[r0 + tid], (double)rowKs[tid]);
      atomicAdd(&colL[r0 + tid], (double)rowLs[tid]);
    }
  }
}

// ---- radix-select scan (one block; both matrices, both queries) ------------
template <int SEG>
__global__ void scan_select(const unsigned* __restrict__ hxa, const unsigned* __restrict__ hya,
                            int qstride, Ctrl* ctrlx, Ctrl* ctrly, int level) {
  __shared__ unsigned part[256];
  __shared__ unsigned s_bin[2];
  const int tid = threadIdx.x;
  for (int m = 0; m < 2; ++m) {
    const unsigned* hbase = m ? hya : hxa;
    Ctrl* ctrl = m ? ctrly : ctrlx;
    for (int q = 0; q < 2; ++q) {
      const unsigned* h = hbase + q * qstride;
      unsigned rank = (level == 1) ? ((q == 0) ? RANK0 : RANK1) : ctrl->rrank[q];
      unsigned loc[SEG];
      unsigned s = 0;
      #pragma unroll
      for (int b = 0; b < SEG; ++b) { loc[b] = h[tid * SEG + b]; s += loc[b]; }
      part[tid] = s; __syncthreads();
      for (int off = 1; off < 256; off <<= 1) {
        unsigned t = (tid >= off) ? part[tid - off] : 0u;
        __syncthreads();
        part[tid] += t;
        __syncthreads();
      }
      unsigned pre = part[tid] - s;
      if (rank >= pre && rank < pre + s) {
        unsigned cum = pre;
        #pragma unroll
        for (int b = 0; b < SEG; ++b) {
          if (rank < cum + loc[b]) {
            s_bin[q] = tid * SEG + b;
            if (level == 1) ctrl->rrank[q] = rank - cum;
            break;
          }
          cum += loc[b];
        }
      }
      __syncthreads();
    }
    if (level == 1) {
      if (tid < 2) ctrl->pref[tid] = s_bin[tid];
    } else {
      if (tid == 0) {
        unsigned u0 = (((ctrl->pref[0] << 12) | s_bin[0]) << 8) + 128u;
        unsigned u1 = (((ctrl->pref[1] << 12) | s_bin[1]) << 8) + 128u;
        float med = 0.5f * (unmapf(u0) + unmapf(u1));
        float sig = fmaxf(1e-6f, med);
        ctrl->sigma = sig;
        ctrl->coef  = -1.4426950408889634f / sig;
      }
    }
    __syncthreads();
  }
}

// ---- final combine ---------------------------------------------------------
__global__ void finalize_hsic(const double* __restrict__ colK, const double* __restrict__ colL,
                              const double* __restrict__ S1, float* __restrict__ out) {
  __shared__ double rk[256], rl[256], rkl[256];
  double tk = 0.0, tl = 0.0, tkl = 0.0;
  for (int i = threadIdx.x; i < MM; i += 256) {
    double k = colK[i], l = colL[i];
    tk += k; tl += l; tkl += k * l;
  }
  rk[threadIdx.x] = tk; rl[threadIdx.x] = tl; rkl[threadIdx.x] = tkl;
  __syncthreads();
  for (int off = 128; off > 0; off >>= 1) {
    if (threadIdx.x < off) {
      rk[threadIdx.x]  += rk[threadIdx.x + off];
      rl[threadIdx.x]  += rl[threadIdx.x + off];
      rkl[threadIdx.x] += rkl[threadIdx.x + off];
    }
    __syncthreads();
  }
  if (threadIdx.x == 0) {
    double m = 4096.0;
    double s = S1[0] - (2.0 / m) * rkl[0] + rk[0] * rl[0] / (m * m);
    out[0] = (float)(s / (4095.0 * 4095.0));
  }
}

// ---------------------------------------------------------------------------
extern "C" void kernel_launch(void* const* d_in, const int* in_sizes, int n_in,
                              void* d_out, int out_size, void* d_ws, size_t ws_size,
                              hipStream_t stream) {
  const float* x   = (const float*)d_in[0];
  const float* y   = (const float*)d_in[1];
  const float* bxg = (const float*)d_in[2];
  const float* bxb = (const float*)d_in[3];
  const float* byg = (const float*)d_in[4];
  const float* byb = (const float*)d_in[5];
  const float* W   = (const float*)d_in[6];
  const float* b   = (const float*)d_in[7];
  float* out = (float*)d_out;

  char* w = (char*)d_ws;
  unsigned short* Ah  = (unsigned short*)(w);                   // 8 MB
  unsigned short* Al  = (unsigned short*)(w + 8388608ull);      // 8 MB
  unsigned short* Wh  = (unsigned short*)(w + 16777216ull);     // 256 KB
  unsigned short* Wl  = (unsigned short*)(w + 17039360ull);     // 256 KB
  unsigned short* Zhx = (unsigned short*)(w + 17301504ull);     // 1 MB each
  unsigned short* Zlx = (unsigned short*)(w + 18350080ull);
  unsigned short* Zhy = (unsigned short*)(w + 19398656ull);
  unsigned short* Zly = (unsigned short*)(w + 20447232ull);
  float*          Pp  = (float*)(w + 21495808ull);              // 8 x 2 MB
  // MODE-2 per-block hist slices overlay dead Ah/Al/Wh/Wl: 17,301,504 B.
  unsigned*       part = (unsigned*)(w);
  size_t ZR = 21495808ull + 16777216ull;
  double*   sumx = (double*)(w + ZR);
  double*   sqx  = sumx + 1024;
  double*   sumy = sqx + 1024;
  double*   sqy  = sumy + 128;
  unsigned* h1x  = (unsigned*)(sqy + 128);
  unsigned* h1y  = h1x + 4096;
  unsigned* h2x  = h1y + 4096;
  unsigned* h2y  = h2x + 8192;
  double*   colK = (double*)(h2y + 8192);
  double*   colL = colK + 4096;
  double*   S1   = colL + 4096;
  size_t zero_bytes = (size_t)((char*)(S1 + 1) - (w + ZR));
  size_t PR = ZR + ((zero_bytes + 255ull) & ~255ull);
  float* ax  = (float*)(w + PR);
  float* cx  = ax + 1024;
  float* ay  = cx + 1024;
  float* cy  = ay + 128;
  float* bp  = cy + 128;
  float* n2x = bp + 128;
  float* n2y = n2x + 4096;
  Ctrl* ctrlx = (Ctrl*)(n2y + 4096);
  Ctrl* ctrly = ctrlx + 1;

  // pd store (fast path): u32[2][528][16384] at 40 MiB
  constexpr size_t PD0     = 41943040ull;
  constexpr size_t PD_ELEM = (size_t)NTRI128 * 16384;            // per z
  constexpr size_t WS_FAST = PD0 + 2ull * PD_ELEM * 4ull;        // 111,149,056
  unsigned* pdx = (unsigned*)(w + PD0);
  unsigned* pdy = pdx + PD_ELEM;
  const bool fast = (ws_size >= WS_FAST);

  hipMemsetAsync(w + ZR, 0, zero_bytes, stream);

  colstats<<<dim3(5, 16), 256, 0, stream>>>(x, y, sumx, sqx, sumy, sqy);
  finalize_stats<<<5, 256, 0, stream>>>(sumx, sqx, sumy, sqy, bxg, bxb, byg, byb,
                                        ax, cx, ay, cy);
  prep<<<5376, 256, 0, stream>>>(x, y, W, b, ax, cx, ay, cy,
                                 Ah, Al, Wh, Wl, Zhy, Zly, n2y, bp);
  proj_part<<<dim3(32, 8), 256, 0, stream>>>(Ah, Al, Wh, Wl, Pp);
  proj_finish<<<1024, 256, 0, stream>>>(Pp, bp, Zhx, Zlx, n2x);

  if (fast) {
    gram_hist_pd<<<dim3(NTRI128, 2), 256, 0, stream>>>(Zhx, Zlx, Zhy, Zly, n2x, n2y,
                                                       h1x, h1y, pdx);
    scan_select<16><<<1, 256, 0, stream>>>(h1x, h1y, 0, ctrlx, ctrly, 1);
    pd_hist2<<<dim3(NTRI128, 2), 256, 0, stream>>>(pdx, ctrlx, ctrly, part);
    hist2_reduce<<<dim3(16, 2, 8), 256, 0, stream>>>(part, h2x, h2y);
    scan_select<16><<<1, 256, 0, stream>>>(h2x, h2y, 4096, ctrlx, ctrly, 2);
    pd_kl<<<dim3(NTRI128, 2), 256, 0, stream>>>(pdx, pdy, ctrlx, ctrly,
                                                colK, colL, S1);
  } else {
    gram_hist<1><<<dim3(NTRI128, 2), 256, 0, stream>>>(Zhx, Zlx, Zhy, Zly, n2x, n2y,
                                                       ctrlx, ctrly, h1x, h1y, part);
    scan_select<16><<<1, 256, 0, stream>>>(h1x, h1y, 0, ctrlx, ctrly, 1);
    gram_hist<2><<<dim3(NTRI128, 2), 256, 0, stream>>>(Zhx, Zlx, Zhy, Zly, n2x, n2y,
                                                       ctrlx, ctrly, h2x, h2y, part);
    hist2_reduce<<<dim3(16, 2, 8), 256, 0, stream>>>(part, h2x, h2y);
    scan_select<16><<<1, 256, 0, stream>>>(h2x, h2y, 4096, ctrlx, ctrly, 2);
    gram_kl<<<NTRI64, 256, 0, stream>>>(Zhx, Zlx, Zhy, Zly, n2x, n2y,
                                        ctrlx, ctrly, colK, colL, S1);
  }
  finalize_hsic<<<1, 256, 0, stream>>>(colK, colL, S1, out);
}

// Round 8
// 152.171 us; speedup vs baseline: 1.1244x; 1.0850x over previous
//
#include <hip/hip_runtime.h>

// ---------------------------------------------------------------------------
// HSIC feature-extraction pipeline, M=4096, DIM_X=1024, DIM_Y=PROJ=128
// Round 14 (base = round-11/13, 164-165 us measured):
//   - gram_hist_pd: 512 threads/block (8 waves) on the same 128^2 tile +
//     64KB double-buffer. Doubles waves/CU at any residency; halves the
//     per-thread epilogue (32 values). pd slab reshaped to [8][2048].
//   - pd_kl: matching 512-thread rewrite, grid(528).
//   - pd_hist2: unchanged (layout-agnostic over the 16384 values).
//   - scan_select: grid(2) (parallel over matrices); level-1 locates both
//     ranks in ONE scan (histogram identical, only rank differs).
// ---------------------------------------------------------------------------

constexpr int   MM  = 4096;
constexpr int   DX  = 1024;
constexpr int   DY  = 128;
constexpr int   PJ  = 128;
constexpr unsigned RANK0 = 8388607u;           // median ranks (even count)
constexpr unsigned RANK1 = 8388608u;
constexpr int   NTRI128 = 528;                 // 32*33/2 tiles (128^2)
constexpr int   NTRI64  = 2080;                // 64*65/2 tiles (64^2)

typedef __attribute__((ext_vector_type(8))) short bf16x8;
typedef __attribute__((ext_vector_type(4))) float f32x4;

struct Ctrl {
  unsigned pref[2];
  unsigned rrank[2];
  float sigma;
  float coef;      // -log2(e)/sigma
};

__device__ __forceinline__ unsigned mapf(float f) {
  unsigned b = __float_as_uint(f);
  return (b & 0x80000000u) ? ~b : (b | 0x80000000u);
}
__device__ __forceinline__ float unmapf(unsigned u) {
  unsigned b = (u & 0x80000000u) ? (u & 0x7fffffffu) : ~u;
  return __uint_as_float(b);
}
__device__ __forceinline__ unsigned short f2bf(float f) {
  unsigned u = __float_as_uint(f);
  return (unsigned short)((u + 0x7fffu + ((u >> 16) & 1u)) >> 16);
}
__device__ __forceinline__ float bf2f(unsigned short h) {
  return __uint_as_float(((unsigned)h) << 16);
}
__device__ __forceinline__ void gload_lds16(const void* g, void* l) {
  __builtin_amdgcn_global_load_lds(
      (const __attribute__((address_space(1))) unsigned int*)g,
      (__attribute__((address_space(3))) unsigned int*)l, 16, 0, 0);
}
__device__ __forceinline__ void tri_map(int lin, int& bi, int& bj) {
  int b = (int)((sqrtf(8.0f * (float)lin + 1.0f) - 1.0f) * 0.5f);
  while ((b + 1) * (b + 2) / 2 <= lin) ++b;
  while (b * (b + 1) / 2 > lin) --b;
  bi = b;
  bj = lin - b * (b + 1) / 2;
}

// ---- column stats (merged x and y) -----------------------------------------
__global__ void colstats(const float* __restrict__ x, const float* __restrict__ y,
                         double* __restrict__ sumx, double* __restrict__ sqx,
                         double* __restrict__ sumy, double* __restrict__ sqy) {
  const int r0 = blockIdx.y * 256;
  const float* src;
  double *sum, *sq;
  int col, ncols;
  if (blockIdx.x < 4) {
    col = blockIdx.x * 256 + threadIdx.x; ncols = DX; src = x; sum = sumx; sq = sqx;
  } else {
    col = threadIdx.x; ncols = DY; src = y; sum = sumy; sq = sqy;
    if (col >= DY) return;
  }
  const float* px = src + (size_t)r0 * ncols + col;
  double s = 0.0, s2 = 0.0;
  for (int r = 0; r < 256; ++r) {
    float v = *px;
    s  += (double)v;
    s2 += (double)v * (double)v;
    px += ncols;
  }
  atomicAdd(&sum[col], s);
  atomicAdd(&sq[col],  s2);
}

__global__ void finalize_stats(const double* __restrict__ sumx, const double* __restrict__ sqx,
                               const double* __restrict__ sumy, const double* __restrict__ sqy,
                               const float* __restrict__ gx, const float* __restrict__ bx,
                               const float* __restrict__ gy, const float* __restrict__ by,
                               float* __restrict__ axv, float* __restrict__ cxv,
                               float* __restrict__ ayv, float* __restrict__ cyv) {
  const double* sum; const double* sq; const float* gamma; const float* beta;
  float *a, *c; int j;
  if (blockIdx.x < 4) {
    j = blockIdx.x * 256 + threadIdx.x;
    sum = sumx; sq = sqx; gamma = gx; beta = bx; a = axv; c = cxv;
  } else {
    j = threadIdx.x;
    if (j >= DY) return;
    sum = sumy; sq = sqy; gamma = gy; beta = by; a = ayv; c = cyv;
  }
  double mu  = sum[j] * (1.0 / 4096.0);
  double var = sq[j] * (1.0 / 4096.0) - mu * mu;
  float rstd = (float)(1.0 / sqrt(var + 1e-5));
  float aj   = rstd * gamma[j];
  a[j] = aj;
  c[j] = beta[j] - (float)mu * aj;
}

// ---- merged prep: xsplit | ysplit | wsplit | bprime ------------------------
__global__ __launch_bounds__(256) void prep(
    const float* __restrict__ x, const float* __restrict__ y,
    const float* __restrict__ W, const float* __restrict__ b,
    const float* __restrict__ ax, const float* __restrict__ cx,
    const float* __restrict__ ay, const float* __restrict__ cy,
    unsigned short* __restrict__ Ah, unsigned short* __restrict__ Al,
    unsigned short* __restrict__ Wh, unsigned short* __restrict__ Wl,
    unsigned short* __restrict__ Zhy, unsigned short* __restrict__ Zly,
    float* __restrict__ n2y, float* __restrict__ bp) {
  __shared__ float red[256];
  const int bx = blockIdx.x, tid = threadIdx.x;
  if (bx < 4096) {                          // xsplit: xn = x*ax -> bf16 hi/lo
    int i4 = bx * 256 + tid;
    float4 v = ((const float4*)x)[i4];
    int c0 = (i4 * 4) & 1023;
    v.x *= ax[c0]; v.y *= ax[c0 + 1]; v.z *= ax[c0 + 2]; v.w *= ax[c0 + 3];
    ushort4 h, lo;
    h.x = f2bf(v.x); h.y = f2bf(v.y); h.z = f2bf(v.z); h.w = f2bf(v.w);
    lo.x = f2bf(v.x - bf2f(h.x)); lo.y = f2bf(v.y - bf2f(h.y));
    lo.z = f2bf(v.z - bf2f(h.z)); lo.w = f2bf(v.w - bf2f(h.w));
    ((ushort4*)Ah)[i4] = h;
    ((ushort4*)Al)[i4] = lo;
  } else if (bx < 5120) {                   // ysplit + row-norm
    int wv = tid >> 6, lane = tid & 63;
    int row = (bx - 4096) * 4 + wv;
    size_t base = (size_t)row * 128;
    float v0 = y[base + lane]      * ay[lane]      + cy[lane];
    float v1 = y[base + 64 + lane] * ay[64 + lane] + cy[64 + lane];
    unsigned short h0 = f2bf(v0), h1 = f2bf(v1);
    Zhy[base + lane] = h0;            Zhy[base + 64 + lane] = h1;
    Zly[base + lane] = f2bf(v0 - bf2f(h0));
    Zly[base + 64 + lane] = f2bf(v1 - bf2f(h1));
    float s = v0 * v0 + v1 * v1;
    for (int off = 32; off > 0; off >>= 1) s += __shfl_down(s, off, 64);
    if (lane == 0) n2y[row] = s;
  } else if (bx < 5248) {                   // wsplit
    int i4 = (bx - 5120) * 256 + tid;
    float4 v = ((const float4*)W)[i4];
    ushort4 h, lo;
    h.x = f2bf(v.x); h.y = f2bf(v.y); h.z = f2bf(v.z); h.w = f2bf(v.w);
    lo.x = f2bf(v.x - bf2f(h.x)); lo.y = f2bf(v.y - bf2f(h.y));
    lo.z = f2bf(v.z - bf2f(h.z)); lo.w = f2bf(v.w - bf2f(h.w));
    ((ushort4*)Wh)[i4] = h;
    ((ushort4*)Wl)[i4] = lo;
  } else {                                  // bprime: bp = b + cx @ W^T
    int p = bx - 5248;
    float s = 0.f;
    for (int j = tid; j < DX; j += 256) s += cx[j] * W[(size_t)p * DX + j];
    red[tid] = s; __syncthreads();
    for (int off = 128; off > 0; off >>= 1) {
      if (tid < off) red[tid] += red[tid + off];
      __syncthreads();
    }
    if (tid == 0) bp[p] = b[p] + red[0];
  }
}

// ---- shared MFMA helpers (128-row tiles, 256-thread) -----------------------
template <int STRIDE>
__device__ __forceinline__ void stage_panel(const unsigned short* __restrict__ src,
                                            int r0, int k0, short* dst, int tid) {
  #pragma unroll
  for (int c = 0; c < 4; ++c) {
    int e     = c * 256 + tid;            // 16B chunk index, 0..1023
    int row   = e >> 3;                   // 0..127
    int inrow = (e & 7) << 4;             // byte offset within 128B row
    int srcb  = inrow ^ ((row & 7) << 4); // pre-swizzled global source
    gload_lds16(src + (size_t)(r0 + row) * STRIDE + k0 + (srcb >> 1), &dst[e * 8]);
  }
}

// 512-thread variant (2 chunks/thread)
template <int STRIDE>
__device__ __forceinline__ void stage_panel2(const unsigned short* __restrict__ src,
                                             int r0, int k0, short* dst, int tid) {
  #pragma unroll
  for (int c = 0; c < 2; ++c) {
    int e     = c * 512 + tid;            // 16B chunk index, 0..1023
    int row   = e >> 3;
    int inrow = (e & 7) << 4;
    int srcb  = inrow ^ ((row & 7) << 4);
    gload_lds16(src + (size_t)(r0 + row) * STRIDE + k0 + (srcb >> 1), &dst[e * 8]);
  }
}

__device__ __forceinline__ void mfma_tiles(const short* As, const short* Bs,
                                           int wr, int wc, int l, f32x4 (&acc)[4][4]) {
  #pragma unroll
  for (int ks = 0; ks < 2; ++ks) {
    bf16x8 af[4], bfr[4];
    #pragma unroll
    for (int mi = 0; mi < 4; ++mi) {
      int row   = wr * 64 + mi * 16 + (l & 15);
      int inrow = (ks * 64 + ((l >> 4) << 4)) ^ ((row & 7) << 4);
      af[mi] = *(const bf16x8*)&As[row * 64 + (inrow >> 1)];
    }
    #pragma unroll
    for (int ni = 0; ni < 4; ++ni) {
      int row   = wc * 64 + ni * 16 + (l & 15);
      int inrow = (ks * 64 + ((l >> 4) << 4)) ^ ((row & 7) << 4);
      bfr[ni] = *(const bf16x8*)&Bs[row * 64 + (inrow >> 1)];
    }
    #pragma unroll
    for (int mi = 0; mi < 4; ++mi)
      #pragma unroll
      for (int ni = 0; ni < 4; ++ni)
        acc[mi][ni] = __builtin_amdgcn_mfma_f32_16x16x32_bf16(af[mi], bfr[ni], acc[mi][ni], 0, 0, 0);
  }
}

// 8-wave variant: wave (wr 0..1, wc 0..3) owns 64x32; acc[4][2]
__device__ __forceinline__ void mfma_tiles8(const short* As, const short* Bs,
                                            int wr, int wc, int l, f32x4 (&acc)[4][2]) {
  #pragma unroll
  for (int ks = 0; ks < 2; ++ks) {
    bf16x8 af[4], bfr[2];
    #pragma unroll
    for (int mi = 0; mi < 4; ++mi) {
      int row   = wr * 64 + mi * 16 + (l & 15);
      int inrow = (ks * 64 + ((l >> 4) << 4)) ^ ((row & 7) << 4);
      af[mi] = *(const bf16x8*)&As[row * 64 + (inrow >> 1)];
    }
    #pragma unroll
    for (int ni = 0; ni < 2; ++ni) {
      int row   = wc * 32 + ni * 16 + (l & 15);
      int inrow = (ks * 64 + ((l >> 4) << 4)) ^ ((row & 7) << 4);
      bfr[ni] = *(const bf16x8*)&Bs[row * 64 + (inrow >> 1)];
    }
    #pragma unroll
    for (int mi = 0; mi < 4; ++mi)
      #pragma unroll
      for (int ni = 0; ni < 2; ++ni)
        acc[mi][ni] = __builtin_amdgcn_mfma_f32_16x16x32_bf16(af[mi], bfr[ni], acc[mi][ni], 0, 0, 0);
  }
}

// ---- 64-row tile helpers (fallback KL pass) --------------------------------
__device__ __forceinline__ void stage64(const unsigned short* __restrict__ src,
                                        int r0, int k0, short* dst, int tid) {
  #pragma unroll
  for (int c = 0; c < 2; ++c) {
    int e     = c * 256 + tid;            // 16B chunk index, 0..511
    int row   = e >> 3;                   // 0..63  (8 chunks per 128B row)
    int inrow = (e & 7) << 4;             // byte offset within 128B row
    int srcb  = inrow ^ ((row & 7) << 4);
    gload_lds16(src + (size_t)(r0 + row) * 128 + k0 + (srcb >> 1), &dst[e * 8]);
  }
}

__device__ __forceinline__ void mfma64(const short* As, const short* Bs,
                                       int wr, int wc, int l, f32x4 (&acc)[2][2]) {
  #pragma unroll
  for (int ks = 0; ks < 2; ++ks) {
    bf16x8 af[2], bfr[2];
    #pragma unroll
    for (int mi = 0; mi < 2; ++mi) {
      int row   = wr * 32 + mi * 16 + (l & 15);
      int inrow = (ks * 64 + ((l >> 4) << 4)) ^ ((row & 7) << 4);
      af[mi] = *(const bf16x8*)&As[row * 64 + (inrow >> 1)];
    }
    #pragma unroll
    for (int ni = 0; ni < 2; ++ni) {
      int row   = wc * 32 + ni * 16 + (l & 15);
      int inrow = (ks * 64 + ((l >> 4) << 4)) ^ ((row & 7) << 4);
      bfr[ni] = *(const bf16x8*)&Bs[row * 64 + (inrow >> 1)];
    }
    #pragma unroll
    for (int mi = 0; mi < 2; ++mi)
      #pragma unroll
      for (int ni = 0; ni < 2; ++ni)
        acc[mi][ni] = __builtin_amdgcn_mfma_f32_16x16x32_bf16(af[mi], bfr[ni], acc[mi][ni], 0, 0, 0);
  }
}

// ---- proj partial GEMM: grid (32 row-tiles, 8 K-chunks), double-buffered ---
__global__ __launch_bounds__(256) void proj_part(
    const unsigned short* __restrict__ Ah, const unsigned short* __restrict__ Al,
    const unsigned short* __restrict__ Wh, const unsigned short* __restrict__ Wl,
    float* __restrict__ Pp) {
  __shared__ __align__(16) short smem[32768];   // 64 KB: 2 x (A 16KB | B 16KB)
  const int tid = threadIdx.x;
  const int l   = tid & 63, w = tid >> 6;
  const int wr  = w >> 1, wc = w & 1;
  const int r0  = blockIdx.x * 128;
  const int s   = blockIdx.y;

  auto stage_ph = [&](int t, short* h) {
    int ktg  = s * 6 + t;                  // 0..47: 3 terms x 16 K-chunks
    int term = ktg >> 4, k0 = (ktg & 15) << 6;
    const unsigned short* sA = (term < 2) ? Ah : Al;   // [hi|hi|lo]
    const unsigned short* sB = (term == 1) ? Wl : Wh;  // [hi|lo|hi]
    stage_panel<1024>(sA, r0, k0, h, tid);
    stage_panel<1024>(sB, 0, k0, h + 8192, tid);
  };

  f32x4 acc[4][4] = {};
  stage_ph(0, smem);
  asm volatile("s_waitcnt vmcnt(0)" ::: "memory");
  __syncthreads();
  for (int t = 0; t < 6; ++t) {
    short* h = smem + (t & 1) * 16384;
    if (t < 5) stage_ph(t + 1, smem + ((t + 1) & 1) * 16384);
    mfma_tiles(h, h + 8192, wr, wc, l, acc);
    asm volatile("s_waitcnt vmcnt(0)" ::: "memory");
    __syncthreads();
  }
  float* out = Pp + (size_t)s * (MM * PJ);
  #pragma unroll
  for (int mi = 0; mi < 4; ++mi)
    #pragma unroll
    for (int ni = 0; ni < 4; ++ni)
      #pragma unroll
      for (int r = 0; r < 4; ++r) {
        int i = r0 + wr * 64 + mi * 16 + ((l >> 4) << 2) + r;
        int j = wc * 64 + ni * 16 + (l & 15);
        out[(size_t)i * PJ + j] = acc[mi][ni][r];
      }
}

// ---- proj finish: sum partials + bias + split + row-norm -------------------
__global__ void proj_finish(const float* __restrict__ Pp, const float* __restrict__ bp,
                            unsigned short* __restrict__ Zh, unsigned short* __restrict__ Zl,
                            float* __restrict__ n2x) {
  int wv = threadIdx.x >> 6, lane = threadIdx.x & 63;
  int row = blockIdx.x * 4 + wv;
  size_t base = (size_t)row * 128;
  float v0 = bp[lane], v1 = bp[64 + lane];
  #pragma unroll
  for (int s = 0; s < 8; ++s) {
    v0 += Pp[(size_t)s * (MM * PJ) + base + lane];
    v1 += Pp[(size_t)s * (MM * PJ) + base + 64 + lane];
  }
  unsigned short h0 = f2bf(v0), h1 = f2bf(v1);
  Zh[base + lane] = h0;            Zh[base + 64 + lane] = h1;
  Zl[base + lane] = f2bf(v0 - bf2f(h0));
  Zl[base + 64 + lane] = f2bf(v1 - bf2f(h1));
  float s2 = v0 * v0 + v1 * v1;
  for (int off = 32; off > 0; off >>= 1) s2 += __shfl_down(s2, off, 64);
  if (lane == 0) n2x[row] = s2;
}

// ---- fused gram + hist1 + pd store (fast path, 512 threads / 8 waves) ------
// pd slab layout per (z,tile): u32[8][2048], elem (mi*2+ni)*2048 + tid*4 + r.
// Stored as one uint4 per (mi,ni): 16B/lane coalesced.
__global__ __launch_bounds__(512) void gram_hist_pd(
    const unsigned short* __restrict__ Zhx, const unsigned short* __restrict__ Zlx,
    const unsigned short* __restrict__ Zhy, const unsigned short* __restrict__ Zly,
    const float* __restrict__ n2x, const float* __restrict__ n2y,
    unsigned* __restrict__ ghx, unsigned* __restrict__ ghy,
    unsigned* __restrict__ pd) {
  __shared__ __align__(16) short smem[32768];   // 64 KB: 2 x (As 16KB | Bs 16KB)
  int bi, bj;
  tri_map(blockIdx.x, bi, bj);
  const int z = blockIdx.y;
  const unsigned short* Zh = z ? Zhy : Zhx;
  const unsigned short* Zl = z ? Zly : Zlx;
  const float* n2 = z ? n2y : n2x;
  unsigned* gh = z ? ghy : ghx;
  const int r0 = bi * 128, c0 = bj * 128;

  const int tid = threadIdx.x;                 // 0..511
  const int l   = tid & 63, w = tid >> 6;      // w 0..7
  const int wr  = w >> 2, wc = w & 3;          // wave tile: 64 rows x 32 cols

  auto stage_ph = [&](int kt, short* h) {
    const unsigned short* srcA = (kt < 4) ? Zh : Zl;
    const unsigned short* srcB = (kt < 2 || kt >= 4) ? Zh : Zl;
    const int k0 = (kt & 1) * 64;
    stage_panel2<128>(srcA, r0, k0, h, tid);
    stage_panel2<128>(srcB, c0, k0, h + 8192, tid);
  };

  f32x4 acc[4][2] = {};
  stage_ph(0, smem);
  asm volatile("s_waitcnt vmcnt(0)" ::: "memory");
  __syncthreads();
  for (int kt = 0; kt < 6; ++kt) {
    short* h = smem + (kt & 1) * 16384;
    if (kt < 5) stage_ph(kt + 1, smem + ((kt + 1) & 1) * 16384);
    mfma_tiles8(h, h + 8192, wr, wc, l, acc);
    asm volatile("s_waitcnt vmcnt(0)" ::: "memory");
    __syncthreads();
  }

  unsigned* lh = (unsigned*)smem;
  for (int t = tid; t < 8192; t += 512) lh[t] = 0u;
  __syncthreads();

  const unsigned inc = (bi == bj) ? 1u : 2u;
  unsigned* pdt = pd + ((size_t)z * NTRI128 + blockIdx.x) * 16384;

  float n2i[4][4], n2j[2];
  #pragma unroll
  for (int mi = 0; mi < 4; ++mi)
    #pragma unroll
    for (int r = 0; r < 4; ++r)
      n2i[mi][r] = n2[r0 + wr * 64 + mi * 16 + ((l >> 4) << 2) + r];
  #pragma unroll
  for (int ni = 0; ni < 2; ++ni) n2j[ni] = n2[c0 + wc * 32 + ni * 16 + (l & 15)];

  #pragma unroll
  for (int mi = 0; mi < 4; ++mi) {
    #pragma unroll
    for (int ni = 0; ni < 2; ++ni) {
      uint4 uv;
      #pragma unroll
      for (int r = 0; r < 4; ++r) {
        float pdv = n2i[mi][r] + n2j[ni] - 2.0f * acc[mi][ni][r];
        unsigned u = mapf(pdv);
        ((unsigned*)&uv)[r] = u;
        unsigned bin = u >> 20;
        atomicAdd(&lh[((bin & 2047u) << 2) | (unsigned)(l & 3)],
                  inc << ((bin >> 11) << 4));
      }
      *(uint4*)&pdt[(mi * 2 + ni) * 2048 + tid * 4] = uv;
    }
  }
  __syncthreads();
  for (int t = tid; t < 4096; t += 512) {
    unsigned idx = (unsigned)(t & 2047) << 2;
    int sh = (t >> 11) << 4;
    unsigned v = ((lh[idx]     >> sh) & 0xffffu)
               + ((lh[idx | 1] >> sh) & 0xffffu)
               + ((lh[idx | 2] >> sh) & 0xffffu)
               + ((lh[idx | 3] >> sh) & 0xffffu);
    if (v) atomicAdd(&gh[t], v);
  }
}

// ---- streaming hist2 from stored pd (fast path, uint4 loads) ---------------
// Layout-agnostic: histograms all 16384 values of the slab regardless of order.
__global__ __launch_bounds__(256) void pd_hist2(
    const unsigned* __restrict__ pd,
    const Ctrl* __restrict__ ctrlx, const Ctrl* __restrict__ ctrly,
    unsigned* __restrict__ part) {
  __shared__ unsigned lh[8192];
  const int tid = threadIdx.x, z = blockIdx.y;
  int bi, bj;
  tri_map(blockIdx.x, bi, bj);
  const Ctrl* ctrl = z ? ctrly : ctrlx;
  const unsigned p0 = ctrl->pref[0], p1 = ctrl->pref[1];
  const unsigned inc = (bi == bj) ? 1u : 2u;
  const uint4* pt = (const uint4*)(pd + ((size_t)z * NTRI128 + blockIdx.x) * 16384);
  for (int t = tid; t < 8192; t += 256) lh[t] = 0u;
  __syncthreads();
  #pragma unroll 4
  for (int it = 0; it < 16; ++it) {
    uint4 uv = pt[it * 256 + tid];
    #pragma unroll
    for (int e = 0; e < 4; ++e) {
      unsigned u = ((const unsigned*)&uv)[e];
      unsigned top = u >> 20, mid = (u >> 8) & 4095u;
      if (top == p0) atomicAdd(&lh[mid], inc);
      if (top == p1) atomicAdd(&lh[4096 + mid], inc);
    }
  }
  __syncthreads();
  unsigned* dst = part + ((size_t)z * NTRI128 + blockIdx.x) * 4096;
  for (int t = tid; t < 4096; t += 256)
    dst[t] = (lh[2 * t] & 0xffffu) | (lh[2 * t + 1] << 16);
}

// ---- streaming KL from stored pd (fast path, 512 threads, grid 528) --------
// Index map mirrors the 512-thread producer:
//   value (mi*2+ni)*2048 + tid*4 + r  <->  i = r0 + wr*64+mi*16+((l>>4)<<2)+r,
//                                          j = c0 + wc*32+ni*16+(l&15)
__global__ __launch_bounds__(512) void pd_kl(
    const unsigned* __restrict__ pdx, const unsigned* __restrict__ pdy,
    const Ctrl* __restrict__ ctrlx, const Ctrl* __restrict__ ctrly,
    double* __restrict__ colK, double* __restrict__ colL, double* __restrict__ S1) {
  __shared__ float rowKs[128], rowLs[128], colKs[128], colLs[128];
  __shared__ float red[512];
  int bi, bj;
  tri_map(blockIdx.x, bi, bj);
  const int r0 = bi * 128, c0 = bj * 128;
  const bool diag = (bi == bj);
  const int tid = threadIdx.x;
  const int l = tid & 63, w = tid >> 6;
  const int wr = w >> 2, wc = w & 3;
  const float fx = ctrlx->coef, fy = ctrly->coef;
  const uint4* ptx = (const uint4*)(pdx + (size_t)blockIdx.x * 16384);
  const uint4* pty = (const uint4*)(pdy + (size_t)blockIdx.x * 16384);
  if (tid < 128) { rowKs[tid] = 0.f; rowLs[tid] = 0.f; colKs[tid] = 0.f; colLs[tid] = 0.f; }
  __syncthreads();
  float s1 = 0.f;
  float cK[2] = {}, cL[2] = {};
  #pragma unroll
  for (int mi = 0; mi < 4; ++mi) {
    float rkK[4] = {}, rkL[4] = {};
    #pragma unroll
    for (int ni = 0; ni < 2; ++ni) {
      uint4 ux = ptx[(mi * 2 + ni) * 512 + tid];
      uint4 uy = pty[(mi * 2 + ni) * 512 + tid];
      #pragma unroll
      for (int r = 0; r < 4; ++r) {
        float Kv = exp2f(unmapf(((const unsigned*)&ux)[r]) * fx);
        float Lv = exp2f(unmapf(((const unsigned*)&uy)[r]) * fy);
        s1 += Kv * Lv;
        rkK[r] += Kv; rkL[r] += Lv;
        cK[ni] += Kv; cL[ni] += Lv;
      }
    }
    #pragma unroll
    for (int r = 0; r < 4; ++r) {
      int il = wr * 64 + mi * 16 + ((l >> 4) << 2) + r;
      float rk = rkK[r], rl = rkL[r];
      rk += __shfl_xor(rk, 1); rk += __shfl_xor(rk, 2);
      rk += __shfl_xor(rk, 4); rk += __shfl_xor(rk, 8);
      rl += __shfl_xor(rl, 1); rl += __shfl_xor(rl, 2);
      rl += __shfl_xor(rl, 4); rl += __shfl_xor(rl, 8);
      if ((l & 15) == 0) {
        atomicAdd(&rowKs[il], rk);
        atomicAdd(&rowLs[il], rl);
      }
    }
  }
  #pragma unroll
  for (int ni = 0; ni < 2; ++ni) {
    float ck = cK[ni], cl = cL[ni];
    ck += __shfl_xor(ck, 16); ck += __shfl_xor(ck, 32);
    cl += __shfl_xor(cl, 16); cl += __shfl_xor(cl, 32);
    if (l < 16) {
      int jl = wc * 32 + ni * 16 + l;
      atomicAdd(&colKs[jl], ck);
      atomicAdd(&colLs[jl], cl);
    }
  }
  red[tid] = s1;
  __syncthreads();
  for (int off = 256; off > 0; off >>= 1) {
    if (tid < off) red[tid] += red[tid + off];
    __syncthreads();
  }
  if (tid == 0) atomicAdd(S1, (double)red[0] * (diag ? 1.0 : 2.0));
  if (tid < 128) {
    atomicAdd(&colK[c0 + tid], (double)colKs[tid]);
    atomicAdd(&colL[c0 + tid], (double)colLs[tid]);
    if (!diag) {
      atomicAdd(&colK[r0 + tid], (double)rowKs[tid]);
      atomicAdd(&colL[r0 + tid], (double)rowLs[tid]);
    }
  }
}

// ---- gram hist passes (fallback path) --------------------------------------
template <int MODE>
__global__ __launch_bounds__(256) void gram_hist(
    const unsigned short* __restrict__ Zhx, const unsigned short* __restrict__ Zlx,
    const unsigned short* __restrict__ Zhy, const unsigned short* __restrict__ Zly,
    const float* __restrict__ n2x, const float* __restrict__ n2y,
    const Ctrl* __restrict__ ctrlx, const Ctrl* __restrict__ ctrly,
    unsigned* __restrict__ ghx, unsigned* __restrict__ ghy,
    unsigned* __restrict__ part) {
  __shared__ __align__(16) short smem[32768];
  int bi, bj;
  tri_map(blockIdx.x, bi, bj);
  const int z = blockIdx.y;
  const unsigned short* Zh = z ? Zhy : Zhx;
  const unsigned short* Zl = z ? Zly : Zlx;
  const float* n2 = z ? n2y : n2x;
  const Ctrl* ctrl = z ? ctrly : ctrlx;
  unsigned* gh = z ? ghy : ghx;
  const int r0 = bi * 128, c0 = bj * 128;

  const int tid = threadIdx.x;
  const int l   = tid & 63, w = tid >> 6;
  const int wr  = w >> 1, wc = w & 1;

  auto stage_ph = [&](int kt, short* h) {
    const unsigned short* srcA = (kt < 4) ? Zh : Zl;
    const unsigned short* srcB = (kt < 2 || kt >= 4) ? Zh : Zl;
    const int k0 = (kt & 1) * 64;
    stage_panel<128>(srcA, r0, k0, h, tid);
    stage_panel<128>(srcB, c0, k0, h + 8192, tid);
  };

  f32x4 acc[4][4] = {};
  stage_ph(0, smem);
  asm volatile("s_waitcnt vmcnt(0)" ::: "memory");
  __syncthreads();
  for (int kt = 0; kt < 6; ++kt) {
    short* h = smem + (kt & 1) * 16384;
    if (kt < 5) stage_ph(kt + 1, smem + ((kt + 1) & 1) * 16384);
    mfma_tiles(h, h + 8192, wr, wc, l, acc);
    asm volatile("s_waitcnt vmcnt(0)" ::: "memory");
    __syncthreads();
  }

  unsigned* lh = (unsigned*)smem;
  for (int t = tid; t < 8192; t += 256) lh[t] = 0u;
  __syncthreads();

  unsigned p0 = 0, p1 = 0;
  if constexpr (MODE == 2) { p0 = ctrl->pref[0]; p1 = ctrl->pref[1]; }
  const unsigned inc = (bi == bj) ? 1u : 2u;

  float n2i[4][4], n2j[4];
  #pragma unroll
  for (int mi = 0; mi < 4; ++mi)
    #pragma unroll
    for (int r = 0; r < 4; ++r)
      n2i[mi][r] = n2[r0 + wr * 64 + mi * 16 + ((l >> 4) << 2) + r];
  #pragma unroll
  for (int ni = 0; ni < 4; ++ni) n2j[ni] = n2[c0 + wc * 64 + ni * 16 + (l & 15)];

  #pragma unroll
  for (int mi = 0; mi < 4; ++mi) {
    #pragma unroll
    for (int ni = 0; ni < 4; ++ni) {
      #pragma unroll
      for (int r = 0; r < 4; ++r) {
        float pdv = n2i[mi][r] + n2j[ni] - 2.0f * acc[mi][ni][r];
        unsigned u = mapf(pdv);
        if constexpr (MODE == 1) {
          unsigned bin = u >> 20;
          atomicAdd(&lh[((bin & 2047u) << 2) | (unsigned)(l & 3)],
                    inc << ((bin >> 11) << 4));
        } else {
          unsigned top = u >> 20, mid = (u >> 8) & 4095u;
          if (top == p0) atomicAdd(&lh[mid], inc);
          if (top == p1) atomicAdd(&lh[4096 + mid], inc);
        }
      }
    }
  }
  __syncthreads();
  if constexpr (MODE == 1) {
    for (int t = tid; t < 4096; t += 256) {
      unsigned idx = (unsigned)(t & 2047) << 2;
      int sh = (t >> 11) << 4;
      unsigned v = ((lh[idx]     >> sh) & 0xffffu)
                 + ((lh[idx | 1] >> sh) & 0xffffu)
                 + ((lh[idx | 2] >> sh) & 0xffffu)
                 + ((lh[idx | 3] >> sh) & 0xffffu);
      if (v) atomicAdd(&gh[t], v);
    }
  } else {
    unsigned* dst = part + ((size_t)z * NTRI128 + blockIdx.x) * 4096;
    for (int t = tid; t < 4096; t += 256)
      dst[t] = (lh[2 * t] & 0xffffu) | (lh[2 * t + 1] << 16);
  }
}

// ---- sum the per-block MODE-2 histograms -----------------------------------
__global__ void hist2_reduce(const unsigned* __restrict__ part,
                             unsigned* __restrict__ ghx, unsigned* __restrict__ ghy) {
  const int t = blockIdx.x * 256 + threadIdx.x;   // 0..4095: u32 pair index
  const int z = blockIdx.y;
  const int b0 = blockIdx.z * 66;
  const int nb = (b0 + 66 <= NTRI128) ? 66 : (NTRI128 - b0);
  const unsigned* p = part + ((size_t)z * NTRI128 + b0) * 4096;
  unsigned s0 = 0, s1 = 0;
  for (int b = 0; b < nb; ++b) {
    unsigned v = p[(size_t)b * 4096 + t];
    s0 += v & 0xffffu;
    s1 += v >> 16;
  }
  unsigned* gh = z ? ghy : ghx;
  if (s0) atomicAdd(&gh[2 * t], s0);
  if (s1) atomicAdd(&gh[2 * t + 1], s1);
}

// ---- KL pass (fallback path, round-8 single-buffer 64^2 version) -----------
__global__ __launch_bounds__(256) void gram_kl(
    const unsigned short* __restrict__ Zhx, const unsigned short* __restrict__ Zlx,
    const unsigned short* __restrict__ Zhy, const unsigned short* __restrict__ Zly,
    const float* __restrict__ n2x, const float* __restrict__ n2y,
    const Ctrl* __restrict__ ctrlx, const Ctrl* __restrict__ ctrly,
    double* __restrict__ colK, double* __restrict__ colL, double* __restrict__ S1) {
  __shared__ __align__(16) short smem[8192];   // 16 KB: As(64x64) | Bs(64x64)
  int bi, bj;
  tri_map(blockIdx.x, bi, bj);
  const int r0 = bi * 64, c0 = bj * 64;
  const bool diag = (bi == bj);
  const int tid = threadIdx.x;
  const int l   = tid & 63, w = tid >> 6;
  const int wr  = w >> 1, wc = w & 1;
  short* As = smem;
  short* Bs = smem + 4096;

  f32x4 accx[2][2] = {};
  f32x4 accy[2][2] = {};
  #pragma unroll
  for (int m = 0; m < 2; ++m) {
    const unsigned short* Zh = m ? Zhy : Zhx;
    const unsigned short* Zl = m ? Zly : Zlx;
    for (int kt = 0; kt < 6; ++kt) {
      const unsigned short* sA = (kt < 4) ? Zh : Zl;
      const unsigned short* sB = (kt < 2 || kt >= 4) ? Zh : Zl;
      const int k0 = (kt & 1) * 64;
      stage64(sA, r0, k0, As, tid);
      stage64(sB, c0, k0, Bs, tid);
      asm volatile("s_waitcnt vmcnt(0)" ::: "memory");
      __syncthreads();
      if (m == 0) mfma64(As, Bs, wr, wc, l, accx);
      else        mfma64(As, Bs, wr, wc, l, accy);
      __syncthreads();
    }
  }

  float* rowKs = (float*)smem;
  float* rowLs = rowKs + 64;
  float* colKs = rowLs + 64;
  float* colLs = colKs + 64;
  float* red   = colLs + 64;
  ((float*)smem)[tid] = 0.f;
  __syncthreads();

  const float fx = ctrlx->coef, fy = ctrly->coef;
  float s1 = 0.f;
  float cK[2] = {0.f, 0.f}, cL[2] = {0.f, 0.f};
  #pragma unroll
  for (int mi = 0; mi < 2; ++mi) {
    #pragma unroll
    for (int r = 0; r < 4; ++r) {
      int il = wr * 32 + mi * 16 + ((l >> 4) << 2) + r;
      int i  = r0 + il;
      float rk = 0.f, rl = 0.f;
      #pragma unroll
      for (int ni = 0; ni < 2; ++ni) {
        int j = c0 + wc * 32 + ni * 16 + (l & 15);
        float Kv = exp2f((n2x[i] + n2x[j] - 2.0f * accx[mi][ni][r]) * fx);
        float Lv = exp2f((n2y[i] + n2y[j] - 2.0f * accy[mi][ni][r]) * fy);
        s1 += Kv * Lv;
        rk += Kv; rl += Lv;
        cK[ni] += Kv; cL[ni] += Lv;
      }
      rk += __shfl_xor(rk, 1); rk += __shfl_xor(rk, 2);
      rk += __shfl_xor(rk, 4); rk += __shfl_xor(rk, 8);
      rl += __shfl_xor(rl, 1); rl += __shfl_xor(rl, 2);
      rl += __shfl_xor(rl, 4); rl += __shfl_xor(rl, 8);
      if ((l & 15) == 0) {
        atomicAdd(&rowKs[il], rk);
        atomicAdd(&rowLs[il], rl);
      }
    }
  }
  #pragma unroll
  for (int ni = 0; ni < 2; ++ni) {
    float ck = cK[ni], cl = cL[ni];
    ck += __shfl_xor(ck, 16); ck += __shfl_xor(ck, 32);
    cl += __shfl_xor(cl, 16); cl += __shfl_xor(cl, 32);
    if (l < 16) {
      int jl = wc * 32 + ni * 16 + l;
      atomicAdd(&colKs[jl], ck);
      atomicAdd(&colLs[jl], cl);
    }
  }
  red[tid] = s1;
  __syncthreads();
  for (int off = 128; off > 0; off >>= 1) {
    if (tid < off) red[tid] += red[tid + off];
    __syncthreads();
  }
  if (tid == 0) atomicAdd(S1, (double)red[0] * (diag ? 1.0 : 2.0));
  if (tid < 64) {
    atomicAdd(&colK[c0 + tid], (double)colKs[tid]);
    atomicAdd(&colL[c0 + tid], (double)colLs[tid]);
    if (!diag) {
      atomicAdd(&colK[r0 + tid], (double)rowKs[tid]);
      atomicAdd(&colL[r0 + tid], (double)rowLs[tid]);
    }
  }
}

// ---- radix-select scan: grid(2) = one block per matrix ---------------------
// level 1: ONE scan locates both RANK0 and RANK1 (same histogram).
// level 2: two scans (q=0,1) over the refine histograms; tid0 computes sigma.
template <int SEG>
__global__ void scan_select(const unsigned* __restrict__ hxa, const unsigned* __restrict__ hya,
                            int qstride, Ctrl* ctrlx, Ctrl* ctrly, int level) {
  __shared__ unsigned part[256];
  __shared__ unsigned s_bin[2];
  const int tid = threadIdx.x;
  const int m = blockIdx.x;
  const unsigned* hbase = m ? hya : hxa;
  Ctrl* ctrl = m ? ctrly : ctrlx;
  const int nq = (level == 1) ? 1 : 2;
  for (int q = 0; q < nq; ++q) {
    const unsigned* h = hbase + q * qstride;
    unsigned loc[SEG];
    unsigned s = 0;
    #pragma unroll
    for (int b = 0; b < SEG; ++b) { loc[b] = h[tid * SEG + b]; s += loc[b]; }
    part[tid] = s; __syncthreads();
    for (int off = 1; off < 256; off <<= 1) {
      unsigned t = (tid >= off) ? part[tid - off] : 0u;
      __syncthreads();
      part[tid] += t;
      __syncthreads();
    }
    unsigned pre = part[tid] - s;
    if (level == 1) {
      #pragma unroll
      for (int qq = 0; qq < 2; ++qq) {
        unsigned rank = qq ? RANK1 : RANK0;
        if (rank >= pre && rank < pre + s) {
          unsigned cum = pre;
          #pragma unroll
          for (int b = 0; b < SEG; ++b) {
            if (rank < cum + loc[b]) {
              s_bin[qq] = tid * SEG + b;
              ctrl->rrank[qq] = rank - cum;
              break;
            }
            cum += loc[b];
          }
        }
      }
    } else {
      unsigned rank = ctrl->rrank[q];
      if (rank >= pre && rank < pre + s) {
        unsigned cum = pre;
        #pragma unroll
        for (int b = 0; b < SEG; ++b) {
          if (rank < cum + loc[b]) {
            s_bin[q] = tid * SEG + b;
            break;
          }
          cum += loc[b];
        }
      }
    }
    __syncthreads();
  }
  if (level == 1) {
    if (tid < 2) ctrl->pref[tid] = s_bin[tid];
  } else if (tid == 0) {
    unsigned u0 = (((ctrl->pref[0] << 12) | s_bin[0]) << 8) + 128u;
    unsigned u1 = (((ctrl->pref[1] << 12) | s_bin[1]) << 8) + 128u;
    float med = 0.5f * (unmapf(u0) + unmapf(u1));
    float sig = fmaxf(1e-6f, med);
    ctrl->sigma = sig;
    ctrl->coef  = -1.4426950408889634f / sig;
  }
}

// ---- final combine ---------------------------------------------------------
__global__ void finalize_hsic(const double* __restrict__ colK, const double* __restrict__ colL,
                              const double* __restrict__ S1, float* __restrict__ out) {
  __shared__ double rk[256], rl[256], rkl[256];
  double tk = 0.0, tl = 0.0, tkl = 0.0;
  for (int i = threadIdx.x; i < MM; i += 256) {
    double k = colK[i], l = colL[i];
    tk += k; tl += l; tkl += k * l;
  }
  rk[threadIdx.x] = tk; rl[threadIdx.x] = tl; rkl[threadIdx.x] = tkl;
  __syncthreads();
  for (int off = 128; off > 0; off >>= 1) {
    if (threadIdx.x < off) {
      rk[threadIdx.x]  += rk[threadIdx.x + off];
      rl[threadIdx.x]  += rl[threadIdx.x + off];
      rkl[threadIdx.x] += rkl[threadIdx.x + off];
    }
    __syncthreads();
  }
  if (threadIdx.x == 0) {
    double m = 4096.0;
    double s = S1[0] - (2.0 / m) * rkl[0] + rk[0] * rl[0] / (m * m);
    out[0] = (float)(s / (4095.0 * 4095.0));
  }
}

// ---------------------------------------------------------------------------
extern "C" void kernel_launch(void* const* d_in, const int* in_sizes, int n_in,
                              void* d_out, int out_size, void* d_ws, size_t ws_size,
                              hipStream_t stream) {
  const float* x   = (const float*)d_in[0];
  const float* y   = (const float*)d_in[1];
  const float* bxg = (const float*)d_in[2];
  const float* bxb = (const float*)d_in[3];
  const float* byg = (const float*)d_in[4];
  const float* byb = (const float*)d_in[5];
  const float* W   = (const float*)d_in[6];
  const float* b   = (const float*)d_in[7];
  float* out = (float*)d_out;

  char* w = (char*)d_ws;
  unsigned short* Ah  = (unsigned short*)(w);                   // 8 MB
  unsigned short* Al  = (unsigned short*)(w + 8388608ull);      // 8 MB
  unsigned short* Wh  = (unsigned short*)(w + 16777216ull);     // 256 KB
  unsigned short* Wl  = (unsigned short*)(w + 17039360ull);     // 256 KB
  unsigned short* Zhx = (unsigned short*)(w + 17301504ull);     // 1 MB each
  unsigned short* Zlx = (unsigned short*)(w + 18350080ull);
  unsigned short* Zhy = (unsigned short*)(w + 19398656ull);
  unsigned short* Zly = (unsigned short*)(w + 20447232ull);
  float*          Pp  = (float*)(w + 21495808ull);              // 8 x 2 MB
  // MODE-2 per-block hist slices overlay dead Ah/Al/Wh/Wl: 17,301,504 B.
  unsigned*       part = (unsigned*)(w);
  size_t ZR = 21495808ull + 16777216ull;
  double*   sumx = (double*)(w + ZR);
  double*   sqx  = sumx + 1024;
  double*   sumy = sqx + 1024;
  double*   sqy  = sumy + 128;
  unsigned* h1x  = (unsigned*)(sqy + 128);
  unsigned* h1y  = h1x + 4096;
  unsigned* h2x  = h1y + 4096;
  unsigned* h2y  = h2x + 8192;
  double*   colK = (double*)(h2y + 8192);
  double*   colL = colK + 4096;
  double*   S1   = colL + 4096;
  size_t zero_bytes = (size_t)((char*)(S1 + 1) - (w + ZR));
  size_t PR = ZR + ((zero_bytes + 255ull) & ~255ull);
  float* ax  = (float*)(w + PR);
  float* cx  = ax + 1024;
  float* ay  = cx + 1024;
  float* cy  = ay + 128;
  float* bp  = cy + 128;
  float* n2x = bp + 128;
  float* n2y = n2x + 4096;
  Ctrl* ctrlx = (Ctrl*)(n2y + 4096);
  Ctrl* ctrly = ctrlx + 1;

  // pd store (fast path): u32[2][528][16384] at 40 MiB
  constexpr size_t PD0     = 41943040ull;
  constexpr size_t PD_ELEM = (size_t)NTRI128 * 16384;            // per z
  constexpr size_t WS_FAST = PD0 + 2ull * PD_ELEM * 4ull;        // 111,149,056
  unsigned* pdx = (unsigned*)(w + PD0);
  unsigned* pdy = pdx + PD_ELEM;
  const bool fast = (ws_size >= WS_FAST);

  hipMemsetAsync(w + ZR, 0, zero_bytes, stream);

  colstats<<<dim3(5, 16), 256, 0, stream>>>(x, y, sumx, sqx, sumy, sqy);
  finalize_stats<<<5, 256, 0, stream>>>(sumx, sqx, sumy, sqy, bxg, bxb, byg, byb,
                                        ax, cx, ay, cy);
  prep<<<5376, 256, 0, stream>>>(x, y, W, b, ax, cx, ay, cy,
                                 Ah, Al, Wh, Wl, Zhy, Zly, n2y, bp);
  proj_part<<<dim3(32, 8), 256, 0, stream>>>(Ah, Al, Wh, Wl, Pp);
  proj_finish<<<1024, 256, 0, stream>>>(Pp, bp, Zhx, Zlx, n2x);

  if (fast) {
    gram_hist_pd<<<dim3(NTRI128, 2), 512, 0, stream>>>(Zhx, Zlx, Zhy, Zly, n2x, n2y,
                                                       h1x, h1y, pdx);
    scan_select<16><<<2, 256, 0, stream>>>(h1x, h1y, 0, ctrlx, ctrly, 1);
    pd_hist2<<<dim3(NTRI128, 2), 256, 0, stream>>>(pdx, ctrlx, ctrly, part);
    hist2_reduce<<<dim3(16, 2, 8), 256, 0, stream>>>(part, h2x, h2y);
    scan_select<16><<<2, 256, 0, stream>>>(h2x, h2y, 4096, ctrlx, ctrly, 2);
    pd_kl<<<NTRI128, 512, 0, stream>>>(pdx, pdy, ctrlx, ctrly,
                                       colK, colL, S1);
  } else {
    gram_hist<1><<<dim3(NTRI128, 2), 256, 0, stream>>>(Zhx, Zlx, Zhy, Zly, n2x, n2y,
                                                       ctrlx, ctrly, h1x, h1y, part);
    scan_select<16><<<2, 256, 0, stream>>>(h1x, h1y, 0, ctrlx, ctrly, 1);
    gram_hist<2><<<dim3(NTRI128, 2), 256, 0, stream>>>(Zhx, Zlx, Zhy, Zly, n2x, n2y,
                                                       ctrlx, ctrly, h2x, h2y, part);
    hist2_reduce<<<dim3(16, 2, 8), 256, 0, stream>>>(part, h2x, h2y);
    scan_select<16><<<2, 256, 0, stream>>>(h2x, h2y, 4096, ctrlx, ctrly, 2);
    gram_kl<<<NTRI64, 256, 0, stream>>>(Zhx, Zlx, Zhy, Zly, n2x, n2y,
                                        ctrlx, ctrly, colK, colL, S1);
  }
  finalize_hsic<<<1, 256, 0, stream>>>(colK, colL, S1, out);
}

// Round 9
// 150.242 us; speedup vs baseline: 1.1389x; 1.0128x over previous
//
#include <hip/hip_runtime.h>

// ---------------------------------------------------------------------------
// HSIC feature-extraction pipeline, M=4096, DIM_X=1024, DIM_Y=PROJ=128
// Round 15 (base = round-14, 152.2 us measured):
//   - hipMemsetAsync(180 KB) replaced by a custom zero_ws kernel.
//     rocprof showed the runtime's fillBufferAligned occupying ~39.5 us per
//     iteration at 8% occupancy with near-zero traffic; a grid-stride uint4
//     zero kernel does the same work in ~2 us.
//   - everything else identical to round 14.
// ---------------------------------------------------------------------------

constexpr int   MM  = 4096;
constexpr int   DX  = 1024;
constexpr int   DY  = 128;
constexpr int   PJ  = 128;
constexpr unsigned RANK0 = 8388607u;           // median ranks (even count)
constexpr unsigned RANK1 = 8388608u;
constexpr int   NTRI128 = 528;                 // 32*33/2 tiles (128^2)
constexpr int   NTRI64  = 2080;                // 64*65/2 tiles (64^2)

typedef __attribute__((ext_vector_type(8))) short bf16x8;
typedef __attribute__((ext_vector_type(4))) float f32x4;

struct Ctrl {
  unsigned pref[2];
  unsigned rrank[2];
  float sigma;
  float coef;      // -log2(e)/sigma
};

__device__ __forceinline__ unsigned mapf(float f) {
  unsigned b = __float_as_uint(f);
  return (b & 0x80000000u) ? ~b : (b | 0x80000000u);
}
__device__ __forceinline__ float unmapf(unsigned u) {
  unsigned b = (u & 0x80000000u) ? (u & 0x7fffffffu) : ~u;
  return __uint_as_float(b);
}
__device__ __forceinline__ unsigned short f2bf(float f) {
  unsigned u = __float_as_uint(f);
  return (unsigned short)((u + 0x7fffu + ((u >> 16) & 1u)) >> 16);
}
__device__ __forceinline__ float bf2f(unsigned short h) {
  return __uint_as_float(((unsigned)h) << 16);
}
__device__ __forceinline__ void gload_lds16(const void* g, void* l) {
  __builtin_amdgcn_global_load_lds(
      (const __attribute__((address_space(1))) unsigned int*)g,
      (__attribute__((address_space(3))) unsigned int*)l, 16, 0, 0);
}
__device__ __forceinline__ void tri_map(int lin, int& bi, int& bj) {
  int b = (int)((sqrtf(8.0f * (float)lin + 1.0f) - 1.0f) * 0.5f);
  while ((b + 1) * (b + 2) / 2 <= lin) ++b;
  while (b * (b + 1) / 2 > lin) --b;
  bi = b;
  bj = lin - b * (b + 1) / 2;
}

// ---- workspace zeroing (replaces pathological hipMemsetAsync fill) ---------
__global__ void zero_ws(uint4* __restrict__ dst, int n16) {
  int i = blockIdx.x * 256 + threadIdx.x;
  if (i < n16) dst[i] = uint4{0u, 0u, 0u, 0u};
}

// ---- column stats (merged x and y) -----------------------------------------
__global__ void colstats(const float* __restrict__ x, const float* __restrict__ y,
                         double* __restrict__ sumx, double* __restrict__ sqx,
                         double* __restrict__ sumy, double* __restrict__ sqy) {
  const int r0 = blockIdx.y * 256;
  const float* src;
  double *sum, *sq;
  int col, ncols;
  if (blockIdx.x < 4) {
    col = blockIdx.x * 256 + threadIdx.x; ncols = DX; src = x; sum = sumx; sq = sqx;
  } else {
    col = threadIdx.x; ncols = DY; src = y; sum = sumy; sq = sqy;
    if (col >= DY) return;
  }
  const float* px = src + (size_t)r0 * ncols + col;
  double s = 0.0, s2 = 0.0;
  for (int r = 0; r < 256; ++r) {
    float v = *px;
    s  += (double)v;
    s2 += (double)v * (double)v;
    px += ncols;
  }
  atomicAdd(&sum[col], s);
  atomicAdd(&sq[col],  s2);
}

__global__ void finalize_stats(const double* __restrict__ sumx, const double* __restrict__ sqx,
                               const double* __restrict__ sumy, const double* __restrict__ sqy,
                               const float* __restrict__ gx, const float* __restrict__ bx,
                               const float* __restrict__ gy, const float* __restrict__ by,
                               float* __restrict__ axv, float* __restrict__ cxv,
                               float* __restrict__ ayv, float* __restrict__ cyv) {
  const double* sum; const double* sq; const float* gamma; const float* beta;
  float *a, *c; int j;
  if (blockIdx.x < 4) {
    j = blockIdx.x * 256 + threadIdx.x;
    sum = sumx; sq = sqx; gamma = gx; beta = bx; a = axv; c = cxv;
  } else {
    j = threadIdx.x;
    if (j >= DY) return;
    sum = sumy; sq = sqy; gamma = gy; beta = by; a = ayv; c = cyv;
  }
  double mu  = sum[j] * (1.0 / 4096.0);
  double var = sq[j] * (1.0 / 4096.0) - mu * mu;
  float rstd = (float)(1.0 / sqrt(var + 1e-5));
  float aj   = rstd * gamma[j];
  a[j] = aj;
  c[j] = beta[j] - (float)mu * aj;
}

// ---- merged prep: xsplit | ysplit | wsplit | bprime ------------------------
__global__ __launch_bounds__(256) void prep(
    const float* __restrict__ x, const float* __restrict__ y,
    const float* __restrict__ W, const float* __restrict__ b,
    const float* __restrict__ ax, const float* __restrict__ cx,
    const float* __restrict__ ay, const float* __restrict__ cy,
    unsigned short* __restrict__ Ah, unsigned short* __restrict__ Al,
    unsigned short* __restrict__ Wh, unsigned short* __restrict__ Wl,
    unsigned short* __restrict__ Zhy, unsigned short* __restrict__ Zly,
    float* __restrict__ n2y, float* __restrict__ bp) {
  __shared__ float red[256];
  const int bx = blockIdx.x, tid = threadIdx.x;
  if (bx < 4096) {                          // xsplit: xn = x*ax -> bf16 hi/lo
    int i4 = bx * 256 + tid;
    float4 v = ((const float4*)x)[i4];
    int c0 = (i4 * 4) & 1023;
    v.x *= ax[c0]; v.y *= ax[c0 + 1]; v.z *= ax[c0 + 2]; v.w *= ax[c0 + 3];
    ushort4 h, lo;
    h.x = f2bf(v.x); h.y = f2bf(v.y); h.z = f2bf(v.z); h.w = f2bf(v.w);
    lo.x = f2bf(v.x - bf2f(h.x)); lo.y = f2bf(v.y - bf2f(h.y));
    lo.z = f2bf(v.z - bf2f(h.z)); lo.w = f2bf(v.w - bf2f(h.w));
    ((ushort4*)Ah)[i4] = h;
    ((ushort4*)Al)[i4] = lo;
  } else if (bx < 5120) {                   // ysplit + row-norm
    int wv = tid >> 6, lane = tid & 63;
    int row = (bx - 4096) * 4 + wv;
    size_t base = (size_t)row * 128;
    float v0 = y[base + lane]      * ay[lane]      + cy[lane];
    float v1 = y[base + 64 + lane] * ay[64 + lane] + cy[64 + lane];
    unsigned short h0 = f2bf(v0), h1 = f2bf(v1);
    Zhy[base + lane] = h0;            Zhy[base + 64 + lane] = h1;
    Zly[base + lane] = f2bf(v0 - bf2f(h0));
    Zly[base + 64 + lane] = f2bf(v1 - bf2f(h1));
    float s = v0 * v0 + v1 * v1;
    for (int off = 32; off > 0; off >>= 1) s += __shfl_down(s, off, 64);
    if (lane == 0) n2y[row] = s;
  } else if (bx < 5248) {                   // wsplit
    int i4 = (bx - 5120) * 256 + tid;
    float4 v = ((const float4*)W)[i4];
    ushort4 h, lo;
    h.x = f2bf(v.x); h.y = f2bf(v.y); h.z = f2bf(v.z); h.w = f2bf(v.w);
    lo.x = f2bf(v.x - bf2f(h.x)); lo.y = f2bf(v.y - bf2f(h.y));
    lo.z = f2bf(v.z - bf2f(h.z)); lo.w = f2bf(v.w - bf2f(h.w));
    ((ushort4*)Wh)[i4] = h;
    ((ushort4*)Wl)[i4] = lo;
  } else {                                  // bprime: bp = b + cx @ W^T
    int p = bx - 5248;
    float s = 0.f;
    for (int j = tid; j < DX; j += 256) s += cx[j] * W[(size_t)p * DX + j];
    red[tid] = s; __syncthreads();
    for (int off = 128; off > 0; off >>= 1) {
      if (tid < off) red[tid] += red[tid + off];
      __syncthreads();
    }
    if (tid == 0) bp[p] = b[p] + red[0];
  }
}

// ---- shared MFMA helpers (128-row tiles, 256-thread) -----------------------
template <int STRIDE>
__device__ __forceinline__ void stage_panel(const unsigned short* __restrict__ src,
                                            int r0, int k0, short* dst, int tid) {
  #pragma unroll
  for (int c = 0; c < 4; ++c) {
    int e     = c * 256 + tid;            // 16B chunk index, 0..1023
    int row   = e >> 3;                   // 0..127
    int inrow = (e & 7) << 4;             // byte offset within 128B row
    int srcb  = inrow ^ ((row & 7) << 4); // pre-swizzled global source
    gload_lds16(src + (size_t)(r0 + row) * STRIDE + k0 + (srcb >> 1), &dst[e * 8]);
  }
}

// 512-thread variant (2 chunks/thread)
template <int STRIDE>
__device__ __forceinline__ void stage_panel2(const unsigned short* __restrict__ src,
                                             int r0, int k0, short* dst, int tid) {
  #pragma unroll
  for (int c = 0; c < 2; ++c) {
    int e     = c * 512 + tid;            // 16B chunk index, 0..1023
    int row   = e >> 3;
    int inrow = (e & 7) << 4;
    int srcb  = inrow ^ ((row & 7) << 4);
    gload_lds16(src + (size_t)(r0 + row) * STRIDE + k0 + (srcb >> 1), &dst[e * 8]);
  }
}

__device__ __forceinline__ void mfma_tiles(const short* As, const short* Bs,
                                           int wr, int wc, int l, f32x4 (&acc)[4][4]) {
  #pragma unroll
  for (int ks = 0; ks < 2; ++ks) {
    bf16x8 af[4], bfr[4];
    #pragma unroll
    for (int mi = 0; mi < 4; ++mi) {
      int row   = wr * 64 + mi * 16 + (l & 15);
      int inrow = (ks * 64 + ((l >> 4) << 4)) ^ ((row & 7) << 4);
      af[mi] = *(const bf16x8*)&As[row * 64 + (inrow >> 1)];
    }
    #pragma unroll
    for (int ni = 0; ni < 4; ++ni) {
      int row   = wc * 64 + ni * 16 + (l & 15);
      int inrow = (ks * 64 + ((l >> 4) << 4)) ^ ((row & 7) << 4);
      bfr[ni] = *(const bf16x8*)&Bs[row * 64 + (inrow >> 1)];
    }
    #pragma unroll
    for (int mi = 0; mi < 4; ++mi)
      #pragma unroll
      for (int ni = 0; ni < 4; ++ni)
        acc[mi][ni] = __builtin_amdgcn_mfma_f32_16x16x32_bf16(af[mi], bfr[ni], acc[mi][ni], 0, 0, 0);
  }
}

// 8-wave variant: wave (wr 0..1, wc 0..3) owns 64x32; acc[4][2]
__device__ __forceinline__ void mfma_tiles8(const short* As, const short* Bs,
                                            int wr, int wc, int l, f32x4 (&acc)[4][2]) {
  #pragma unroll
  for (int ks = 0; ks < 2; ++ks) {
    bf16x8 af[4], bfr[2];
    #pragma unroll
    for (int mi = 0; mi < 4; ++mi) {
      int row   = wr * 64 + mi * 16 + (l & 15);
      int inrow = (ks * 64 + ((l >> 4) << 4)) ^ ((row & 7) << 4);
      af[mi] = *(const bf16x8*)&As[row * 64 + (inrow >> 1)];
    }
    #pragma unroll
    for (int ni = 0; ni < 2; ++ni) {
      int row   = wc * 32 + ni * 16 + (l & 15);
      int inrow = (ks * 64 + ((l >> 4) << 4)) ^ ((row & 7) << 4);
      bfr[ni] = *(const bf16x8*)&Bs[row * 64 + (inrow >> 1)];
    }
    #pragma unroll
    for (int mi = 0; mi < 4; ++mi)
      #pragma unroll
      for (int ni = 0; ni < 2; ++ni)
        acc[mi][ni] = __builtin_amdgcn_mfma_f32_16x16x32_bf16(af[mi], bfr[ni], acc[mi][ni], 0, 0, 0);
  }
}

// ---- 64-row tile helpers (fallback KL pass) --------------------------------
__device__ __forceinline__ void stage64(const unsigned short* __restrict__ src,
                                        int r0, int k0, short* dst, int tid) {
  #pragma unroll
  for (int c = 0; c < 2; ++c) {
    int e     = c * 256 + tid;            // 16B chunk index, 0..511
    int row   = e >> 3;                   // 0..63  (8 chunks per 128B row)
    int inrow = (e & 7) << 4;             // byte offset within 128B row
    int srcb  = inrow ^ ((row & 7) << 4);
    gload_lds16(src + (size_t)(r0 + row) * 128 + k0 + (srcb >> 1), &dst[e * 8]);
  }
}

__device__ __forceinline__ void mfma64(const short* As, const short* Bs,
                                       int wr, int wc, int l, f32x4 (&acc)[2][2]) {
  #pragma unroll
  for (int ks = 0; ks < 2; ++ks) {
    bf16x8 af[2], bfr[2];
    #pragma unroll
    for (int mi = 0; mi < 2; ++mi) {
      int row   = wr * 32 + mi * 16 + (l & 15);
      int inrow = (ks * 64 + ((l >> 4) << 4)) ^ ((row & 7) << 4);
      af[mi] = *(const bf16x8*)&As[row * 64 + (inrow >> 1)];
    }
    #pragma unroll
    for (int ni = 0; ni < 2; ++ni) {
      int row   = wc * 32 + ni * 16 + (l & 15);
      int inrow = (ks * 64 + ((l >> 4) << 4)) ^ ((row & 7) << 4);
      bfr[ni] = *(const bf16x8*)&Bs[row * 64 + (inrow >> 1)];
    }
    #pragma unroll
    for (int mi = 0; mi < 2; ++mi)
      #pragma unroll
      for (int ni = 0; ni < 2; ++ni)
        acc[mi][ni] = __builtin_amdgcn_mfma_f32_16x16x32_bf16(af[mi], bfr[ni], acc[mi][ni], 0, 0, 0);
  }
}

// ---- proj partial GEMM: grid (32 row-tiles, 8 K-chunks), double-buffered ---
__global__ __launch_bounds__(256) void proj_part(
    const unsigned short* __restrict__ Ah, const unsigned short* __restrict__ Al,
    const unsigned short* __restrict__ Wh, const unsigned short* __restrict__ Wl,
    float* __restrict__ Pp) {
  __shared__ __align__(16) short smem[32768];   // 64 KB: 2 x (A 16KB | B 16KB)
  const int tid = threadIdx.x;
  const int l   = tid & 63, w = tid >> 6;
  const int wr  = w >> 1, wc = w & 1;
  const int r0  = blockIdx.x * 128;
  const int s   = blockIdx.y;

  auto stage_ph = [&](int t, short* h) {
    int ktg  = s * 6 + t;                  // 0..47: 3 terms x 16 K-chunks
    int term = ktg >> 4, k0 = (ktg & 15) << 6;
    const unsigned short* sA = (term < 2) ? Ah : Al;   // [hi|hi|lo]
    const unsigned short* sB = (term == 1) ? Wl : Wh;  // [hi|lo|hi]
    stage_panel<1024>(sA, r0, k0, h, tid);
    stage_panel<1024>(sB, 0, k0, h + 8192, tid);
  };

  f32x4 acc[4][4] = {};
  stage_ph(0, smem);
  asm volatile("s_waitcnt vmcnt(0)" ::: "memory");
  __syncthreads();
  for (int t = 0; t < 6; ++t) {
    short* h = smem + (t & 1) * 16384;
    if (t < 5) stage_ph(t + 1, smem + ((t + 1) & 1) * 16384);
    mfma_tiles(h, h + 8192, wr, wc, l, acc);
    asm volatile("s_waitcnt vmcnt(0)" ::: "memory");
    __syncthreads();
  }
  float* out = Pp + (size_t)s * (MM * PJ);
  #pragma unroll
  for (int mi = 0; mi < 4; ++mi)
    #pragma unroll
    for (int ni = 0; ni < 4; ++ni)
      #pragma unroll
      for (int r = 0; r < 4; ++r) {
        int i = r0 + wr * 64 + mi * 16 + ((l >> 4) << 2) + r;
        int j = wc * 64 + ni * 16 + (l & 15);
        out[(size_t)i * PJ + j] = acc[mi][ni][r];
      }
}

// ---- proj finish: sum partials + bias + split + row-norm -------------------
__global__ void proj_finish(const float* __restrict__ Pp, const float* __restrict__ bp,
                            unsigned short* __restrict__ Zh, unsigned short* __restrict__ Zl,
                            float* __restrict__ n2x) {
  int wv = threadIdx.x >> 6, lane = threadIdx.x & 63;
  int row = blockIdx.x * 4 + wv;
  size_t base = (size_t)row * 128;
  float v0 = bp[lane], v1 = bp[64 + lane];
  #pragma unroll
  for (int s = 0; s < 8; ++s) {
    v0 += Pp[(size_t)s * (MM * PJ) + base + lane];
    v1 += Pp[(size_t)s * (MM * PJ) + base + 64 + lane];
  }
  unsigned short h0 = f2bf(v0), h1 = f2bf(v1);
  Zh[base + lane] = h0;            Zh[base + 64 + lane] = h1;
  Zl[base + lane] = f2bf(v0 - bf2f(h0));
  Zl[base + 64 + lane] = f2bf(v1 - bf2f(h1));
  float s2 = v0 * v0 + v1 * v1;
  for (int off = 32; off > 0; off >>= 1) s2 += __shfl_down(s2, off, 64);
  if (lane == 0) n2x[row] = s2;
}

// ---- fused gram + hist1 + pd store (fast path, 512 threads / 8 waves) ------
// pd slab layout per (z,tile): u32[8][2048], elem (mi*2+ni)*2048 + tid*4 + r.
// Stored as one uint4 per (mi,ni): 16B/lane coalesced.
__global__ __launch_bounds__(512) void gram_hist_pd(
    const unsigned short* __restrict__ Zhx, const unsigned short* __restrict__ Zlx,
    const unsigned short* __restrict__ Zhy, const unsigned short* __restrict__ Zly,
    const float* __restrict__ n2x, const float* __restrict__ n2y,
    unsigned* __restrict__ ghx, unsigned* __restrict__ ghy,
    unsigned* __restrict__ pd) {
  __shared__ __align__(16) short smem[32768];   // 64 KB: 2 x (As 16KB | Bs 16KB)
  int bi, bj;
  tri_map(blockIdx.x, bi, bj);
  const int z = blockIdx.y;
  const unsigned short* Zh = z ? Zhy : Zhx;
  const unsigned short* Zl = z ? Zly : Zlx;
  const float* n2 = z ? n2y : n2x;
  unsigned* gh = z ? ghy : ghx;
  const int r0 = bi * 128, c0 = bj * 128;

  const int tid = threadIdx.x;                 // 0..511
  const int l   = tid & 63, w = tid >> 6;      // w 0..7
  const int wr  = w >> 2, wc = w & 3;          // wave tile: 64 rows x 32 cols

  auto stage_ph = [&](int kt, short* h) {
    const unsigned short* srcA = (kt < 4) ? Zh : Zl;
    const unsigned short* srcB = (kt < 2 || kt >= 4) ? Zh : Zl;
    const int k0 = (kt & 1) * 64;
    stage_panel2<128>(srcA, r0, k0, h, tid);
    stage_panel2<128>(srcB, c0, k0, h + 8192, tid);
  };

  f32x4 acc[4][2] = {};
  stage_ph(0, smem);
  asm volatile("s_waitcnt vmcnt(0)" ::: "memory");
  __syncthreads();
  for (int kt = 0; kt < 6; ++kt) {
    short* h = smem + (kt & 1) * 16384;
    if (kt < 5) stage_ph(kt + 1, smem + ((kt + 1) & 1) * 16384);
    mfma_tiles8(h, h + 8192, wr, wc, l, acc);
    asm volatile("s_waitcnt vmcnt(0)" ::: "memory");
    __syncthreads();
  }

  unsigned* lh = (unsigned*)smem;
  for (int t = tid; t < 8192; t += 512) lh[t] = 0u;
  __syncthreads();

  const unsigned inc = (bi == bj) ? 1u : 2u;
  unsigned* pdt = pd + ((size_t)z * NTRI128 + blockIdx.x) * 16384;

  float n2i[4][4], n2j[2];
  #pragma unroll
  for (int mi = 0; mi < 4; ++mi)
    #pragma unroll
    for (int r = 0; r < 4; ++r)
      n2i[mi][r] = n2[r0 + wr * 64 + mi * 16 + ((l >> 4) << 2) + r];
  #pragma unroll
  for (int ni = 0; ni < 2; ++ni) n2j[ni] = n2[c0 + wc * 32 + ni * 16 + (l & 15)];

  #pragma unroll
  for (int mi = 0; mi < 4; ++mi) {
    #pragma unroll
    for (int ni = 0; ni < 2; ++ni) {
      uint4 uv;
      #pragma unroll
      for (int r = 0; r < 4; ++r) {
        float pdv = n2i[mi][r] + n2j[ni] - 2.0f * acc[mi][ni][r];
        unsigned u = mapf(pdv);
        ((unsigned*)&uv)[r] = u;
        unsigned bin = u >> 20;
        atomicAdd(&lh[((bin & 2047u) << 2) | (unsigned)(l & 3)],
                  inc << ((bin >> 11) << 4));
      }
      *(uint4*)&pdt[(mi * 2 + ni) * 2048 + tid * 4] = uv;
    }
  }
  __syncthreads();
  for (int t = tid; t < 4096; t += 512) {
    unsigned idx = (unsigned)(t & 2047) << 2;
    int sh = (t >> 11) << 4;
    unsigned v = ((lh[idx]     >> sh) & 0xffffu)
               + ((lh[idx | 1] >> sh) & 0xffffu)
               + ((lh[idx | 2] >> sh) & 0xffffu)
               + ((lh[idx | 3] >> sh) & 0xffffu);
    if (v) atomicAdd(&gh[t], v);
  }
}

// ---- streaming hist2 from stored pd (fast path, uint4 loads) ---------------
// Layout-agnostic: histograms all 16384 values of the slab regardless of order.
__global__ __launch_bounds__(256) void pd_hist2(
    const unsigned* __restrict__ pd,
    const Ctrl* __restrict__ ctrlx, const Ctrl* __restrict__ ctrly,
    unsigned* __restrict__ part) {
  __shared__ unsigned lh[8192];
  const int tid = threadIdx.x, z = blockIdx.y;
  int bi, bj;
  tri_map(blockIdx.x, bi, bj);
  const Ctrl* ctrl = z ? ctrly : ctrlx;
  const unsigned p0 = ctrl->pref[0], p1 = ctrl->pref[1];
  const unsigned inc = (bi == bj) ? 1u : 2u;
  const uint4* pt = (const uint4*)(pd + ((size_t)z * NTRI128 + blockIdx.x) * 16384);
  for (int t = tid; t < 8192; t += 256) lh[t] = 0u;
  __syncthreads();
  #pragma unroll 4
  for (int it = 0; it < 16; ++it) {
    uint4 uv = pt[it * 256 + tid];
    #pragma unroll
    for (int e = 0; e < 4; ++e) {
      unsigned u = ((const unsigned*)&uv)[e];
      unsigned top = u >> 20, mid = (u >> 8) & 4095u;
      if (top == p0) atomicAdd(&lh[mid], inc);
      if (top == p1) atomicAdd(&lh[4096 + mid], inc);
    }
  }
  __syncthreads();
  unsigned* dst = part + ((size_t)z * NTRI128 + blockIdx.x) * 4096;
  for (int t = tid; t < 4096; t += 256)
    dst[t] = (lh[2 * t] & 0xffffu) | (lh[2 * t + 1] << 16);
}

// ---- streaming KL from stored pd (fast path, 512 threads, grid 528) --------
// Index map mirrors the 512-thread producer:
//   value (mi*2+ni)*2048 + tid*4 + r  <->  i = r0 + wr*64+mi*16+((l>>4)<<2)+r,
//                                          j = c0 + wc*32+ni*16+(l&15)
__global__ __launch_bounds__(512) void pd_kl(
    const unsigned* __restrict__ pdx, const unsigned* __restrict__ pdy,
    const Ctrl* __restrict__ ctrlx, const Ctrl* __restrict__ ctrly,
    double* __restrict__ colK, double* __restrict__ colL, double* __restrict__ S1) {
  __shared__ float rowKs[128], rowLs[128], colKs[128], colLs[128];
  __shared__ float red[512];
  int bi, bj;
  tri_map(blockIdx.x, bi, bj);
  const int r0 = bi * 128, c0 = bj * 128;
  const bool diag = (bi == bj);
  const int tid = threadIdx.x;
  const int l = tid & 63, w = tid >> 6;
  const int wr = w >> 2, wc = w & 3;
  const float fx = ctrlx->coef, fy = ctrly->coef;
  const uint4* ptx = (const uint4*)(pdx + (size_t)blockIdx.x * 16384);
  const uint4* pty = (const uint4*)(pdy + (size_t)blockIdx.x * 16384);
  if (tid < 128) { rowKs[tid] = 0.f; rowLs[tid] = 0.f; colKs[tid] = 0.f; colLs[tid] = 0.f; }
  __syncthreads();
  float s1 = 0.f;
  float cK[2] = {}, cL[2] = {};
  #pragma unroll
  for (int mi = 0; mi < 4; ++mi) {
    float rkK[4] = {}, rkL[4] = {};
    #pragma unroll
    for (int ni = 0; ni < 2; ++ni) {
      uint4 ux = ptx[(mi * 2 + ni) * 512 + tid];
      uint4 uy = pty[(mi * 2 + ni) * 512 + tid];
      #pragma unroll
      for (int r = 0; r < 4; ++r) {
        float Kv = exp2f(unmapf(((const unsigned*)&ux)[r]) * fx);
        float Lv = exp2f(unmapf(((const unsigned*)&uy)[r]) * fy);
        s1 += Kv * Lv;
        rkK[r] += Kv; rkL[r] += Lv;
        cK[ni] += Kv; cL[ni] += Lv;
      }
    }
    #pragma unroll
    for (int r = 0; r < 4; ++r) {
      int il = wr * 64 + mi * 16 + ((l >> 4) << 2) + r;
      float rk = rkK[r], rl = rkL[r];
      rk += __shfl_xor(rk, 1); rk += __shfl_xor(rk, 2);
      rk += __shfl_xor(rk, 4); rk += __shfl_xor(rk, 8);
      rl += __shfl_xor(rl, 1); rl += __shfl_xor(rl, 2);
      rl += __shfl_xor(rl, 4); rl += __shfl_xor(rl, 8);
      if ((l & 15) == 0) {
        atomicAdd(&rowKs[il], rk);
        atomicAdd(&rowLs[il], rl);
      }
    }
  }
  #pragma unroll
  for (int ni = 0; ni < 2; ++ni) {
    float ck = cK[ni], cl = cL[ni];
    ck += __shfl_xor(ck, 16); ck += __shfl_xor(ck, 32);
    cl += __shfl_xor(cl, 16); cl += __shfl_xor(cl, 32);
    if (l < 16) {
      int jl = wc * 32 + ni * 16 + l;
      atomicAdd(&colKs[jl], ck);
      atomicAdd(&colLs[jl], cl);
    }
  }
  red[tid] = s1;
  __syncthreads();
  for (int off = 256; off > 0; off >>= 1) {
    if (tid < off) red[tid] += red[tid + off];
    __syncthreads();
  }
  if (tid == 0) atomicAdd(S1, (double)red[0] * (diag ? 1.0 : 2.0));
  if (tid < 128) {
    atomicAdd(&colK[c0 + tid], (double)colKs[tid]);
    atomicAdd(&colL[c0 + tid], (double)colLs[tid]);
    if (!diag) {
      atomicAdd(&colK[r0 + tid], (double)rowKs[tid]);
      atomicAdd(&colL[r0 + tid], (double)rowLs[tid]);
    }
  }
}

// ---- gram hist passes (fallback path) --------------------------------------
template <int MODE>
__global__ __launch_bounds__(256) void gram_hist(
    const unsigned short* __restrict__ Zhx, const unsigned short* __restrict__ Zlx,
    const unsigned short* __restrict__ Zhy, const unsigned short* __restrict__ Zly,
    const float* __restrict__ n2x, const float* __restrict__ n2y,
    const Ctrl* __restrict__ ctrlx, const Ctrl* __restrict__ ctrly,
    unsigned* __restrict__ ghx, unsigned* __restrict__ ghy,
    unsigned* __restrict__ part) {
  __shared__ __align__(16) short smem[32768];
  int bi, bj;
  tri_map(blockIdx.x, bi, bj);
  const int z = blockIdx.y;
  const unsigned short* Zh = z ? Zhy : Zhx;
  const unsigned short* Zl = z ? Zly : Zlx;
  const float* n2 = z ? n2y : n2x;
  const Ctrl* ctrl = z ? ctrly : ctrlx;
  unsigned* gh = z ? ghy : ghx;
  const int r0 = bi * 128, c0 = bj * 128;

  const int tid = threadIdx.x;
  const int l   = tid & 63, w = tid >> 6;
  const int wr  = w >> 1, wc = w & 1;

  auto stage_ph = [&](int kt, short* h) {
    const unsigned short* srcA = (kt < 4) ? Zh : Zl;
    const unsigned short* srcB = (kt < 2 || kt >= 4) ? Zh : Zl;
    const int k0 = (kt & 1) * 64;
    stage_panel<128>(srcA, r0, k0, h, tid);
    stage_panel<128>(srcB, c0, k0, h + 8192, tid);
  };

  f32x4 acc[4][4] = {};
  stage_ph(0, smem);
  asm volatile("s_waitcnt vmcnt(0)" ::: "memory");
  __syncthreads();
  for (int kt = 0; kt < 6; ++kt) {
    short* h = smem + (kt & 1) * 16384;
    if (kt < 5) stage_ph(kt + 1, smem + ((kt + 1) & 1) * 16384);
    mfma_tiles(h, h + 8192, wr, wc, l, acc);
    asm volatile("s_waitcnt vmcnt(0)" ::: "memory");
    __syncthreads();
  }

  unsigned* lh = (unsigned*)smem;
  for (int t = tid; t < 8192; t += 256) lh[t] = 0u;
  __syncthreads();

  unsigned p0 = 0, p1 = 0;
  if constexpr (MODE == 2) { p0 = ctrl->pref[0]; p1 = ctrl->pref[1]; }
  const unsigned inc = (bi == bj) ? 1u : 2u;

  float n2i[4][4], n2j[4];
  #pragma unroll
  for (int mi = 0; mi < 4; ++mi)
    #pragma unroll
    for (int r = 0; r < 4; ++r)
      n2i[mi][r] = n2[r0 + wr * 64 + mi * 16 + ((l >> 4) << 2) + r];
  #pragma unroll
  for (int ni = 0; ni < 4; ++ni) n2j[ni] = n2[c0 + wc * 64 + ni * 16 + (l & 15)];

  #pragma unroll
  for (int mi = 0; mi < 4; ++mi) {
    #pragma unroll
    for (int ni = 0; ni < 4; ++ni) {
      #pragma unroll
      for (int r = 0; r < 4; ++r) {
        float pdv = n2i[mi][r] + n2j[ni] - 2.0f * acc[mi][ni][r];
        unsigned u = mapf(pdv);
        if constexpr (MODE == 1) {
          unsigned bin = u >> 20;
          atomicAdd(&lh[((bin & 2047u) << 2) | (unsigned)(l & 3)],
                    inc << ((bin >> 11) << 4));
        } else {
          unsigned top = u >> 20, mid = (u >> 8) & 4095u;
          if (top == p0) atomicAdd(&lh[mid], inc);
          if (top == p1) atomicAdd(&lh[4096 + mid], inc);
        }
      }
    }
  }
  __syncthreads();
  if constexpr (MODE == 1) {
    for (int t = tid; t < 4096; t += 256) {
      unsigned idx = (unsigned)(t & 2047) << 2;
      int sh = (t >> 11) << 4;
      unsigned v = ((lh[idx]     >> sh) & 0xffffu)
                 + ((lh[idx | 1] >> sh) & 0xffffu)
                 + ((lh[idx | 2] >> sh) & 0xffffu)
                 + ((lh[idx | 3] >> sh) & 0xffffu);
      if (v) atomicAdd(&gh[t], v);
    }
  } else {
    unsigned* dst = part + ((size_t)z * NTRI128 + blockIdx.x) * 4096;
    for (int t = tid; t < 4096; t += 256)
      dst[t] = (lh[2 * t] & 0xffffu) | (lh[2 * t + 1] << 16);
  }
}

// ---- sum the per-block MODE-2 histograms -----------------------------------
__global__ void hist2_reduce(const unsigned* __restrict__ part,
                             unsigned* __restrict__ ghx, unsigned* __restrict__ ghy) {
  const int t = blockIdx.x * 256 + threadIdx.x;   // 0..4095: u32 pair index
  const int z = blockIdx.y;
  const int b0 = blockIdx.z * 66;
  const int nb = (b0 + 66 <= NTRI128) ? 66 : (NTRI128 - b0);
  const unsigned* p = part + ((size_t)z * NTRI128 + b0) * 4096;
  unsigned s0 = 0, s1 = 0;
  for (int b = 0; b < nb; ++b) {
    unsigned v = p[(size_t)b * 4096 + t];
    s0 += v & 0xffffu;
    s1 += v >> 16;
  }
  unsigned* gh = z ? ghy : ghx;
  if (s0) atomicAdd(&gh[2 * t], s0);
  if (s1) atomicAdd(&gh[2 * t + 1], s1);
}

// ---- KL pass (fallback path, round-8 single-buffer 64^2 version) -----------
__global__ __launch_bounds__(256) void gram_kl(
    const unsigned short* __restrict__ Zhx, const unsigned short* __restrict__ Zlx,
    const unsigned short* __restrict__ Zhy, const unsigned short* __restrict__ Zly,
    const float* __restrict__ n2x, const float* __restrict__ n2y,
    const Ctrl* __restrict__ ctrlx, const Ctrl* __restrict__ ctrly,
    double* __restrict__ colK, double* __restrict__ colL, double* __restrict__ S1) {
  __shared__ __align__(16) short smem[8192];   // 16 KB: As(64x64) | Bs(64x64)
  int bi, bj;
  tri_map(blockIdx.x, bi, bj);
  const int r0 = bi * 64, c0 = bj * 64;
  const bool diag = (bi == bj);
  const int tid = threadIdx.x;
  const int l   = tid & 63, w = tid >> 6;
  const int wr  = w >> 1, wc = w & 1;
  short* As = smem;
  short* Bs = smem + 4096;

  f32x4 accx[2][2] = {};
  f32x4 accy[2][2] = {};
  #pragma unroll
  for (int m = 0; m < 2; ++m) {
    const unsigned short* Zh = m ? Zhy : Zhx;
    const unsigned short* Zl = m ? Zly : Zlx;
    for (int kt = 0; kt < 6; ++kt) {
      const unsigned short* sA = (kt < 4) ? Zh : Zl;
      const unsigned short* sB = (kt < 2 || kt >= 4) ? Zh : Zl;
      const int k0 = (kt & 1) * 64;
      stage64(sA, r0, k0, As, tid);
      stage64(sB, c0, k0, Bs, tid);
      asm volatile("s_waitcnt vmcnt(0)" ::: "memory");
      __syncthreads();
      if (m == 0) mfma64(As, Bs, wr, wc, l, accx);
      else        mfma64(As, Bs, wr, wc, l, accy);
      __syncthreads();
    }
  }

  float* rowKs = (float*)smem;
  float* rowLs = rowKs + 64;
  float* colKs = rowLs + 64;
  float* colLs = colKs + 64;
  float* red   = colLs + 64;
  ((float*)smem)[tid] = 0.f;
  __syncthreads();

  const float fx = ctrlx->coef, fy = ctrly->coef;
  float s1 = 0.f;
  float cK[2] = {0.f, 0.f}, cL[2] = {0.f, 0.f};
  #pragma unroll
  for (int mi = 0; mi < 2; ++mi) {
    #pragma unroll
    for (int r = 0; r < 4; ++r) {
      int il = wr * 32 + mi * 16 + ((l >> 4) << 2) + r;
      int i  = r0 + il;
      float rk = 0.f, rl = 0.f;
      #pragma unroll
      for (int ni = 0; ni < 2; ++ni) {
        int j = c0 + wc * 32 + ni * 16 + (l & 15);
        float Kv = exp2f((n2x[i] + n2x[j] - 2.0f * accx[mi][ni][r]) * fx);
        float Lv = exp2f((n2y[i] + n2y[j] - 2.0f * accy[mi][ni][r]) * fy);
        s1 += Kv * Lv;
        rk += Kv; rl += Lv;
        cK[ni] += Kv; cL[ni] += Lv;
      }
      rk += __shfl_xor(rk, 1); rk += __shfl_xor(rk, 2);
      rk += __shfl_xor(rk, 4); rk += __shfl_xor(rk, 8);
      rl += __shfl_xor(rl, 1); rl += __shfl_xor(rl, 2);
      rl += __shfl_xor(rl, 4); rl += __shfl_xor(rl, 8);
      if ((l & 15) == 0) {
        atomicAdd(&rowKs[il], rk);
        atomicAdd(&rowLs[il], rl);
      }
    }
  }
  #pragma unroll
  for (int ni = 0; ni < 2; ++ni) {
    float ck = cK[ni], cl = cL[ni];
    ck += __shfl_xor(ck, 16); ck += __shfl_xor(ck, 32);
    cl += __shfl_xor(cl, 16); cl += __shfl_xor(cl, 32);
    if (l < 16) {
      int jl = wc * 32 + ni * 16 + l;
      atomicAdd(&colKs[jl], ck);
      atomicAdd(&colLs[jl], cl);
    }
  }
  red[tid] = s1;
  __syncthreads();
  for (int off = 128; off > 0; off >>= 1) {
    if (tid < off) red[tid] += red[tid + off];
    __syncthreads();
  }
  if (tid == 0) atomicAdd(S1, (double)red[0] * (diag ? 1.0 : 2.0));
  if (tid < 64) {
    atomicAdd(&colK[c0 + tid], (double)colKs[tid]);
    atomicAdd(&colL[c0 + tid], (double)colLs[tid]);
    if (!diag) {
      atomicAdd(&colK[r0 + tid], (double)rowKs[tid]);
      atomicAdd(&colL[r0 + tid], (double)rowLs[tid]);
    }
  }
}

// ---- radix-select scan: grid(2) = one block per matrix ---------------------
// level 1: ONE scan locates both RANK0 and RANK1 (same histogram).
// level 2: two scans (q=0,1) over the refine histograms; tid0 computes sigma.
template <int SEG>
__global__ void scan_select(const unsigned* __restrict__ hxa, const unsigned* __restrict__ hya,
                            int qstride, Ctrl* ctrlx, Ctrl* ctrly, int level) {
  __shared__ unsigned part[256];
  __shared__ unsigned s_bin[2];
  const int tid = threadIdx.x;
  const int m = blockIdx.x;
  const unsigned* hbase = m ? hya : hxa;
  Ctrl* ctrl = m ? ctrly : ctrlx;
  const int nq = (level == 1) ? 1 : 2;
  for (int q = 0; q < nq; ++q) {
    const unsigned* h = hbase + q * qstride;
    unsigned loc[SEG];
    unsigned s = 0;
    #pragma unroll
    for (int b = 0; b < SEG; ++b) { loc[b] = h[tid * SEG + b]; s += loc[b]; }
    part[tid] = s; __syncthreads();
    for (int off = 1; off < 256; off <<= 1) {
      unsigned t = (tid >= off) ? part[tid - off] : 0u;
      __syncthreads();
      part[tid] += t;
      __syncthreads();
    }
    unsigned pre = part[tid] - s;
    if (level == 1) {
      #pragma unroll
      for (int qq = 0; qq < 2; ++qq) {
        unsigned rank = qq ? RANK1 : RANK0;
        if (rank >= pre && rank < pre + s) {
          unsigned cum = pre;
          #pragma unroll
          for (int b = 0; b < SEG; ++b) {
            if (rank < cum + loc[b]) {
              s_bin[qq] = tid * SEG + b;
              ctrl->rrank[qq] = rank - cum;
              break;
            }
            cum += loc[b];
          }
        }
      }
    } else {
      unsigned rank = ctrl->rrank[q];
      if (rank >= pre && rank < pre + s) {
        unsigned cum = pre;
        #pragma unroll
        for (int b = 0; b < SEG; ++b) {
          if (rank < cum + loc[b]) {
            s_bin[q] = tid * SEG + b;
            break;
          }
          cum += loc[b];
        }
      }
    }
    __syncthreads();
  }
  if (level == 1) {
    if (tid < 2) ctrl->pref[tid] = s_bin[tid];
  } else if (tid == 0) {
    unsigned u0 = (((ctrl->pref[0] << 12) | s_bin[0]) << 8) + 128u;
    unsigned u1 = (((ctrl->pref[1] << 12) | s_bin[1]) << 8) + 128u;
    float med = 0.5f * (unmapf(u0) + unmapf(u1));
    float sig = fmaxf(1e-6f, med);
    ctrl->sigma = sig;
    ctrl->coef  = -1.4426950408889634f / sig;
  }
}

// ---- final combine ---------------------------------------------------------
__global__ void finalize_hsic(const double* __restrict__ colK, const double* __restrict__ colL,
                              const double* __restrict__ S1, float* __restrict__ out) {
  __shared__ double rk[256], rl[256], rkl[256];
  double tk = 0.0, tl = 0.0, tkl = 0.0;
  for (int i = threadIdx.x; i < MM; i += 256) {
    double k = colK[i], l = colL[i];
    tk += k; tl += l; tkl += k * l;
  }
  rk[threadIdx.x] = tk; rl[threadIdx.x] = tl; rkl[threadIdx.x] = tkl;
  __syncthreads();
  for (int off = 128; off > 0; off >>= 1) {
    if (threadIdx.x < off) {
      rk[threadIdx.x]  += rk[threadIdx.x + off];
      rl[threadIdx.x]  += rl[threadIdx.x + off];
      rkl[threadIdx.x] += rkl[threadIdx.x + off];
    }
    __syncthreads();
  }
  if (threadIdx.x == 0) {
    double m = 4096.0;
    double s = S1[0] - (2.0 / m) * rkl[0] + rk[0] * rl[0] / (m * m);
    out[0] = (float)(s / (4095.0 * 4095.0));
  }
}

// ---------------------------------------------------------------------------
extern "C" void kernel_launch(void* const* d_in, const int* in_sizes, int n_in,
                              void* d_out, int out_size, void* d_ws, size_t ws_size,
                              hipStream_t stream) {
  const float* x   = (const float*)d_in[0];
  const float* y   = (const float*)d_in[1];
  const float* bxg = (const float*)d_in[2];
  const float* bxb = (const float*)d_in[3];
  const float* byg = (const float*)d_in[4];
  const float* byb = (const float*)d_in[5];
  const float* W   = (const float*)d_in[6];
  const float* b   = (const float*)d_in[7];
  float* out = (float*)d_out;

  char* w = (char*)d_ws;
  unsigned short* Ah  = (unsigned short*)(w);                   // 8 MB
  unsigned short* Al  = (unsigned short*)(w + 8388608ull);      // 8 MB
  unsigned short* Wh  = (unsigned short*)(w + 16777216ull);     // 256 KB
  unsigned short* Wl  = (unsigned short*)(w + 17039360ull);     // 256 KB
  unsigned short* Zhx = (unsigned short*)(w + 17301504ull);     // 1 MB each
  unsigned short* Zlx = (unsigned short*)(w + 18350080ull);
  unsigned short* Zhy = (unsigned short*)(w + 19398656ull);
  unsigned short* Zly = (unsigned short*)(w + 20447232ull);
  float*          Pp  = (float*)(w + 21495808ull);              // 8 x 2 MB
  // MODE-2 per-block hist slices overlay dead Ah/Al/Wh/Wl: 17,301,504 B.
  unsigned*       part = (unsigned*)(w);
  size_t ZR = 21495808ull + 16777216ull;
  double*   sumx = (double*)(w + ZR);
  double*   sqx  = sumx + 1024;
  double*   sumy = sqx + 1024;
  double*   sqy  = sumy + 128;
  unsigned* h1x  = (unsigned*)(sqy + 128);
  unsigned* h1y  = h1x + 4096;
  unsigned* h2x  = h1y + 4096;
  unsigned* h2y  = h2x + 8192;
  double*   colK = (double*)(h2y + 8192);
  double*   colL = colK + 4096;
  double*   S1   = colL + 4096;
  size_t zero_bytes = (size_t)((char*)(S1 + 1) - (w + ZR));
  size_t PR = ZR + ((zero_bytes + 255ull) & ~255ull);
  float* ax  = (float*)(w + PR);
  float* cx  = ax + 1024;
  float* ay  = cx + 1024;
  float* cy  = ay + 128;
  float* bp  = cy + 128;
  float* n2x = bp + 128;
  float* n2y = n2x + 4096;
  Ctrl* ctrlx = (Ctrl*)(n2y + 4096);
  Ctrl* ctrly = ctrlx + 1;

  // pd store (fast path): u32[2][528][16384] at 40 MiB
  constexpr size_t PD0     = 41943040ull;
  constexpr size_t PD_ELEM = (size_t)NTRI128 * 16384;            // per z
  constexpr size_t WS_FAST = PD0 + 2ull * PD_ELEM * 4ull;        // 111,149,056
  unsigned* pdx = (unsigned*)(w + PD0);
  unsigned* pdy = pdx + PD_ELEM;
  const bool fast = (ws_size >= WS_FAST);

  // zero the accumulator region with our own kernel (hipMemsetAsync's
  // fillBufferAligned measured ~39.5 us/iter at 8% occupancy for 180 KB).
  // Rounding into the 256B alignment pad is safe: [ZR+zero_bytes, PR) is
  // dead until finalize_stats overwrites ax/cx/ay/cy.
  int n16 = (int)((zero_bytes + 15) >> 4);
  zero_ws<<<(n16 + 255) / 256, 256, 0, stream>>>((uint4*)(w + ZR), n16);

  colstats<<<dim3(5, 16), 256, 0, stream>>>(x, y, sumx, sqx, sumy, sqy);
  finalize_stats<<<5, 256, 0, stream>>>(sumx, sqx, sumy, sqy, bxg, bxb, byg, byb,
                                        ax, cx, ay, cy);
  prep<<<5376, 256, 0, stream>>>(x, y, W, b, ax, cx, ay, cy,
                                 Ah, Al, Wh, Wl, Zhy, Zly, n2y, bp);
  proj_part<<<dim3(32, 8), 256, 0, stream>>>(Ah, Al, Wh, Wl, Pp);
  proj_finish<<<1024, 256, 0, stream>>>(Pp, bp, Zhx, Zlx, n2x);

  if (fast) {
    gram_hist_pd<<<dim3(NTRI128, 2), 512, 0, stream>>>(Zhx, Zlx, Zhy, Zly, n2x, n2y,
                                                       h1x, h1y, pdx);
    scan_select<16><<<2, 256, 0, stream>>>(h1x, h1y, 0, ctrlx, ctrly, 1);
    pd_hist2<<<dim3(NTRI128, 2), 256, 0, stream>>>(pdx, ctrlx, ctrly, part);
    hist2_reduce<<<dim3(16, 2, 8), 256, 0, stream>>>(part, h2x, h2y);
    scan_select<16><<<2, 256, 0, stream>>>(h2x, h2y, 4096, ctrlx, ctrly, 2);
    pd_kl<<<NTRI128, 512, 0, stream>>>(pdx, pdy, ctrlx, ctrly,
                                       colK, colL, S1);
  } else {
    gram_hist<1><<<dim3(NTRI128, 2), 256, 0, stream>>>(Zhx, Zlx, Zhy, Zly, n2x, n2y,
                                                       ctrlx, ctrly, h1x, h1y, part);
    scan_select<16><<<2, 256, 0, stream>>>(h1x, h1y, 0, ctrlx, ctrly, 1);
    gram_hist<2><<<dim3(NTRI128, 2), 256, 0, stream>>>(Zhx, Zlx, Zhy, Zly, n2x, n2y,
                                                       ctrlx, ctrly, h2x, h2y, part);
    hist2_reduce<<<dim3(16, 2, 8), 256, 0, stream>>>(part, h2x, h2y);
    scan_select<16><<<2, 256, 0, stream>>>(h2x, h2y, 4096, ctrlx, ctrly, 2);
    gram_kl<<<NTRI64, 256, 0, stream>>>(Zhx, Zlx, Zhy, Zly, n2x, n2y,
                                        ctrlx, ctrly, colK, colL, S1);
  }
  finalize_hsic<<<1, 256, 0, stream>>>(colK, colL, S1, out);
}

// Round 10
// 148.690 us; speedup vs baseline: 1.1508x; 1.0104x over previous
//
#include <hip/hip_runtime.h>

// ---------------------------------------------------------------------------
// HSIC feature-extraction pipeline, M=4096, DIM_X=1024, DIM_Y=PROJ=128
// Round 16 (base = round-15, 150.2 us measured):
//   - gram_hist_pd: 32 KB single-buffer staging + __launch_bounds__(512,6).
//     At 88 VGPR / 64 KB LDS the kernel sat at 2 blocks/CU (16 waves); 32 KB
//     LDS + VGPR<=85 allows 3 blocks/CU (24 waves, +50% TLP) -- the proven
//     lever for this latency-bound kernel (r8/r14), inverse of the r9 trap.
//   - note: recurring 39.5-us fillBufferAligned dispatches are the HARNESS
//     re-poisoning the 256 MiB workspace at 85% HBM peak (roofline, fixed).
// ---------------------------------------------------------------------------

constexpr int   MM  = 4096;
constexpr int   DX  = 1024;
constexpr int   DY  = 128;
constexpr int   PJ  = 128;
constexpr unsigned RANK0 = 8388607u;           // median ranks (even count)
constexpr unsigned RANK1 = 8388608u;
constexpr int   NTRI128 = 528;                 // 32*33/2 tiles (128^2)
constexpr int   NTRI64  = 2080;                // 64*65/2 tiles (64^2)

typedef __attribute__((ext_vector_type(8))) short bf16x8;
typedef __attribute__((ext_vector_type(4))) float f32x4;

struct Ctrl {
  unsigned pref[2];
  unsigned rrank[2];
  float sigma;
  float coef;      // -log2(e)/sigma
};

__device__ __forceinline__ unsigned mapf(float f) {
  unsigned b = __float_as_uint(f);
  return (b & 0x80000000u) ? ~b : (b | 0x80000000u);
}
__device__ __forceinline__ float unmapf(unsigned u) {
  unsigned b = (u & 0x80000000u) ? (u & 0x7fffffffu) : ~u;
  return __uint_as_float(b);
}
__device__ __forceinline__ unsigned short f2bf(float f) {
  unsigned u = __float_as_uint(f);
  return (unsigned short)((u + 0x7fffu + ((u >> 16) & 1u)) >> 16);
}
__device__ __forceinline__ float bf2f(unsigned short h) {
  return __uint_as_float(((unsigned)h) << 16);
}
__device__ __forceinline__ void gload_lds16(const void* g, void* l) {
  __builtin_amdgcn_global_load_lds(
      (const __attribute__((address_space(1))) unsigned int*)g,
      (__attribute__((address_space(3))) unsigned int*)l, 16, 0, 0);
}
__device__ __forceinline__ void tri_map(int lin, int& bi, int& bj) {
  int b = (int)((sqrtf(8.0f * (float)lin + 1.0f) - 1.0f) * 0.5f);
  while ((b + 1) * (b + 2) / 2 <= lin) ++b;
  while (b * (b + 1) / 2 > lin) --b;
  bi = b;
  bj = lin - b * (b + 1) / 2;
}

// ---- workspace zeroing (replaces pathological hipMemsetAsync fill) ---------
__global__ void zero_ws(uint4* __restrict__ dst, int n16) {
  int i = blockIdx.x * 256 + threadIdx.x;
  if (i < n16) dst[i] = uint4{0u, 0u, 0u, 0u};
}

// ---- column stats (merged x and y) -----------------------------------------
__global__ void colstats(const float* __restrict__ x, const float* __restrict__ y,
                         double* __restrict__ sumx, double* __restrict__ sqx,
                         double* __restrict__ sumy, double* __restrict__ sqy) {
  const int r0 = blockIdx.y * 256;
  const float* src;
  double *sum, *sq;
  int col, ncols;
  if (blockIdx.x < 4) {
    col = blockIdx.x * 256 + threadIdx.x; ncols = DX; src = x; sum = sumx; sq = sqx;
  } else {
    col = threadIdx.x; ncols = DY; src = y; sum = sumy; sq = sqy;
    if (col >= DY) return;
  }
  const float* px = src + (size_t)r0 * ncols + col;
  double s = 0.0, s2 = 0.0;
  for (int r = 0; r < 256; ++r) {
    float v = *px;
    s  += (double)v;
    s2 += (double)v * (double)v;
    px += ncols;
  }
  atomicAdd(&sum[col], s);
  atomicAdd(&sq[col],  s2);
}

__global__ void finalize_stats(const double* __restrict__ sumx, const double* __restrict__ sqx,
                               const double* __restrict__ sumy, const double* __restrict__ sqy,
                               const float* __restrict__ gx, const float* __restrict__ bx,
                               const float* __restrict__ gy, const float* __restrict__ by,
                               float* __restrict__ axv, float* __restrict__ cxv,
                               float* __restrict__ ayv, float* __restrict__ cyv) {
  const double* sum; const double* sq; const float* gamma; const float* beta;
  float *a, *c; int j;
  if (blockIdx.x < 4) {
    j = blockIdx.x * 256 + threadIdx.x;
    sum = sumx; sq = sqx; gamma = gx; beta = bx; a = axv; c = cxv;
  } else {
    j = threadIdx.x;
    if (j >= DY) return;
    sum = sumy; sq = sqy; gamma = gy; beta = by; a = ayv; c = cyv;
  }
  double mu  = sum[j] * (1.0 / 4096.0);
  double var = sq[j] * (1.0 / 4096.0) - mu * mu;
  float rstd = (float)(1.0 / sqrt(var + 1e-5));
  float aj   = rstd * gamma[j];
  a[j] = aj;
  c[j] = beta[j] - (float)mu * aj;
}

// ---- merged prep: xsplit | ysplit | wsplit | bprime ------------------------
__global__ __launch_bounds__(256) void prep(
    const float* __restrict__ x, const float* __restrict__ y,
    const float* __restrict__ W, const float* __restrict__ b,
    const float* __restrict__ ax, const float* __restrict__ cx,
    const float* __restrict__ ay, const float* __restrict__ cy,
    unsigned short* __restrict__ Ah, unsigned short* __restrict__ Al,
    unsigned short* __restrict__ Wh, unsigned short* __restrict__ Wl,
    unsigned short* __restrict__ Zhy, unsigned short* __restrict__ Zly,
    float* __restrict__ n2y, float* __restrict__ bp) {
  __shared__ float red[256];
  const int bx = blockIdx.x, tid = threadIdx.x;
  if (bx < 4096) {                          // xsplit: xn = x*ax -> bf16 hi/lo
    int i4 = bx * 256 + tid;
    float4 v = ((const float4*)x)[i4];
    int c0 = (i4 * 4) & 1023;
    v.x *= ax[c0]; v.y *= ax[c0 + 1]; v.z *= ax[c0 + 2]; v.w *= ax[c0 + 3];
    ushort4 h, lo;
    h.x = f2bf(v.x); h.y = f2bf(v.y); h.z = f2bf(v.z); h.w = f2bf(v.w);
    lo.x = f2bf(v.x - bf2f(h.x)); lo.y = f2bf(v.y - bf2f(h.y));
    lo.z = f2bf(v.z - bf2f(h.z)); lo.w = f2bf(v.w - bf2f(h.w));
    ((ushort4*)Ah)[i4] = h;
    ((ushort4*)Al)[i4] = lo;
  } else if (bx < 5120) {                   // ysplit + row-norm
    int wv = tid >> 6, lane = tid & 63;
    int row = (bx - 4096) * 4 + wv;
    size_t base = (size_t)row * 128;
    float v0 = y[base + lane]      * ay[lane]      + cy[lane];
    float v1 = y[base + 64 + lane] * ay[64 + lane] + cy[64 + lane];
    unsigned short h0 = f2bf(v0), h1 = f2bf(v1);
    Zhy[base + lane] = h0;            Zhy[base + 64 + lane] = h1;
    Zly[base + lane] = f2bf(v0 - bf2f(h0));
    Zly[base + 64 + lane] = f2bf(v1 - bf2f(h1));
    float s = v0 * v0 + v1 * v1;
    for (int off = 32; off > 0; off >>= 1) s += __shfl_down(s, off, 64);
    if (lane == 0) n2y[row] = s;
  } else if (bx < 5248) {                   // wsplit
    int i4 = (bx - 5120) * 256 + tid;
    float4 v = ((const float4*)W)[i4];
    ushort4 h, lo;
    h.x = f2bf(v.x); h.y = f2bf(v.y); h.z = f2bf(v.z); h.w = f2bf(v.w);
    lo.x = f2bf(v.x - bf2f(h.x)); lo.y = f2bf(v.y - bf2f(h.y));
    lo.z = f2bf(v.z - bf2f(h.z)); lo.w = f2bf(v.w - bf2f(h.w));
    ((ushort4*)Wh)[i4] = h;
    ((ushort4*)Wl)[i4] = lo;
  } else {                                  // bprime: bp = b + cx @ W^T
    int p = bx - 5248;
    float s = 0.f;
    for (int j = tid; j < DX; j += 256) s += cx[j] * W[(size_t)p * DX + j];
    red[tid] = s; __syncthreads();
    for (int off = 128; off > 0; off >>= 1) {
      if (tid < off) red[tid] += red[tid + off];
      __syncthreads();
    }
    if (tid == 0) bp[p] = b[p] + red[0];
  }
}

// ---- shared MFMA helpers (128-row tiles, 256-thread) -----------------------
template <int STRIDE>
__device__ __forceinline__ void stage_panel(const unsigned short* __restrict__ src,
                                            int r0, int k0, short* dst, int tid) {
  #pragma unroll
  for (int c = 0; c < 4; ++c) {
    int e     = c * 256 + tid;            // 16B chunk index, 0..1023
    int row   = e >> 3;                   // 0..127
    int inrow = (e & 7) << 4;             // byte offset within 128B row
    int srcb  = inrow ^ ((row & 7) << 4); // pre-swizzled global source
    gload_lds16(src + (size_t)(r0 + row) * STRIDE + k0 + (srcb >> 1), &dst[e * 8]);
  }
}

// 512-thread variant (2 chunks/thread)
template <int STRIDE>
__device__ __forceinline__ void stage_panel2(const unsigned short* __restrict__ src,
                                             int r0, int k0, short* dst, int tid) {
  #pragma unroll
  for (int c = 0; c < 2; ++c) {
    int e     = c * 512 + tid;            // 16B chunk index, 0..1023
    int row   = e >> 3;
    int inrow = (e & 7) << 4;
    int srcb  = inrow ^ ((row & 7) << 4);
    gload_lds16(src + (size_t)(r0 + row) * STRIDE + k0 + (srcb >> 1), &dst[e * 8]);
  }
}

__device__ __forceinline__ void mfma_tiles(const short* As, const short* Bs,
                                           int wr, int wc, int l, f32x4 (&acc)[4][4]) {
  #pragma unroll
  for (int ks = 0; ks < 2; ++ks) {
    bf16x8 af[4], bfr[4];
    #pragma unroll
    for (int mi = 0; mi < 4; ++mi) {
      int row   = wr * 64 + mi * 16 + (l & 15);
      int inrow = (ks * 64 + ((l >> 4) << 4)) ^ ((row & 7) << 4);
      af[mi] = *(const bf16x8*)&As[row * 64 + (inrow >> 1)];
    }
    #pragma unroll
    for (int ni = 0; ni < 4; ++ni) {
      int row   = wc * 64 + ni * 16 + (l & 15);
      int inrow = (ks * 64 + ((l >> 4) << 4)) ^ ((row & 7) << 4);
      bfr[ni] = *(const bf16x8*)&Bs[row * 64 + (inrow >> 1)];
    }
    #pragma unroll
    for (int mi = 0; mi < 4; ++mi)
      #pragma unroll
      for (int ni = 0; ni < 4; ++ni)
        acc[mi][ni] = __builtin_amdgcn_mfma_f32_16x16x32_bf16(af[mi], bfr[ni], acc[mi][ni], 0, 0, 0);
  }
}

// 8-wave variant: wave (wr 0..1, wc 0..3) owns 64x32; acc[4][2]
__device__ __forceinline__ void mfma_tiles8(const short* As, const short* Bs,
                                            int wr, int wc, int l, f32x4 (&acc)[4][2]) {
  #pragma unroll
  for (int ks = 0; ks < 2; ++ks) {
    bf16x8 af[4], bfr[2];
    #pragma unroll
    for (int mi = 0; mi < 4; ++mi) {
      int row   = wr * 64 + mi * 16 + (l & 15);
      int inrow = (ks * 64 + ((l >> 4) << 4)) ^ ((row & 7) << 4);
      af[mi] = *(const bf16x8*)&As[row * 64 + (inrow >> 1)];
    }
    #pragma unroll
    for (int ni = 0; ni < 2; ++ni) {
      int row   = wc * 32 + ni * 16 + (l & 15);
      int inrow = (ks * 64 + ((l >> 4) << 4)) ^ ((row & 7) << 4);
      bfr[ni] = *(const bf16x8*)&Bs[row * 64 + (inrow >> 1)];
    }
    #pragma unroll
    for (int mi = 0; mi < 4; ++mi)
      #pragma unroll
      for (int ni = 0; ni < 2; ++ni)
        acc[mi][ni] = __builtin_amdgcn_mfma_f32_16x16x32_bf16(af[mi], bfr[ni], acc[mi][ni], 0, 0, 0);
  }
}

// ---- 64-row tile helpers (fallback KL pass) --------------------------------
__device__ __forceinline__ void stage64(const unsigned short* __restrict__ src,
                                        int r0, int k0, short* dst, int tid) {
  #pragma unroll
  for (int c = 0; c < 2; ++c) {
    int e     = c * 256 + tid;            // 16B chunk index, 0..511
    int row   = e >> 3;                   // 0..63  (8 chunks per 128B row)
    int inrow = (e & 7) << 4;             // byte offset within 128B row
    int srcb  = inrow ^ ((row & 7) << 4);
    gload_lds16(src + (size_t)(r0 + row) * 128 + k0 + (srcb >> 1), &dst[e * 8]);
  }
}

__device__ __forceinline__ void mfma64(const short* As, const short* Bs,
                                       int wr, int wc, int l, f32x4 (&acc)[2][2]) {
  #pragma unroll
  for (int ks = 0; ks < 2; ++ks) {
    bf16x8 af[2], bfr[2];
    #pragma unroll
    for (int mi = 0; mi < 2; ++mi) {
      int row   = wr * 32 + mi * 16 + (l & 15);
      int inrow = (ks * 64 + ((l >> 4) << 4)) ^ ((row & 7) << 4);
      af[mi] = *(const bf16x8*)&As[row * 64 + (inrow >> 1)];
    }
    #pragma unroll
    for (int ni = 0; ni < 2; ++ni) {
      int row   = wc * 32 + ni * 16 + (l & 15);
      int inrow = (ks * 64 + ((l >> 4) << 4)) ^ ((row & 7) << 4);
      bfr[ni] = *(const bf16x8*)&Bs[row * 64 + (inrow >> 1)];
    }
    #pragma unroll
    for (int mi = 0; mi < 2; ++mi)
      #pragma unroll
      for (int ni = 0; ni < 2; ++ni)
        acc[mi][ni] = __builtin_amdgcn_mfma_f32_16x16x32_bf16(af[mi], bfr[ni], acc[mi][ni], 0, 0, 0);
  }
}

// ---- proj partial GEMM: grid (32 row-tiles, 8 K-chunks), double-buffered ---
__global__ __launch_bounds__(256) void proj_part(
    const unsigned short* __restrict__ Ah, const unsigned short* __restrict__ Al,
    const unsigned short* __restrict__ Wh, const unsigned short* __restrict__ Wl,
    float* __restrict__ Pp) {
  __shared__ __align__(16) short smem[32768];   // 64 KB: 2 x (A 16KB | B 16KB)
  const int tid = threadIdx.x;
  const int l   = tid & 63, w = tid >> 6;
  const int wr  = w >> 1, wc = w & 1;
  const int r0  = blockIdx.x * 128;
  const int s   = blockIdx.y;

  auto stage_ph = [&](int t, short* h) {
    int ktg  = s * 6 + t;                  // 0..47: 3 terms x 16 K-chunks
    int term = ktg >> 4, k0 = (ktg & 15) << 6;
    const unsigned short* sA = (term < 2) ? Ah : Al;   // [hi|hi|lo]
    const unsigned short* sB = (term == 1) ? Wl : Wh;  // [hi|lo|hi]
    stage_panel<1024>(sA, r0, k0, h, tid);
    stage_panel<1024>(sB, 0, k0, h + 8192, tid);
  };

  f32x4 acc[4][4] = {};
  stage_ph(0, smem);
  asm volatile("s_waitcnt vmcnt(0)" ::: "memory");
  __syncthreads();
  for (int t = 0; t < 6; ++t) {
    short* h = smem + (t & 1) * 16384;
    if (t < 5) stage_ph(t + 1, smem + ((t + 1) & 1) * 16384);
    mfma_tiles(h, h + 8192, wr, wc, l, acc);
    asm volatile("s_waitcnt vmcnt(0)" ::: "memory");
    __syncthreads();
  }
  float* out = Pp + (size_t)s * (MM * PJ);
  #pragma unroll
  for (int mi = 0; mi < 4; ++mi)
    #pragma unroll
    for (int ni = 0; ni < 4; ++ni)
      #pragma unroll
      for (int r = 0; r < 4; ++r) {
        int i = r0 + wr * 64 + mi * 16 + ((l >> 4) << 2) + r;
        int j = wc * 64 + ni * 16 + (l & 15);
        out[(size_t)i * PJ + j] = acc[mi][ni][r];
      }
}

// ---- proj finish: sum partials + bias + split + row-norm -------------------
__global__ void proj_finish(const float* __restrict__ Pp, const float* __restrict__ bp,
                            unsigned short* __restrict__ Zh, unsigned short* __restrict__ Zl,
                            float* __restrict__ n2x) {
  int wv = threadIdx.x >> 6, lane = threadIdx.x & 63;
  int row = blockIdx.x * 4 + wv;
  size_t base = (size_t)row * 128;
  float v0 = bp[lane], v1 = bp[64 + lane];
  #pragma unroll
  for (int s = 0; s < 8; ++s) {
    v0 += Pp[(size_t)s * (MM * PJ) + base + lane];
    v1 += Pp[(size_t)s * (MM * PJ) + base + 64 + lane];
  }
  unsigned short h0 = f2bf(v0), h1 = f2bf(v1);
  Zh[base + lane] = h0;            Zh[base + 64 + lane] = h1;
  Zl[base + lane] = f2bf(v0 - bf2f(h0));
  Zl[base + 64 + lane] = f2bf(v1 - bf2f(h1));
  float s2 = v0 * v0 + v1 * v1;
  for (int off = 32; off > 0; off >>= 1) s2 += __shfl_down(s2, off, 64);
  if (lane == 0) n2x[row] = s2;
}

// ---- fused gram + hist1 + pd store (fast path, 512 threads / 8 waves) ------
// 32 KB single-buffer staging + launch_bounds(512,6): VGPR<=85 + 32KB LDS
// -> 3 blocks/CU (24 waves) vs round-14's 2 blocks. Cross-block TLP hides
// the per-phase stage latency (r8/r14 mechanism).
// pd slab layout per (z,tile): u32[8][2048], elem (mi*2+ni)*2048 + tid*4 + r.
__global__ __launch_bounds__(512, 6) void gram_hist_pd(
    const unsigned short* __restrict__ Zhx, const unsigned short* __restrict__ Zlx,
    const unsigned short* __restrict__ Zhy, const unsigned short* __restrict__ Zly,
    const float* __restrict__ n2x, const float* __restrict__ n2y,
    unsigned* __restrict__ ghx, unsigned* __restrict__ ghy,
    unsigned* __restrict__ pd) {
  __shared__ __align__(16) short smem[16384];   // 32 KB: As 16KB | Bs 16KB
  int bi, bj;
  tri_map(blockIdx.x, bi, bj);
  const int z = blockIdx.y;
  const unsigned short* Zh = z ? Zhy : Zhx;
  const unsigned short* Zl = z ? Zly : Zlx;
  const float* n2 = z ? n2y : n2x;
  unsigned* gh = z ? ghy : ghx;
  const int r0 = bi * 128, c0 = bj * 128;

  const int tid = threadIdx.x;                 // 0..511
  const int l   = tid & 63, w = tid >> 6;      // w 0..7
  const int wr  = w >> 2, wc = w & 3;          // wave tile: 64 rows x 32 cols

  f32x4 acc[4][2] = {};
  for (int kt = 0; kt < 6; ++kt) {
    const unsigned short* srcA = (kt < 4) ? Zh : Zl;
    const unsigned short* srcB = (kt < 2 || kt >= 4) ? Zh : Zl;
    const int k0 = (kt & 1) * 64;
    stage_panel2<128>(srcA, r0, k0, smem, tid);
    stage_panel2<128>(srcB, c0, k0, smem + 8192, tid);
    asm volatile("s_waitcnt vmcnt(0)" ::: "memory");
    __syncthreads();
    mfma_tiles8(smem, smem + 8192, wr, wc, l, acc);
    __syncthreads();
  }

  unsigned* lh = (unsigned*)smem;
  for (int t = tid; t < 8192; t += 512) lh[t] = 0u;
  __syncthreads();

  const unsigned inc = (bi == bj) ? 1u : 2u;
  unsigned* pdt = pd + ((size_t)z * NTRI128 + blockIdx.x) * 16384;

  float n2i[4][4], n2j[2];
  #pragma unroll
  for (int mi = 0; mi < 4; ++mi)
    #pragma unroll
    for (int r = 0; r < 4; ++r)
      n2i[mi][r] = n2[r0 + wr * 64 + mi * 16 + ((l >> 4) << 2) + r];
  #pragma unroll
  for (int ni = 0; ni < 2; ++ni) n2j[ni] = n2[c0 + wc * 32 + ni * 16 + (l & 15)];

  #pragma unroll
  for (int mi = 0; mi < 4; ++mi) {
    #pragma unroll
    for (int ni = 0; ni < 2; ++ni) {
      uint4 uv;
      #pragma unroll
      for (int r = 0; r < 4; ++r) {
        float pdv = n2i[mi][r] + n2j[ni] - 2.0f * acc[mi][ni][r];
        unsigned u = mapf(pdv);
        ((unsigned*)&uv)[r] = u;
        unsigned bin = u >> 20;
        atomicAdd(&lh[((bin & 2047u) << 2) | (unsigned)(l & 3)],
                  inc << ((bin >> 11) << 4));
      }
      *(uint4*)&pdt[(mi * 2 + ni) * 2048 + tid * 4] = uv;
    }
  }
  __syncthreads();
  for (int t = tid; t < 4096; t += 512) {
    unsigned idx = (unsigned)(t & 2047) << 2;
    int sh = (t >> 11) << 4;
    unsigned v = ((lh[idx]     >> sh) & 0xffffu)
               + ((lh[idx | 1] >> sh) & 0xffffu)
               + ((lh[idx | 2] >> sh) & 0xffffu)
               + ((lh[idx | 3] >> sh) & 0xffffu);
    if (v) atomicAdd(&gh[t], v);
  }
}

// ---- streaming hist2 from stored pd (fast path, uint4 loads) ---------------
// Layout-agnostic: histograms all 16384 values of the slab regardless of order.
__global__ __launch_bounds__(256) void pd_hist2(
    const unsigned* __restrict__ pd,
    const Ctrl* __restrict__ ctrlx, const Ctrl* __restrict__ ctrly,
    unsigned* __restrict__ part) {
  __shared__ unsigned lh[8192];
  const int tid = threadIdx.x, z = blockIdx.y;
  int bi, bj;
  tri_map(blockIdx.x, bi, bj);
  const Ctrl* ctrl = z ? ctrly : ctrlx;
  const unsigned p0 = ctrl->pref[0], p1 = ctrl->pref[1];
  const unsigned inc = (bi == bj) ? 1u : 2u;
  const uint4* pt = (const uint4*)(pd + ((size_t)z * NTRI128 + blockIdx.x) * 16384);
  for (int t = tid; t < 8192; t += 256) lh[t] = 0u;
  __syncthreads();
  #pragma unroll 4
  for (int it = 0; it < 16; ++it) {
    uint4 uv = pt[it * 256 + tid];
    #pragma unroll
    for (int e = 0; e < 4; ++e) {
      unsigned u = ((const unsigned*)&uv)[e];
      unsigned top = u >> 20, mid = (u >> 8) & 4095u;
      if (top == p0) atomicAdd(&lh[mid], inc);
      if (top == p1) atomicAdd(&lh[4096 + mid], inc);
    }
  }
  __syncthreads();
  unsigned* dst = part + ((size_t)z * NTRI128 + blockIdx.x) * 4096;
  for (int t = tid; t < 4096; t += 256)
    dst[t] = (lh[2 * t] & 0xffffu) | (lh[2 * t + 1] << 16);
}

// ---- streaming KL from stored pd (fast path, 512 threads, grid 528) --------
// Index map mirrors the 512-thread producer:
//   value (mi*2+ni)*2048 + tid*4 + r  <->  i = r0 + wr*64+mi*16+((l>>4)<<2)+r,
//                                          j = c0 + wc*32+ni*16+(l&15)
__global__ __launch_bounds__(512) void pd_kl(
    const unsigned* __restrict__ pdx, const unsigned* __restrict__ pdy,
    const Ctrl* __restrict__ ctrlx, const Ctrl* __restrict__ ctrly,
    double* __restrict__ colK, double* __restrict__ colL, double* __restrict__ S1) {
  __shared__ float rowKs[128], rowLs[128], colKs[128], colLs[128];
  __shared__ float red[512];
  int bi, bj;
  tri_map(blockIdx.x, bi, bj);
  const int r0 = bi * 128, c0 = bj * 128;
  const bool diag = (bi == bj);
  const int tid = threadIdx.x;
  const int l = tid & 63, w = tid >> 6;
  const int wr = w >> 2, wc = w & 3;
  const float fx = ctrlx->coef, fy = ctrly->coef;
  const uint4* ptx = (const uint4*)(pdx + (size_t)blockIdx.x * 16384);
  const uint4* pty = (const uint4*)(pdy + (size_t)blockIdx.x * 16384);
  if (tid < 128) { rowKs[tid] = 0.f; rowLs[tid] = 0.f; colKs[tid] = 0.f; colLs[tid] = 0.f; }
  __syncthreads();
  float s1 = 0.f;
  float cK[2] = {}, cL[2] = {};
  #pragma unroll
  for (int mi = 0; mi < 4; ++mi) {
    float rkK[4] = {}, rkL[4] = {};
    #pragma unroll
    for (int ni = 0; ni < 2; ++ni) {
      uint4 ux = ptx[(mi * 2 + ni) * 512 + tid];
      uint4 uy = pty[(mi * 2 + ni) * 512 + tid];
      #pragma unroll
      for (int r = 0; r < 4; ++r) {
        float Kv = exp2f(unmapf(((const unsigned*)&ux)[r]) * fx);
        float Lv = exp2f(unmapf(((const unsigned*)&uy)[r]) * fy);
        s1 += Kv * Lv;
        rkK[r] += Kv; rkL[r] += Lv;
        cK[ni] += Kv; cL[ni] += Lv;
      }
    }
    #pragma unroll
    for (int r = 0; r < 4; ++r) {
      int il = wr * 64 + mi * 16 + ((l >> 4) << 2) + r;
      float rk = rkK[r], rl = rkL[r];
      rk += __shfl_xor(rk, 1); rk += __shfl_xor(rk, 2);
      rk += __shfl_xor(rk, 4); rk += __shfl_xor(rk, 8);
      rl += __shfl_xor(rl, 1); rl += __shfl_xor(rl, 2);
      rl += __shfl_xor(rl, 4); rl += __shfl_xor(rl, 8);
      if ((l & 15) == 0) {
        atomicAdd(&rowKs[il], rk);
        atomicAdd(&rowLs[il], rl);
      }
    }
  }
  #pragma unroll
  for (int ni = 0; ni < 2; ++ni) {
    float ck = cK[ni], cl = cL[ni];
    ck += __shfl_xor(ck, 16); ck += __shfl_xor(ck, 32);
    cl += __shfl_xor(cl, 16); cl += __shfl_xor(cl, 32);
    if (l < 16) {
      int jl = wc * 32 + ni * 16 + l;
      atomicAdd(&colKs[jl], ck);
      atomicAdd(&colLs[jl], cl);
    }
  }
  red[tid] = s1;
  __syncthreads();
  for (int off = 256; off > 0; off >>= 1) {
    if (tid < off) red[tid] += red[tid + off];
    __syncthreads();
  }
  if (tid == 0) atomicAdd(S1, (double)red[0] * (diag ? 1.0 : 2.0));
  if (tid < 128) {
    atomicAdd(&colK[c0 + tid], (double)colKs[tid]);
    atomicAdd(&colL[c0 + tid], (double)colLs[tid]);
    if (!diag) {
      atomicAdd(&colK[r0 + tid], (double)rowKs[tid]);
      atomicAdd(&colL[r0 + tid], (double)rowLs[tid]);
    }
  }
}

// ---- gram hist passes (fallback path) --------------------------------------
template <int MODE>
__global__ __launch_bounds__(256) void gram_hist(
    const unsigned short* __restrict__ Zhx, const unsigned short* __restrict__ Zlx,
    const unsigned short* __restrict__ Zhy, const unsigned short* __restrict__ Zly,
    const float* __restrict__ n2x, const float* __restrict__ n2y,
    const Ctrl* __restrict__ ctrlx, const Ctrl* __restrict__ ctrly,
    unsigned* __restrict__ ghx, unsigned* __restrict__ ghy,
    unsigned* __restrict__ part) {
  __shared__ __align__(16) short smem[32768];
  int bi, bj;
  tri_map(blockIdx.x, bi, bj);
  const int z = blockIdx.y;
  const unsigned short* Zh = z ? Zhy : Zhx;
  const unsigned short* Zl = z ? Zly : Zlx;
  const float* n2 = z ? n2y : n2x;
  const Ctrl* ctrl = z ? ctrly : ctrlx;
  unsigned* gh = z ? ghy : ghx;
  const int r0 = bi * 128, c0 = bj * 128;

  const int tid = threadIdx.x;
  const int l   = tid & 63, w = tid >> 6;
  const int wr  = w >> 1, wc = w & 1;

  auto stage_ph = [&](int kt, short* h) {
    const unsigned short* srcA = (kt < 4) ? Zh : Zl;
    const unsigned short* srcB = (kt < 2 || kt >= 4) ? Zh : Zl;
    const int k0 = (kt & 1) * 64;
    stage_panel<128>(srcA, r0, k0, h, tid);
    stage_panel<128>(srcB, c0, k0, h + 8192, tid);
  };

  f32x4 acc[4][4] = {};
  stage_ph(0, smem);
  asm volatile("s_waitcnt vmcnt(0)" ::: "memory");
  __syncthreads();
  for (int kt = 0; kt < 6; ++kt) {
    short* h = smem + (kt & 1) * 16384;
    if (kt < 5) stage_ph(kt + 1, smem + ((kt + 1) & 1) * 16384);
    mfma_tiles(h, h + 8192, wr, wc, l, acc);
    asm volatile("s_waitcnt vmcnt(0)" ::: "memory");
    __syncthreads();
  }

  unsigned* lh = (unsigned*)smem;
  for (int t = tid; t < 8192; t += 256) lh[t] = 0u;
  __syncthreads();

  unsigned p0 = 0, p1 = 0;
  if constexpr (MODE == 2) { p0 = ctrl->pref[0]; p1 = ctrl->pref[1]; }
  const unsigned inc = (bi == bj) ? 1u : 2u;

  float n2i[4][4], n2j[4];
  #pragma unroll
  for (int mi = 0; mi < 4; ++mi)
    #pragma unroll
    for (int r = 0; r < 4; ++r)
      n2i[mi][r] = n2[r0 + wr * 64 + mi * 16 + ((l >> 4) << 2) + r];
  #pragma unroll
  for (int ni = 0; ni < 4; ++ni) n2j[ni] = n2[c0 + wc * 64 + ni * 16 + (l & 15)];

  #pragma unroll
  for (int mi = 0; mi < 4; ++mi) {
    #pragma unroll
    for (int ni = 0; ni < 4; ++ni) {
      #pragma unroll
      for (int r = 0; r < 4; ++r) {
        float pdv = n2i[mi][r] + n2j[ni] - 2.0f * acc[mi][ni][r];
        unsigned u = mapf(pdv);
        if constexpr (MODE == 1) {
          unsigned bin = u >> 20;
          atomicAdd(&lh[((bin & 2047u) << 2) | (unsigned)(l & 3)],
                    inc << ((bin >> 11) << 4));
        } else {
          unsigned top = u >> 20, mid = (u >> 8) & 4095u;
          if (top == p0) atomicAdd(&lh[mid], inc);
          if (top == p1) atomicAdd(&lh[4096 + mid], inc);
        }
      }
    }
  }
  __syncthreads();
  if constexpr (MODE == 1) {
    for (int t = tid; t < 4096; t += 256) {
      unsigned idx = (unsigned)(t & 2047) << 2;
      int sh = (t >> 11) << 4;
      unsigned v = ((lh[idx]     >> sh) & 0xffffu)
                 + ((lh[idx | 1] >> sh) & 0xffffu)
                 + ((lh[idx | 2] >> sh) & 0xffffu)
                 + ((lh[idx | 3] >> sh) & 0xffffu);
      if (v) atomicAdd(&gh[t], v);
    }
  } else {
    unsigned* dst = part + ((size_t)z * NTRI128 + blockIdx.x) * 4096;
    for (int t = tid; t < 4096; t += 256)
      dst[t] = (lh[2 * t] & 0xffffu) | (lh[2 * t + 1] << 16);
  }
}

// ---- sum the per-block MODE-2 histograms -----------------------------------
__global__ void hist2_reduce(const unsigned* __restrict__ part,
                             unsigned* __restrict__ ghx, unsigned* __restrict__ ghy) {
  const int t = blockIdx.x * 256 + threadIdx.x;   // 0..4095: u32 pair index
  const int z = blockIdx.y;
  const int b0 = blockIdx.z * 66;
  const int nb = (b0 + 66 <= NTRI128) ? 66 : (NTRI128 - b0);
  const unsigned* p = part + ((size_t)z * NTRI128 + b0) * 4096;
  unsigned s0 = 0, s1 = 0;
  for (int b = 0; b < nb; ++b) {
    unsigned v = p[(size_t)b * 4096 + t];
    s0 += v & 0xffffu;
    s1 += v >> 16;
  }
  unsigned* gh = z ? ghy : ghx;
  if (s0) atomicAdd(&gh[2 * t], s0);
  if (s1) atomicAdd(&gh[2 * t + 1], s1);
}

// ---- KL pass (fallback path, round-8 single-buffer 64^2 version) -----------
__global__ __launch_bounds__(256) void gram_kl(
    const unsigned short* __restrict__ Zhx, const unsigned short* __restrict__ Zlx,
    const unsigned short* __restrict__ Zhy, const unsigned short* __restrict__ Zly,
    const float* __restrict__ n2x, const float* __restrict__ n2y,
    const Ctrl* __restrict__ ctrlx, const Ctrl* __restrict__ ctrly,
    double* __restrict__ colK, double* __restrict__ colL, double* __restrict__ S1) {
  __shared__ __align__(16) short smem[8192];   // 16 KB: As(64x64) | Bs(64x64)
  int bi, bj;
  tri_map(blockIdx.x, bi, bj);
  const int r0 = bi * 64, c0 = bj * 64;
  const bool diag = (bi == bj);
  const int tid = threadIdx.x;
  const int l   = tid & 63, w = tid >> 6;
  const int wr  = w >> 1, wc = w & 1;
  short* As = smem;
  short* Bs = smem + 4096;

  f32x4 accx[2][2] = {};
  f32x4 accy[2][2] = {};
  #pragma unroll
  for (int m = 0; m < 2; ++m) {
    const unsigned short* Zh = m ? Zhy : Zhx;
    const unsigned short* Zl = m ? Zly : Zlx;
    for (int kt = 0; kt < 6; ++kt) {
      const unsigned short* sA = (kt < 4) ? Zh : Zl;
      const unsigned short* sB = (kt < 2 || kt >= 4) ? Zh : Zl;
      const int k0 = (kt & 1) * 64;
      stage64(sA, r0, k0, As, tid);
      stage64(sB, c0, k0, Bs, tid);
      asm volatile("s_waitcnt vmcnt(0)" ::: "memory");
      __syncthreads();
      if (m == 0) mfma64(As, Bs, wr, wc, l, accx);
      else        mfma64(As, Bs, wr, wc, l, accy);
      __syncthreads();
    }
  }

  float* rowKs = (float*)smem;
  float* rowLs = rowKs + 64;
  float* colKs = rowLs + 64;
  float* colLs = colKs + 64;
  float* red   = colLs + 64;
  ((float*)smem)[tid] = 0.f;
  __syncthreads();

  const float fx = ctrlx->coef, fy = ctrly->coef;
  float s1 = 0.f;
  float cK[2] = {0.f, 0.f}, cL[2] = {0.f, 0.f};
  #pragma unroll
  for (int mi = 0; mi < 2; ++mi) {
    #pragma unroll
    for (int r = 0; r < 4; ++r) {
      int il = wr * 32 + mi * 16 + ((l >> 4) << 2) + r;
      int i  = r0 + il;
      float rk = 0.f, rl = 0.f;
      #pragma unroll
      for (int ni = 0; ni < 2; ++ni) {
        int j = c0 + wc * 32 + ni * 16 + (l & 15);
        float Kv = exp2f((n2x[i] + n2x[j] - 2.0f * accx[mi][ni][r]) * fx);
        float Lv = exp2f((n2y[i] + n2y[j] - 2.0f * accy[mi][ni][r]) * fy);
        s1 += Kv * Lv;
        rk += Kv; rl += Lv;
        cK[ni] += Kv; cL[ni] += Lv;
      }
      rk += __shfl_xor(rk, 1); rk += __shfl_xor(rk, 2);
      rk += __shfl_xor(rk, 4); rk += __shfl_xor(rk, 8);
      rl += __shfl_xor(rl, 1); rl += __shfl_xor(rl, 2);
      rl += __shfl_xor(rl, 4); rl += __shfl_xor(rl, 8);
      if ((l & 15) == 0) {
        atomicAdd(&rowKs[il], rk);
        atomicAdd(&rowLs[il], rl);
      }
    }
  }
  #pragma unroll
  for (int ni = 0; ni < 2; ++ni) {
    float ck = cK[ni], cl = cL[ni];
    ck += __shfl_xor(ck, 16); ck += __shfl_xor(ck, 32);
    cl += __shfl_xor(cl, 16); cl += __shfl_xor(cl, 32);
    if (l < 16) {
      int jl = wc * 32 + ni * 16 + l;
      atomicAdd(&colKs[jl], ck);
      atomicAdd(&colLs[jl], cl);
    }
  }
  red[tid] = s1;
  __syncthreads();
  for (int off = 128; off > 0; off >>= 1) {
    if (tid < off) red[tid] += red[tid + off];
    __syncthreads();
  }
  if (tid == 0) atomicAdd(S1, (double)red[0] * (diag ? 1.0 : 2.0));
  if (tid < 64) {
    atomicAdd(&colK[c0 + tid], (double)colKs[tid]);
    atomicAdd(&colL[c0 + tid], (double)colLs[tid]);
    if (!diag) {
      atomicAdd(&colK[r0 + tid], (double)rowKs[tid]);
      atomicAdd(&colL[r0 + tid], (double)rowLs[tid]);
    }
  }
}

// ---- radix-select scan: grid(2) = one block per matrix ---------------------
// level 1: ONE scan locates both RANK0 and RANK1 (same histogram).
// level 2: two scans (q=0,1) over the refine histograms; tid0 computes sigma.
template <int SEG>
__global__ void scan_select(const unsigned* __restrict__ hxa, const unsigned* __restrict__ hya,
                            int qstride, Ctrl* ctrlx, Ctrl* ctrly, int level) {
  __shared__ unsigned part[256];
  __shared__ unsigned s_bin[2];
  const int tid = threadIdx.x;
  const int m = blockIdx.x;
  const unsigned* hbase = m ? hya : hxa;
  Ctrl* ctrl = m ? ctrly : ctrlx;
  const int nq = (level == 1) ? 1 : 2;
  for (int q = 0; q < nq; ++q) {
    const unsigned* h = hbase + q * qstride;
    unsigned loc[SEG];
    unsigned s = 0;
    #pragma unroll
    for (int b = 0; b < SEG; ++b) { loc[b] = h[tid * SEG + b]; s += loc[b]; }
    part[tid] = s; __syncthreads();
    for (int off = 1; off < 256; off <<= 1) {
      unsigned t = (tid >= off) ? part[tid - off] : 0u;
      __syncthreads();
      part[tid] += t;
      __syncthreads();
    }
    unsigned pre = part[tid] - s;
    if (level == 1) {
      #pragma unroll
      for (int qq = 0; qq < 2; ++qq) {
        unsigned rank = qq ? RANK1 : RANK0;
        if (rank >= pre && rank < pre + s) {
          unsigned cum = pre;
          #pragma unroll
          for (int b = 0; b < SEG; ++b) {
            if (rank < cum + loc[b]) {
              s_bin[qq] = tid * SEG + b;
              ctrl->rrank[qq] = rank - cum;
              break;
            }
            cum += loc[b];
          }
        }
      }
    } else {
      unsigned rank = ctrl->rrank[q];
      if (rank >= pre && rank < pre + s) {
        unsigned cum = pre;
        #pragma unroll
        for (int b = 0; b < SEG; ++b) {
          if (rank < cum + loc[b]) {
            s_bin[q] = tid * SEG + b;
            break;
          }
          cum += loc[b];
        }
      }
    }
    __syncthreads();
  }
  if (level == 1) {
    if (tid < 2) ctrl->pref[tid] = s_bin[tid];
  } else if (tid == 0) {
    unsigned u0 = (((ctrl->pref[0] << 12) | s_bin[0]) << 8) + 128u;
    unsigned u1 = (((ctrl->pref[1] << 12) | s_bin[1]) << 8) + 128u;
    float med = 0.5f * (unmapf(u0) + unmapf(u1));
    float sig = fmaxf(1e-6f, med);
    ctrl->sigma = sig;
    ctrl->coef  = -1.4426950408889634f / sig;
  }
}

// ---- final combine ---------------------------------------------------------
__global__ void finalize_hsic(const double* __restrict__ colK, const double* __restrict__ colL,
                              const double* __restrict__ S1, float* __restrict__ out) {
  __shared__ double rk[256], rl[256], rkl[256];
  double tk = 0.0, tl = 0.0, tkl = 0.0;
  for (int i = threadIdx.x; i < MM; i += 256) {
    double k = colK[i], l = colL[i];
    tk += k; tl += l; tkl += k * l;
  }
  rk[threadIdx.x] = tk; rl[threadIdx.x] = tl; rkl[threadIdx.x] = tkl;
  __syncthreads();
  for (int off = 128; off > 0; off >>= 1) {
    if (threadIdx.x < off) {
      rk[threadIdx.x]  += rk[threadIdx.x + off];
      rl[threadIdx.x]  += rl[threadIdx.x + off];
      rkl[threadIdx.x] += rkl[threadIdx.x + off];
    }
    __syncthreads();
  }
  if (threadIdx.x == 0) {
    double m = 4096.0;
    double s = S1[0] - (2.0 / m) * rkl[0] + rk[0] * rl[0] / (m * m);
    out[0] = (float)(s / (4095.0 * 4095.0));
  }
}

// ---------------------------------------------------------------------------
extern "C" void kernel_launch(void* const* d_in, const int* in_sizes, int n_in,
                              void* d_out, int out_size, void* d_ws, size_t ws_size,
                              hipStream_t stream) {
  const float* x   = (const float*)d_in[0];
  const float* y   = (const float*)d_in[1];
  const float* bxg = (const float*)d_in[2];
  const float* bxb = (const float*)d_in[3];
  const float* byg = (const float*)d_in[4];
  const float* byb = (const float*)d_in[5];
  const float* W   = (const float*)d_in[6];
  const float* b   = (const float*)d_in[7];
  float* out = (float*)d_out;

  char* w = (char*)d_ws;
  unsigned short* Ah  = (unsigned short*)(w);                   // 8 MB
  unsigned short* Al  = (unsigned short*)(w + 8388608ull);      // 8 MB
  unsigned short* Wh  = (unsigned short*)(w + 16777216ull);     // 256 KB
  unsigned short* Wl  = (unsigned short*)(w + 17039360ull);     // 256 KB
  unsigned short* Zhx = (unsigned short*)(w + 17301504ull);     // 1 MB each
  unsigned short* Zlx = (unsigned short*)(w + 18350080ull);
  unsigned short* Zhy = (unsigned short*)(w + 19398656ull);
  unsigned short* Zly = (unsigned short*)(w + 20447232ull);
  float*          Pp  = (float*)(w + 21495808ull);              // 8 x 2 MB
  // MODE-2 per-block hist slices overlay dead Ah/Al/Wh/Wl: 17,301,504 B.
  unsigned*       part = (unsigned*)(w);
  size_t ZR = 21495808ull + 16777216ull;
  double*   sumx = (double*)(w + ZR);
  double*   sqx  = sumx + 1024;
  double*   sumy = sqx + 1024;
  double*   sqy  = sumy + 128;
  unsigned* h1x  = (unsigned*)(sqy + 128);
  unsigned* h1y  = h1x + 4096;
  unsigned* h2x  = h1y + 4096;
  unsigned* h2y  = h2x + 8192;
  double*   colK = (double*)(h2y + 8192);
  double*   colL = colK + 4096;
  double*   S1   = colL + 4096;
  size_t zero_bytes = (size_t)((char*)(S1 + 1) - (w + ZR));
  size_t PR = ZR + ((zero_bytes + 255ull) & ~255ull);
  float* ax  = (float*)(w + PR);
  float* cx  = ax + 1024;
  float* ay  = cx + 1024;
  float* cy  = ay + 128;
  float* bp  = cy + 128;
  float* n2x = bp + 128;
  float* n2y = n2x + 4096;
  Ctrl* ctrlx = (Ctrl*)(n2y + 4096);
  Ctrl* ctrly = ctrlx + 1;

  // pd store (fast path): u32[2][528][16384] at 40 MiB
  constexpr size_t PD0     = 41943040ull;
  constexpr size_t PD_ELEM = (size_t)NTRI128 * 16384;            // per z
  constexpr size_t WS_FAST = PD0 + 2ull * PD_ELEM * 4ull;        // 111,149,056
  unsigned* pdx = (unsigned*)(w + PD0);
  unsigned* pdy = pdx + PD_ELEM;
  const bool fast = (ws_size >= WS_FAST);

  // zero the accumulator region with our own kernel (~2 us vs the runtime
  // fill path). Rounding into the 256B alignment pad is safe: that span is
  // dead until finalize_stats overwrites ax/cx/ay/cy.
  int n16 = (int)((zero_bytes + 15) >> 4);
  zero_ws<<<(n16 + 255) / 256, 256, 0, stream>>>((uint4*)(w + ZR), n16);

  colstats<<<dim3(5, 16), 256, 0, stream>>>(x, y, sumx, sqx, sumy, sqy);
  finalize_stats<<<5, 256, 0, stream>>>(sumx, sqx, sumy, sqy, bxg, bxb, byg, byb,
                                        ax, cx, ay, cy);
  prep<<<5376, 256, 0, stream>>>(x, y, W, b, ax, cx, ay, cy,
                                 Ah, Al, Wh, Wl, Zhy, Zly, n2y, bp);
  proj_part<<<dim3(32, 8), 256, 0, stream>>>(Ah, Al, Wh, Wl, Pp);
  proj_finish<<<1024, 256, 0, stream>>>(Pp, bp, Zhx, Zlx, n2x);

  if (fast) {
    gram_hist_pd<<<dim3(NTRI128, 2), 512, 0, stream>>>(Zhx, Zlx, Zhy, Zly, n2x, n2y,
                                                       h1x, h1y, pdx);
    scan_select<16><<<2, 256, 0, stream>>>(h1x, h1y, 0, ctrlx, ctrly, 1);
    pd_hist2<<<dim3(NTRI128, 2), 256, 0, stream>>>(pdx, ctrlx, ctrly, part);
    hist2_reduce<<<dim3(16, 2, 8), 256, 0, stream>>>(part, h2x, h2y);
    scan_select<16><<<2, 256, 0, stream>>>(h2x, h2y, 4096, ctrlx, ctrly, 2);
    pd_kl<<<NTRI128, 512, 0, stream>>>(pdx, pdy, ctrlx, ctrly,
                                       colK, colL, S1);
  } else {
    gram_hist<1><<<dim3(NTRI128, 2), 256, 0, stream>>>(Zhx, Zlx, Zhy, Zly, n2x, n2y,
                                                       ctrlx, ctrly, h1x, h1y, part);
    scan_select<16><<<2, 256, 0, stream>>>(h1x, h1y, 0, ctrlx, ctrly, 1);
    gram_hist<2><<<dim3(NTRI128, 2), 256, 0, stream>>>(Zhx, Zlx, Zhy, Zly, n2x, n2y,
                                                       ctrlx, ctrly, h2x, h2y, part);
    hist2_reduce<<<dim3(16, 2, 8), 256, 0, stream>>>(part, h2x, h2y);
    scan_select<16><<<2, 256, 0, stream>>>(h2x, h2y, 4096, ctrlx, ctrly, 2);
    gram_kl<<<NTRI64, 256, 0, stream>>>(Zhx, Zlx, Zhy, Zly, n2x, n2y,
                                        ctrlx, ctrly, colK, colL, S1);
  }
  finalize_hsic<<<1, 256, 0, stream>>>(colK, colL, S1, out);
}